// Round 4
// baseline (1749.847 us; speedup 1.0000x reference)
//
#include <hip/hip_runtime.h>
#include <cstdint>
#include <cstddef>

#define BATCH 8
#define NN 2048
#define RTOT 16384   // BATCH*NN
#define KCL 100
#define CAP 176      // ELL row capacity (mean nnz/row ~102, sigma ~10; 7.5 sigma headroom)

// ---------------- workspace layout (offsets in floats) ----------------
static constexpr size_t OF_L1W   = 0;             // 512*30*2
static constexpr size_t OF_L1B   = 30720;
static constexpr size_t OF_L2W   = 61440;
static constexpr size_t OF_L2B   = 92160;
static constexpr size_t OF_L3W   = 122880;
static constexpr size_t OF_L3B   = 153600;        // 1600*100*2 = 320000
static constexpr size_t OF_S2A   = 473600;        // 8*30*2
static constexpr size_t OF_S2B   = 474080;
static constexpr size_t OF_S2C   = 474560;
static constexpr size_t OF_AC    = 475136;        // 9 slots * 256
static constexpr size_t OF_ELLV  = 477440;                    // 16384*176
static constexpr size_t OF_ELLC  = OF_ELLV + 2883584;         // u16 x 16384*176 = 1441792 floats
static constexpr size_t OF_ROWLEN= OF_ELLC + 1441792;
static constexpr size_t OF_DINVW = OF_ROWLEN + 16384;
static constexpr size_t OF_DINVB = OF_DINVW + 16384;
static constexpr size_t OF_HW    = OF_DINVB + 16384;          // 16384*32 (stride 32)
static constexpr size_t OF_HB    = OF_HW + 524288;            // 16384*100 max (reused as softmax S)
static constexpr size_t OF_ZW    = OF_HB + 1638400;           // 16384*32
static constexpr size_t OF_ZB    = OF_ZW + 524288;            // 16384*100 max (reused as As)
static constexpr size_t OF_X11   = OF_ZB + 1638400;           // stride 32
static constexpr size_t OF_X12   = OF_X11 + 524288;
static constexpr size_t OF_X13   = OF_X12 + 524288;
static constexpr size_t OF_S11   = OF_X13 + 524288;           // stride 32; s11+s12 reused as pool partials
static constexpr size_t OF_S12   = OF_S11 + 524288;
static constexpr size_t OF_A2    = OF_S12 + 524288;           // 8*100*100
static constexpr size_t OF_Z21   = OF_A2 + 80000;             // stage-2 stride 30
static constexpr size_t OF_Z22   = OF_Z21 + 24000;
static constexpr size_t OF_Z23   = OF_Z22 + 24000;
static constexpr size_t OF_X21   = OF_Z23 + 24000;
static constexpr size_t OF_X22   = OF_X21 + 24000;
static constexpr size_t OF_PARTMAX = OF_X22 + 24000;          // 8*8*90

#define FMA4(acc, s, h) { acc.x += (s)*(h).x; acc.y += (s)*(h).y; acc.z += (s)*(h).z; acc.w += (s)*(h).w; }

// ---------------- kernels ----------------

// One pass over adj: build ELL (scan-based compaction, no serialized LDS atomics),
// weighted+binary degree, FUSED H1 = x @ W_in * dinv (stride-32 out).
__global__ __launch_bounds__(256) void k_build_ell(
    const float* __restrict__ adj, const float* __restrict__ x,
    const float* __restrict__ Win, float* __restrict__ ellv,
    unsigned short* __restrict__ ellc, int* __restrict__ rowlen,
    float* __restrict__ dinvw, float* __restrict__ dinvb,
    float* __restrict__ Hw, float* __restrict__ Hb)
{
  int r = blockIdx.x;
  const float* row = adj + (size_t)r * NN;
  int t = threadIdx.x, lane = t & 63, wv = t >> 6;
  __shared__ int wcnt[4];
  __shared__ float wsumA[4];
  __shared__ float dsh[2];
  float4 a = ((const float4*)row)[t];
  float4 b = ((const float4*)row)[256 + t];
  float vals[8] = {a.x, a.y, a.z, a.w, b.x, b.y, b.z, b.w};
  int cbase0 = t*4, cbase1 = 1024 + t*4;
  int cnt = 0; float sum = 0.f;
#pragma unroll
  for (int k = 0; k < 8; ++k) { sum += vals[k]; cnt += (vals[k] != 0.f) ? 1 : 0; }
  // 64-lane inclusive prefix scan of cnt
  int pre = cnt;
#pragma unroll
  for (int o = 1; o < 64; o <<= 1) { int n = __shfl_up(pre, o); if (lane >= o) pre += n; }
  int excl = pre - cnt;
  int wtot = __shfl(pre, 63);
  // wave sum of weighted row-sum
#pragma unroll
  for (int o = 32; o; o >>= 1) sum += __shfl_down(sum, o);
  if (lane == 0) { wcnt[wv] = wtot; wsumA[wv] = sum; }
  __syncthreads();
  int base = 0;
  for (int w = 0; w < wv; ++w) base += wcnt[w];
  int p = base + excl;
  size_t rb = (size_t)r * CAP;
#pragma unroll
  for (int k = 0; k < 8; ++k) {
    float v = vals[k];
    if (v != 0.f && p < CAP) {
      ellv[rb + p] = v;
      ellc[rb + p] = (unsigned short)((k < 4) ? (cbase0 + k) : (cbase1 + (k - 4)));
      ++p;
    }
  }
  if (t == 0) {
    int tot = wcnt[0] + wcnt[1] + wcnt[2] + wcnt[3];
    float ws = wsumA[0] + wsumA[1] + wsumA[2] + wsumA[3];
    int nnz = tot < CAP ? tot : CAP;
    int n = nnz;
    while ((n & 3) && n < CAP) { ellv[rb + n] = 0.f; ellc[rb + n] = 0; ++n; }
    rowlen[r] = n;
    float dw = rsqrtf(ws + 1.f), db = rsqrtf((float)nnz + 1.f);
    dinvw[r] = dw; dinvb[r] = db;
    dsh[0] = dw; dsh[1] = db;
  }
  __syncthreads();
  if (t < 64) {  // fused H1 for this row
    int c = t & 31, side = t >> 5;
    float v = 0.f;
    if (c < 30) {
      float x0 = x[r*3], x1 = x[r*3+1], x2 = x[r*3+2];
      const float* W = Win + side*90;
      v = (x0*W[c] + x1*W[30+c] + x2*W[60+c]) * dsh[side];
    }
    (side ? Hb : Hw)[(size_t)r*32 + c] = v;
  }
}

// Fused ELL SpMM pair (stride-32, float4/thread) with optional per-block BN-stat buckets.
template<bool PAIR, bool STATS>
__global__ __launch_bounds__(256) void k_spmm32(
    const float* __restrict__ Hw, const float* __restrict__ Hb,
    const float* __restrict__ ellv, const unsigned short* __restrict__ ellc,
    const int* __restrict__ rowlen, const float* __restrict__ dinvw,
    const float* __restrict__ dinvb, float* __restrict__ Zw, float* __restrict__ Zb,
    float* __restrict__ bktW, float* __restrict__ bktB)
{
  __shared__ float zs[1024];
  int t = threadIdx.x;
  int gid = blockIdx.x * 256 + t;   // RTOT*8
  int row = gid >> 3, q = gid & 7;
  int len = rowlen[row];
  const float4* ev = (const float4*)(ellv + (size_t)row * CAP);
  const uint2*  ec = (const uint2*) (ellc + (size_t)row * CAP);
  const float4* HW4 = (const float4*)Hw + (size_t)(row >> 11) * (NN*8);
  const float4* HB4 = (const float4*)Hb + (size_t)(row >> 11) * (NN*8);
  float4 aw = {0,0,0,0}, ab = {0,0,0,0};
  int nit = len >> 2;
  for (int i = 0; i < nit; ++i) {
    float4 v = ev[i];
    uint2 cc = ec[i];
    int c0 = cc.x & 0xffff, c1 = cc.x >> 16, c2 = cc.y & 0xffff, c3 = cc.y >> 16;
    float4 h0 = HW4[c0*8+q], h1 = HW4[c1*8+q], h2 = HW4[c2*8+q], h3 = HW4[c3*8+q];
    FMA4(aw, v.x, h0); FMA4(aw, v.y, h1); FMA4(aw, v.z, h2); FMA4(aw, v.w, h3);
    if (PAIR) {
      float4 g0 = HB4[c0*8+q], g1 = HB4[c1*8+q], g2 = HB4[c2*8+q], g3 = HB4[c3*8+q];
      float b0 = v.x>0.f?1.f:0.f, b1 = v.y>0.f?1.f:0.f, b2 = v.z>0.f?1.f:0.f, b3 = v.w>0.f?1.f:0.f;
      FMA4(ab, b0, g0); FMA4(ab, b1, g1); FMA4(ab, b2, g2); FMA4(ab, b3, g3);
    }
  }
  int rl = (row & (NN-1));
  float4 hs = HW4[rl*8+q];
  aw.x += hs.x; aw.y += hs.y; aw.z += hs.z; aw.w += hs.w;
  float dw = dinvw[row];
  float4 ow = {dw*aw.x, dw*aw.y, dw*aw.z, dw*aw.w};
  ((float4*)Zw)[(size_t)row*8+q] = ow;
  float4 ob;
  if (PAIR) {
    float4 gs = HB4[rl*8+q];
    ab.x += gs.x; ab.y += gs.y; ab.z += gs.z; ab.w += gs.w;
    float db = dinvb[row];
    ob.x = db*ab.x; ob.y = db*ab.y; ob.z = db*ab.z; ob.w = db*ab.w;
    ((float4*)Zb)[(size_t)row*8+q] = ob;
  }
  if (STATS) {
    ((float4*)zs)[t] = ow;   // zs laid out [32 rows][32 ch]
    __syncthreads();
    if (t < 30) {
      float s1 = 0.f, s2 = 0.f;
      for (int r = 0; r < 32; ++r) { float v = zs[r*32 + t]; s1 += v; s2 += v*v; }
      bktW[((size_t)blockIdx.x*30 + t)*2]   = s1;
      bktW[((size_t)blockIdx.x*30 + t)*2+1] = s2;
    }
    if (PAIR) {
      __syncthreads();
      ((float4*)zs)[t] = ob;
      __syncthreads();
      if (t < 30) {
        float s1 = 0.f, s2 = 0.f;
        for (int r = 0; r < 32; ++r) { float v = zs[r*32 + t]; s1 += v; s2 += v*v; }
        bktB[((size_t)blockIdx.x*30 + t)*2]   = s1;
        bktB[((size_t)blockIdx.x*30 + t)*2+1] = s2;
      }
    }
  }
}

// ELL SpMM, C=100 (25 float4/row) with optional LDS-reduced per-block BN buckets.
template<bool WEIGHTED, bool SELFLOOP, bool SCALED, bool STATS>
__global__ __launch_bounds__(256) void k_spmm100(
    const float* __restrict__ H, const float* __restrict__ ellv,
    const unsigned short* __restrict__ ellc, const int* __restrict__ rowlen,
    const float* __restrict__ scale, float* __restrict__ Z, float* __restrict__ bkt)
{
  __shared__ float st[200];
  int t = threadIdx.x;
  if (STATS) { for (int i = t; i < 200; i += 256) st[i] = 0.f; __syncthreads(); }
  int gid = blockIdx.x * 256 + t;   // RTOT*25
  int row = gid / 25, q = gid - row*25;
  int len = rowlen[row];
  const float4* ev = (const float4*)(ellv + (size_t)row * CAP);
  const uint2*  ec = (const uint2*) (ellc + (size_t)row * CAP);
  const float4* H4 = (const float4*)H + (size_t)(row >> 11) * (NN*25);
  float4 acc = {0,0,0,0};
  int nit = len >> 2;
  for (int i = 0; i < nit; ++i) {
    float4 v = ev[i];
    uint2 cc = ec[i];
    int c0 = cc.x & 0xffff, c1 = cc.x >> 16, c2 = cc.y & 0xffff, c3 = cc.y >> 16;
    float4 h0 = H4[c0*25+q], h1 = H4[c1*25+q], h2 = H4[c2*25+q], h3 = H4[c3*25+q];
    float w0 = WEIGHTED ? v.x : (v.x>0.f?1.f:0.f);
    float w1 = WEIGHTED ? v.y : (v.y>0.f?1.f:0.f);
    float w2 = WEIGHTED ? v.z : (v.z>0.f?1.f:0.f);
    float w3 = WEIGHTED ? v.w : (v.w>0.f?1.f:0.f);
    FMA4(acc, w0, h0); FMA4(acc, w1, h1); FMA4(acc, w2, h2); FMA4(acc, w3, h3);
  }
  if (SELFLOOP) {
    float4 hs = H4[(row & (NN-1))*25+q];
    acc.x += hs.x; acc.y += hs.y; acc.z += hs.z; acc.w += hs.w;
  }
  float s = SCALED ? scale[row] : 1.f;
  float4 o = {s*acc.x, s*acc.y, s*acc.z, s*acc.w};
  ((float4*)Z)[(size_t)row*25+q] = o;
  if (STATS) {
    int c0 = q*4;
    atomicAdd(&st[(c0+0)*2], o.x); atomicAdd(&st[(c0+0)*2+1], o.x*o.x);
    atomicAdd(&st[(c0+1)*2], o.y); atomicAdd(&st[(c0+1)*2+1], o.y*o.y);
    atomicAdd(&st[(c0+2)*2], o.z); atomicAdd(&st[(c0+2)*2+1], o.z*o.z);
    atomicAdd(&st[(c0+3)*2], o.w); atomicAdd(&st[(c0+3)*2+1], o.w*o.w);
    __syncthreads();
    for (int i = t; i < 200; i += 256) bkt[(size_t)blockIdx.x*200 + i] = st[i];
  }
}

// two-sided bucket reduce -> BN scale/shift pairs
__global__ void k_finalize2(
    const float* __restrict__ bA, int nA, int cA, const float* __restrict__ gA,
    const float* __restrict__ beA, float* __restrict__ outA,
    const float* __restrict__ bB, int nB, int cB, const float* __restrict__ gB,
    const float* __restrict__ beB, float* __restrict__ outB, float count)
{
  int c = threadIdx.x;
  if (c < cA) {
    float s1 = 0.f, s2 = 0.f;
    for (int b = 0; b < nA; ++b) {
      s1 += bA[((size_t)b*cA + c)*2];
      s2 += bA[((size_t)b*cA + c)*2 + 1];
    }
    float mean = s1/count, var = s2/count - mean*mean, inv = rsqrtf(var + 1e-5f);
    float aa = gA[c]*inv; outA[c] = aa; outA[cA + c] = beA[c] - mean*aa;
  } else if (c < cA + cB) {
    int cc = c - cA;
    float s1 = 0.f, s2 = 0.f;
    for (int b = 0; b < nB; ++b) {
      s1 += bB[((size_t)b*cB + cc)*2];
      s2 += bB[((size_t)b*cB + cc)*2 + 1];
    }
    float mean = s1/count, var = s2/count - mean*mean, inv = rsqrtf(var + 1e-5f);
    float aa = gB[cc]*inv; outB[cc] = aa; outB[cB + cc] = beB[cc] - mean*aa;
  }
}

// apply BN -> store x/s (stride 32) -> next-layer weight GEMM pre-scaled by dinv.
template<int NGB, int OSTRIDEB>
__global__ __launch_bounds__(256) void k_apply_gemm(
    const float* __restrict__ Zw, const float* __restrict__ acW,
    float* __restrict__ xst, const float* __restrict__ Ww,
    float* __restrict__ Hwo, const float* __restrict__ dinvw,
    const float* __restrict__ Zb, const float* __restrict__ acB,
    float* __restrict__ sst, const float* __restrict__ Wb,
    float* __restrict__ Hbo, const float* __restrict__ dinvb)
{
  constexpr int NG = 8 + NGB;
  __shared__ float WwL[30*32];
  __shared__ float WbL[30*OSTRIDEB];
  __shared__ float awL[60], abL[60];
  int t = threadIdx.x;
  for (int idx = t; idx < 30*32; idx += 256) {
    int k = idx >> 5, c = idx & 31;
    WwL[idx] = (c < 30) ? Ww[k*30 + c] : 0.f;
  }
  if (OSTRIDEB == 32) {
    for (int idx = t; idx < 30*32; idx += 256) {
      int k = idx >> 5, c = idx & 31;
      WbL[idx] = (c < 30) ? Wb[k*30 + c] : 0.f;
    }
  } else {
    for (int idx = t; idx < 30*OSTRIDEB; idx += 256) WbL[idx] = Wb[idx];
  }
  if (t < 60) { awL[t] = acW[t]; abL[t] = acB[t]; }
  __syncthreads();
  int gid = blockIdx.x * 256 + t;
  int row = gid / NG, g = gid % NG;
  if (g < 8) {
    const float4* Z4 = (const float4*)Zw + (size_t)row*8;
    float4 z4[8];
#pragma unroll
    for (int u = 0; u < 8; ++u) z4[u] = Z4[u];
    const float* z = (const float*)z4;
    float4 xv;
    int ch = 4*g;
    xv.x = (ch+0 < 30) ? awL[ch+0]*z[ch+0] + awL[30+ch+0] : 0.f;
    xv.y = (ch+1 < 30) ? awL[ch+1]*z[ch+1] + awL[30+ch+1] : 0.f;
    xv.z = (ch+2 < 30) ? awL[ch+2]*z[ch+2] + awL[30+ch+2] : 0.f;
    xv.w = (ch+3 < 30) ? awL[ch+3]*z[ch+3] + awL[30+ch+3] : 0.f;
    ((float4*)xst)[(size_t)row*8+g] = xv;
    float4 o = {0,0,0,0};
#pragma unroll
    for (int k = 0; k < 30; ++k) {
      float xk = awL[k]*z[k] + awL[30+k];
      float4 w = *(const float4*)(WwL + k*32 + 4*g);
      FMA4(o, xk, w);
    }
    float d = dinvw[row];
    float4 ov = {d*o.x, d*o.y, d*o.z, d*o.w};
    ((float4*)Hwo)[(size_t)row*8+g] = ov;
  } else {
    int gb = g - 8;
    const float4* Z4 = (const float4*)Zb + (size_t)row*8;
    float4 z4[8];
#pragma unroll
    for (int u = 0; u < 8; ++u) z4[u] = Z4[u];
    const float* z = (const float*)z4;
    if (gb < 8) {
      int ch = 4*gb;
      float4 sv;
      sv.x = (ch+0 < 30) ? abL[ch+0]*z[ch+0] + abL[30+ch+0] : 0.f;
      sv.y = (ch+1 < 30) ? abL[ch+1]*z[ch+1] + abL[30+ch+1] : 0.f;
      sv.z = (ch+2 < 30) ? abL[ch+2]*z[ch+2] + abL[30+ch+2] : 0.f;
      sv.w = (ch+3 < 30) ? abL[ch+3]*z[ch+3] + abL[30+ch+3] : 0.f;
      ((float4*)sst)[(size_t)row*8+gb] = sv;
    }
    float4 o = {0,0,0,0};
#pragma unroll
    for (int k = 0; k < 30; ++k) {
      float sk = abL[k]*z[k] + abL[30+k];
      float4 w = *(const float4*)(WbL + k*OSTRIDEB + 4*gb);
      FMA4(o, sk, w);
    }
    float d = dinvb[row];
    float4 ov = {d*o.x, d*o.y, d*o.z, d*o.w};
    ((float4*)Hbo)[(size_t)row*(OSTRIDEB/4) + gb] = ov;
  }
}

// BN(Z3w)->x13 (stride 32); s13=BN(Z3b); s1 = [s11|s12|s13]@Wfc + bfc; FUSED softmax -> S
__global__ __launch_bounds__(256) void k_fcpool(
    const float* __restrict__ Zw3, const float* __restrict__ acW3,
    const float* __restrict__ Zb3, const float* __restrict__ acB3,
    const float* __restrict__ s11, const float* __restrict__ s12,
    const float* __restrict__ Wfc, const float* __restrict__ bfc,
    float* __restrict__ x13, float* __restrict__ S)
{
  __shared__ float shm[14240];   // feat 64x160 = 10240 | Wl 40x100 = 4000
  float* feat = shm;
  float* Wl = shm + 10240;
  int t = threadIdx.x;
  int g0 = blockIdx.x * 64;
  for (int idx = t; idx < 64*160; idx += 256) {
    int l = idx / 160, c = idx % 160;
    int g = g0 + l;
    float v;
    if (c < 30) v = s11[(size_t)g*32 + c];
    else if (c < 60) v = s12[(size_t)g*32 + (c-30)];
    else { int k = c - 60; v = acB3[k]*Zb3[(size_t)g*100 + k] + acB3[100 + k]; }
    feat[l*160 + c] = v;
  }
  for (int idx = t; idx < 64*32; idx += 256) {
    int l = idx >> 5, c = idx & 31;
    int g = g0 + l;
    x13[(size_t)g*32+c] = (c < 30) ? acW3[c]*Zw3[(size_t)g*32+c] + acW3[30+c] : 0.f;
  }
  int np = t >> 3, kg = t & 7;
  int n0 = np*2, n1 = np*2 + 1;
  int kbase = kg*12 + (kg < 4 ? kg : 4);
  int klen  = kg < 4 ? 13 : 12;
  float a0[13], a1[13];
#pragma unroll
  for (int j = 0; j < 13; ++j) { a0[j] = 0.f; a1[j] = 0.f; }
  for (int ch = 0; ch < 4; ++ch) {
    __syncthreads();
    for (int idx = t; idx < 4000; idx += 256) {
      int r = idx/100, j = idx%100;
      Wl[r*100 + j] = Wfc[(ch*40 + r)*100 + j];
    }
    __syncthreads();
    for (int kk = 0; kk < 40; ++kk) {
      float f0 = feat[n0*160 + ch*40+kk];
      float f1 = feat[n1*160 + ch*40+kk];
#pragma unroll
      for (int j = 0; j < 13; ++j) {
        if (j < klen) {
          float w = Wl[kk*100 + kbase + j];
          a0[j] += f0*w; a1[j] += f1*w;
        }
      }
    }
  }
  __syncthreads();
  // reuse shm[0..6399] as sRow[64][100]
  float* sRow = shm;
  for (int j = 0; j < klen; ++j) {
    int k = kbase + j;
    sRow[n0*100 + k] = a0[j] + bfc[k];
    sRow[n1*100 + k] = a1[j] + bfc[k];
  }
  __syncthreads();
  // softmax: 4 threads per node (25 entries each)
  int n = t >> 2, part = t & 3;
  int i0 = part*25;
  float m = -3.4e38f;
  for (int i = 0; i < 25; ++i) m = fmaxf(m, sRow[n*100 + i0 + i]);
  m = fmaxf(m, __shfl_xor(m, 1));
  m = fmaxf(m, __shfl_xor(m, 2));
  float ev[25]; float s = 0.f;
  for (int i = 0; i < 25; ++i) { float e = __expf(sRow[n*100 + i0 + i] - m); ev[i] = e; s += e; }
  s += __shfl_xor(s, 1);
  s += __shfl_xor(s, 2);
  float rinv = 1.f / s;
  for (int i = 0; i < 25; ++i) S[(size_t)(g0+n)*100 + i0 + i] = ev[i] * rinv;
}

// pooled partials: pp[blk][k][d] over this block's 256 nodes; NO atomics
__global__ __launch_bounds__(256) void k_pool_part(
    const float* __restrict__ S, const float* __restrict__ x13,
    const float* __restrict__ As, float* __restrict__ pp)
{
  __shared__ float sL[64][100];
  __shared__ float xL[64][132];
  int t = threadIdx.x;
  int b = blockIdx.x >> 3, chunk = blockIdx.x & 7;
  int g00 = b * 2048 + chunk * 256;
  int kt = t/10, dt = t%10;
  int k0 = kt*4, d0 = dt*13;
  float acc[4][13];
#pragma unroll
  for (int a = 0; a < 4; ++a)
#pragma unroll
    for (int j = 0; j < 13; ++j) acc[a][j] = 0.f;
  for (int tile = 0; tile < 4; ++tile) {
    int g0 = g00 + tile*64;
    __syncthreads();
    for (int idx = t; idx < 64*100; idx += 256) {
      int l = idx/100, k = idx%100;
      sL[l][k] = S[(size_t)(g0+l)*100 + k];
    }
    for (int idx = t; idx < 64*130; idx += 256) {
      int l = idx/130, d = idx%130;
      xL[l][d] = d < 30 ? x13[(size_t)(g0+l)*32 + d] : As[(size_t)(g0+l)*100 + (d-30)];
    }
    __syncthreads();
    if (t < 250) {
      for (int kk = 0; kk < 64; ++kk) {
        float sv[4];
#pragma unroll
        for (int a = 0; a < 4; ++a) sv[a] = sL[kk][k0+a];
#pragma unroll
        for (int j = 0; j < 13; ++j) {
          float xv = xL[kk][d0+j];
#pragma unroll
          for (int a = 0; a < 4; ++a) acc[a][j] += sv[a]*xv;
        }
      }
    }
  }
  if (t < 250) {
    float* dst = pp + (size_t)blockIdx.x * 13000;
    for (int a = 0; a < 4; ++a)
      for (int j = 0; j < 13; ++j)
        dst[(k0+a)*130 + (d0+j)] = acc[a][j];
  }
}

// stage-2 layer 1 FUSED with pool-reduce + A2 normalize. One block per batch.
__global__ __launch_bounds__(256) void k_s2pool(
    const float* __restrict__ pp, const float* __restrict__ Wm,
    float* __restrict__ A2, float* __restrict__ Zout, float* __restrict__ bkt)
{
  __shared__ float Ah[10000];
  __shared__ float Xl[3000];
  __shared__ float Tl[3000];
  __shared__ float dl[100];
  __shared__ float st1[30], st2[30];
  int b = blockIdx.x, t = threadIdx.x;
  if (t < 30) { st1[t] = 0.f; st2[t] = 0.f; }
  for (int idx = t; idx < 13000; idx += 256) {
    float s = 0.f;
    for (int ch = 0; ch < 8; ++ch) s += pp[(size_t)(b*8 + ch)*13000 + idx];
    int k = idx/130, d = idx%130;
    if (d < 30) Xl[k*30 + d] = s; else Ah[k*100 + (d-30)] = s;
  }
  __syncthreads();
  if (t < 100 && Ah[t*101] == 0.f) Ah[t*101] = 1.f;
  __syncthreads();
  if (t < 100) {
    float s = 0.f;
    for (int j = 0; j < 100; ++j) s += Ah[t*100 + j];
    dl[t] = s > 0.f ? rsqrtf(s) : 0.f;
  }
  __syncthreads();
  for (int idx = t; idx < 10000; idx += 256) {
    int i = idx/100, j = idx%100;
    float v = dl[i]*dl[j]*Ah[idx];
    Ah[idx] = v;
    A2[(size_t)b*10000 + idx] = v;
  }
  __syncthreads();
  for (int idx = t; idx < 3000; idx += 256) {
    int i = idx/30, c = idx%30;
    float acc = 0.f;
    for (int k = 0; k < 30; ++k) acc += Xl[i*30+k]*Wm[k*30+c];
    Tl[idx] = acc;
  }
  __syncthreads();
  for (int idx = t; idx < 3000; idx += 256) {
    int i = idx/30, c = idx%30;
    float acc = 0.f;
    for (int j = 0; j < 100; ++j) acc += Ah[i*100+j]*Tl[j*30+c];
    Zout[(size_t)b*3000 + idx] = acc;
    atomicAdd(&st1[c], acc);
    atomicAdd(&st2[c], acc*acc);
  }
  __syncthreads();
  if (t < 30) {
    bkt[((size_t)b*30 + t)*2]   = st1[t];
    bkt[((size_t)b*30 + t)*2+1] = st2[t];
  }
}

// stage-2 layers 2,3: inline BN-finalize of prev bucket, then layer + stats
__global__ __launch_bounds__(256) void k_s2layer(
    const float* __restrict__ Zprev, const float* __restrict__ prevBkt,
    const float* __restrict__ gamma, const float* __restrict__ beta,
    float* __restrict__ xst, const float* __restrict__ Wm,
    const float* __restrict__ A2, float* __restrict__ Zout, float* __restrict__ bkt)
{
  __shared__ float Xl[3000];
  __shared__ float Tl[3000];
  __shared__ float Al[10000];
  __shared__ float acL[60];
  __shared__ float st1[30], st2[30];
  int b = blockIdx.x, t = threadIdx.x;
  if (t < 30) {
    float s1 = 0.f, s2 = 0.f;
    for (int q = 0; q < 8; ++q) {
      s1 += prevBkt[((size_t)q*30 + t)*2];
      s2 += prevBkt[((size_t)q*30 + t)*2+1];
    }
    float mean = s1/800.f, var = s2/800.f - mean*mean, inv = rsqrtf(var + 1e-5f);
    float aa = gamma[t]*inv; acL[t] = aa; acL[30+t] = beta[t] - mean*aa;
    st1[t] = 0.f; st2[t] = 0.f;
  }
  __syncthreads();
  for (int idx = t; idx < 3000; idx += 256) {
    int c = idx % 30;
    float v = acL[c]*Zprev[(size_t)b*3000 + idx] + acL[30+c];
    xst[(size_t)b*3000 + idx] = v;
    Xl[idx] = v;
  }
  for (int idx = t; idx < 10000; idx += 256) Al[idx] = A2[(size_t)b*10000 + idx];
  __syncthreads();
  for (int idx = t; idx < 3000; idx += 256) {
    int i = idx/30, c = idx%30;
    float acc = 0.f;
    for (int k = 0; k < 30; ++k) acc += Xl[i*30+k]*Wm[k*30+c];
    Tl[idx] = acc;
  }
  __syncthreads();
  for (int idx = t; idx < 3000; idx += 256) {
    int i = idx/30, c = idx%30;
    float acc = 0.f;
    for (int j = 0; j < 100; ++j) acc += Al[i*100+j]*Tl[j*30+c];
    Zout[(size_t)b*3000 + idx] = acc;
    atomicAdd(&st1[c], acc);
    atomicAdd(&st2[c], acc*acc);
  }
  __syncthreads();
  if (t < 30) {
    bkt[((size_t)b*30 + t)*2]   = st1[t];
    bkt[((size_t)b*30 + t)*2+1] = st2[t];
  }
}

// stage-1 per-segment column max of [x11|x12|x13] (stride 32, coalesced)
__global__ __launch_bounds__(256) void k_max1(
    const float* __restrict__ x11, const float* __restrict__ x12,
    const float* __restrict__ x13, float* __restrict__ pm)
{
  __shared__ float red[256];
  int t = threadIdx.x, c = t & 31, rg = t >> 5;
  int b = blockIdx.x >> 3, seg = blockIdx.x & 7;
  int r0 = b*2048 + seg*256;
  const float* srcs[3] = {x11, x12, x13};
  for (int a = 0; a < 3; ++a) {
    const float* p = srcs[a] + (size_t)(r0+rg)*32 + c;
    float m = -3.4e38f;
    for (int it = 0; it < 32; ++it) m = fmaxf(m, p[it*256]);
    red[t] = m;
    __syncthreads();
    if (t < 30) {
      float mm = red[t];
      for (int g = 1; g < 8; ++g) mm = fmaxf(mm, red[g*32+t]);
      pm[(size_t)(b*8+seg)*90 + a*30 + t] = mm;
    }
    __syncthreads();
  }
}

// FUSED: finalize bktS2c -> x1out/x2out maxes -> MLP -> out. One block per batch.
__global__ __launch_bounds__(128) void k_maxmlp(
    const float* __restrict__ pm, const float* __restrict__ x21,
    const float* __restrict__ x22, const float* __restrict__ Z23,
    const float* __restrict__ bktS2c, const float* __restrict__ gamma,
    const float* __restrict__ beta,
    const float* __restrict__ W1, const float* __restrict__ b1,
    const float* __restrict__ W2, const float* __restrict__ b2,
    float* __restrict__ out)
{
  __shared__ float ac[60], x1L[90], x2L[90], hh[50];
  int b = blockIdx.x, t = threadIdx.x;
  if (t < 30) {
    float s1 = 0.f, s2 = 0.f;
    for (int q = 0; q < 8; ++q) {
      s1 += bktS2c[((size_t)q*30 + t)*2];
      s2 += bktS2c[((size_t)q*30 + t)*2+1];
    }
    float mean = s1/800.f, var = s2/800.f - mean*mean, inv = rsqrtf(var + 1e-5f);
    float aa = gamma[t]*inv; ac[t] = aa; ac[30+t] = beta[t] - mean*aa;
  }
  __syncthreads();
  if (t < 90) {
    float m = -3.4e38f;
    for (int s = 0; s < 8; ++s) m = fmaxf(m, pm[(size_t)(b*8+s)*90 + t]);
    x1L[t] = m;
    float m2 = -3.4e38f;
    int cc = t % 30;
    for (int i = 0; i < 100; ++i) {
      float v;
      if (t < 30) v = x21[(size_t)b*3000 + i*30 + cc];
      else if (t < 60) v = x22[(size_t)b*3000 + i*30 + cc];
      else v = ac[cc]*Z23[(size_t)b*3000 + i*30 + cc] + ac[30+cc];
      m2 = fmaxf(m2, v);
    }
    x2L[t] = m2;
  }
  __syncthreads();
  if (t < 50) {
    float acc = b1[t];
    for (int k = 0; k < 90; ++k) acc += x1L[k]*W1[k*50+t];
    for (int k = 0; k < 90; ++k) acc += x2L[k]*W1[(90+k)*50+t];
    hh[t] = fmaxf(acc, 0.f);
  }
  __syncthreads();
  if (t < 6) {
    float acc = b2[t];
    for (int j = 0; j < 50; ++j) acc += hh[j]*W2[j*6+t];
    out[b*6+t] = acc;
  }
}

// ---------------- launcher ----------------
extern "C" void kernel_launch(void* const* d_in, const int* in_sizes, int n_in,
                              void* d_out, int out_size, void* d_ws, size_t ws_size,
                              hipStream_t stream)
{
  const float* x    = (const float*)d_in[0];
  const float* adj  = (const float*)d_in[1];
  const float* Win  = (const float*)d_in[2];
  const float* W3030= (const float*)d_in[3];
  const float* Wp13 = (const float*)d_in[4];
  // d_in[5]=b30, d_in[6]=b100: cancel through training-mode BN -> unused
  const float* Wfc  = (const float*)d_in[7];
  const float* bfc  = (const float*)d_in[8];
  const float* W1   = (const float*)d_in[9];
  const float* b1   = (const float*)d_in[10];
  const float* W2   = (const float*)d_in[11];
  const float* b2   = (const float*)d_in[12];
  const float* g30  = (const float*)d_in[13];
  const float* be30 = (const float*)d_in[14];
  const float* g100 = (const float*)d_in[15];
  const float* be100= (const float*)d_in[16];
  float* out = (float*)d_out;

  float* wsf = (float*)d_ws;
  float* bL1W = wsf + OF_L1W;  float* bL1B = wsf + OF_L1B;
  float* bL2W = wsf + OF_L2W;  float* bL2B = wsf + OF_L2B;
  float* bL3W = wsf + OF_L3W;  float* bL3B = wsf + OF_L3B;
  float* bktS2a = wsf + OF_S2A;
  float* bktS2b = wsf + OF_S2B;
  float* bktS2c = wsf + OF_S2C;
  float* ellv  = wsf + OF_ELLV;
  unsigned short* ellc = (unsigned short*)(wsf + OF_ELLC);
  int*   rowlen = (int*)(wsf + OF_ROWLEN);
  float* dinvw = wsf + OF_DINVW;
  float* dinvb = wsf + OF_DINVB;
  float* Hw = wsf + OF_HW;
  float* Hb = wsf + OF_HB;      // later: softmax S
  float* Zw = wsf + OF_ZW;
  float* Zb = wsf + OF_ZB;      // later: As = adj@s
  float* x11 = wsf + OF_X11;
  float* x12 = wsf + OF_X12;
  float* x13 = wsf + OF_X13;
  float* s11 = wsf + OF_S11;
  float* s12 = wsf + OF_S12;
  float* pp  = wsf + OF_S11;    // pool partials reuse s11+s12 (dead after fcpool)
  float* acw1 = wsf + OF_AC + 0;
  float* acb1 = wsf + OF_AC + 256;
  float* acw2 = wsf + OF_AC + 512;
  float* acb2 = wsf + OF_AC + 768;
  float* acw3 = wsf + OF_AC + 1024;
  float* acb3 = wsf + OF_AC + 1280;
  float* A2  = wsf + OF_A2;
  float* Z21 = wsf + OF_Z21;
  float* Z22 = wsf + OF_Z22;
  float* Z23 = wsf + OF_Z23;
  float* x21 = wsf + OF_X21;
  float* x22 = wsf + OF_X22;
  float* partmax = wsf + OF_PARTMAX;

  k_build_ell<<<RTOT, 256, 0, stream>>>(adj, x, Win, ellv, ellc, rowlen, dinvw, dinvb, Hw, Hb);

  // level 1
  k_spmm32<true,true><<<512, 256, 0, stream>>>(Hw, Hb, ellv, ellc, rowlen, dinvw, dinvb, Zw, Zb, bL1W, bL1B);
  k_finalize2<<<1, 256, 0, stream>>>(bL1W, 512, 30, g30+0,  be30+0,  acw1, bL1B, 512, 30, g30+90,  be30+90,  acb1, 16384.f);
  k_apply_gemm<8,32><<<1024, 256, 0, stream>>>(Zw, acw1, x11, W3030+0, Hw, dinvw, Zb, acb1, s11, W3030+2*900, Hb, dinvb);

  // level 2
  k_spmm32<true,true><<<512, 256, 0, stream>>>(Hw, Hb, ellv, ellc, rowlen, dinvw, dinvb, Zw, Zb, bL2W, bL2B);
  k_finalize2<<<1, 256, 0, stream>>>(bL2W, 512, 30, g30+30, be30+30, acw2, bL2B, 512, 30, g30+120, be30+120, acb2, 16384.f);
  k_apply_gemm<25,100><<<2112, 256, 0, stream>>>(Zw, acw2, x12, W3030+900, Hw, dinvw, Zb, acb2, s12, Wp13, Hb, dinvb);

  // level 3
  k_spmm32<false,true><<<512, 256, 0, stream>>>(Hw, nullptr, ellv, ellc, rowlen, dinvw, nullptr, Zw, nullptr, bL3W, nullptr);
  k_spmm100<false,true,true,true><<<1600, 256, 0, stream>>>(Hb, ellv, ellc, rowlen, dinvb, Zb, bL3B);
  k_finalize2<<<1, 256, 0, stream>>>(bL3W, 512, 30, g30+60, be30+60, acw3, bL3B, 1600, 100, g100, be100, acb3, 16384.f);

  // pooling assignment (fcpool fuses softmax; writes S into Hb region)
  k_fcpool<<<256, 256, 0, stream>>>(Zw, acw3, Zb, acb3, s11, s12, Wfc, bfc, x13, Hb /* S */);
  k_spmm100<true,false,false,false><<<1600, 256, 0, stream>>>(Hb, ellv, ellc, rowlen, nullptr, Zb /* As */, nullptr);
  k_pool_part<<<64, 256, 0, stream>>>(Hb, x13, Zb, pp);

  // stage 2 (s2pool fuses pool-reduce + A2 normalize + layer1)
  k_s2pool<<<BATCH, 256, 0, stream>>>(pp, W3030+3*900, A2, Z21, bktS2a);
  k_s2layer<<<BATCH, 256, 0, stream>>>(Z21, bktS2a, g30+150, be30+150, x21, W3030+4*900, A2, Z22, bktS2b);
  k_s2layer<<<BATCH, 256, 0, stream>>>(Z22, bktS2b, g30+180, be30+180, x22, W3030+5*900, A2, Z23, bktS2c);

  // readout (maxmlp fuses bktS2c finalize + max2 + MLP)
  k_max1<<<64, 256, 0, stream>>>(x11, x12, x13, partmax);
  k_maxmlp<<<BATCH, 128, 0, stream>>>(partmax, x21, x22, Z23, bktS2c, g30+210, be30+210, W1, b1, W2, b2, out);
}

// Round 5
// 765.398 us; speedup vs baseline: 2.2862x; 2.2862x over previous
//
#include <hip/hip_runtime.h>
#include <cstdint>
#include <cstddef>

#define BATCH 8
#define NN 2048
#define RTOT 16384   // BATCH*NN
#define KCL 100
#define CAP 176      // ELL row capacity (mean nnz/row ~102, sigma ~10; 7.5 sigma headroom)

// ---------------- workspace layout (offsets in floats) ----------------
static constexpr size_t OF_L1W   = 0;             // 512*30*2
static constexpr size_t OF_L1B   = 30720;
static constexpr size_t OF_L2W   = 61440;
static constexpr size_t OF_L2B   = 92160;
static constexpr size_t OF_L3W   = 122880;
static constexpr size_t OF_L3B   = 153600;        // 1600*100*2 = 320000
static constexpr size_t OF_S2A   = 473600;        // 8*30*2
static constexpr size_t OF_S2B   = 474080;
static constexpr size_t OF_S2C   = 474560;
static constexpr size_t OF_AC    = 475136;        // 9 slots * 256
static constexpr size_t OF_ELLV  = 477440;                    // 16384*176
static constexpr size_t OF_ELLC  = OF_ELLV + 2883584;         // u16 x 16384*176 = 1441792 floats
static constexpr size_t OF_ROWLEN= OF_ELLC + 1441792;
static constexpr size_t OF_DINVW = OF_ROWLEN + 16384;
static constexpr size_t OF_DINVB = OF_DINVW + 16384;
static constexpr size_t OF_HW    = OF_DINVB + 16384;          // 16384*32 (stride 32)
static constexpr size_t OF_HB    = OF_HW + 524288;            // 16384*100 max (reused as softmax S)
static constexpr size_t OF_ZW    = OF_HB + 1638400;           // 16384*32
static constexpr size_t OF_ZB    = OF_ZW + 524288;            // 16384*100 max (reused as As)
static constexpr size_t OF_X11   = OF_ZB + 1638400;           // stride 32
static constexpr size_t OF_X12   = OF_X11 + 524288;
static constexpr size_t OF_X13   = OF_X12 + 524288;
static constexpr size_t OF_S11   = OF_X13 + 524288;           // stride 32; s11+s12 reused as pool partials
static constexpr size_t OF_S12   = OF_S11 + 524288;
static constexpr size_t OF_A2    = OF_S12 + 524288;           // 8*100*100
static constexpr size_t OF_Z21   = OF_A2 + 80000;             // stage-2 stride 30
static constexpr size_t OF_Z22   = OF_Z21 + 24000;
static constexpr size_t OF_Z23   = OF_Z22 + 24000;
static constexpr size_t OF_X21   = OF_Z23 + 24000;
static constexpr size_t OF_X22   = OF_X21 + 24000;
static constexpr size_t OF_PARTMAX = OF_X22 + 24000;          // 8*8*90

#define FMA4(acc, s, h) { acc.x += (s)*(h).x; acc.y += (s)*(h).y; acc.z += (s)*(h).z; acc.w += (s)*(h).w; }

// ---------------- kernels ----------------

// One pass over adj: build ELL (scan-based compaction, no serialized LDS atomics),
// weighted+binary degree, FUSED H1 = x @ W_in * dinv (stride-32 out).
__global__ __launch_bounds__(256) void k_build_ell(
    const float* __restrict__ adj, const float* __restrict__ x,
    const float* __restrict__ Win, float* __restrict__ ellv,
    unsigned short* __restrict__ ellc, int* __restrict__ rowlen,
    float* __restrict__ dinvw, float* __restrict__ dinvb,
    float* __restrict__ Hw, float* __restrict__ Hb)
{
  int r = blockIdx.x;
  const float* row = adj + (size_t)r * NN;
  int t = threadIdx.x, lane = t & 63, wv = t >> 6;
  __shared__ int wcnt[4];
  __shared__ float wsumA[4];
  __shared__ float dsh[2];
  float4 a = ((const float4*)row)[t];
  float4 b = ((const float4*)row)[256 + t];
  float vals[8] = {a.x, a.y, a.z, a.w, b.x, b.y, b.z, b.w};
  int cbase0 = t*4, cbase1 = 1024 + t*4;
  int cnt = 0; float sum = 0.f;
#pragma unroll
  for (int k = 0; k < 8; ++k) { sum += vals[k]; cnt += (vals[k] != 0.f) ? 1 : 0; }
  // 64-lane inclusive prefix scan of cnt
  int pre = cnt;
#pragma unroll
  for (int o = 1; o < 64; o <<= 1) { int n = __shfl_up(pre, o); if (lane >= o) pre += n; }
  int excl = pre - cnt;
  int wtot = __shfl(pre, 63);
  // wave sum of weighted row-sum
#pragma unroll
  for (int o = 32; o; o >>= 1) sum += __shfl_down(sum, o);
  if (lane == 0) { wcnt[wv] = wtot; wsumA[wv] = sum; }
  __syncthreads();
  int base = 0;
  for (int w = 0; w < wv; ++w) base += wcnt[w];
  int p = base + excl;
  size_t rb = (size_t)r * CAP;
#pragma unroll
  for (int k = 0; k < 8; ++k) {
    float v = vals[k];
    if (v != 0.f && p < CAP) {
      ellv[rb + p] = v;
      ellc[rb + p] = (unsigned short)((k < 4) ? (cbase0 + k) : (cbase1 + (k - 4)));
      ++p;
    }
  }
  if (t == 0) {
    int tot = wcnt[0] + wcnt[1] + wcnt[2] + wcnt[3];
    float ws = wsumA[0] + wsumA[1] + wsumA[2] + wsumA[3];
    int nnz = tot < CAP ? tot : CAP;
    int n = nnz;
    while ((n & 3) && n < CAP) { ellv[rb + n] = 0.f; ellc[rb + n] = 0; ++n; }
    rowlen[r] = n;
    float dw = rsqrtf(ws + 1.f), db = rsqrtf((float)nnz + 1.f);
    dinvw[r] = dw; dinvb[r] = db;
    dsh[0] = dw; dsh[1] = db;
  }
  __syncthreads();
  if (t < 64) {  // fused H1 for this row
    int c = t & 31, side = t >> 5;
    float v = 0.f;
    if (c < 30) {
      float x0 = x[r*3], x1 = x[r*3+1], x2 = x[r*3+2];
      const float* W = Win + side*90;
      v = (x0*W[c] + x1*W[30+c] + x2*W[60+c]) * dsh[side];
    }
    (side ? Hb : Hw)[(size_t)r*32 + c] = v;
  }
}

// Fused ELL SpMM pair (stride-32, float4/thread) with optional per-block BN-stat buckets.
template<bool PAIR, bool STATS>
__global__ __launch_bounds__(256) void k_spmm32(
    const float* __restrict__ Hw, const float* __restrict__ Hb,
    const float* __restrict__ ellv, const unsigned short* __restrict__ ellc,
    const int* __restrict__ rowlen, const float* __restrict__ dinvw,
    const float* __restrict__ dinvb, float* __restrict__ Zw, float* __restrict__ Zb,
    float* __restrict__ bktW, float* __restrict__ bktB)
{
  __shared__ float zs[1024];
  int t = threadIdx.x;
  int gid = blockIdx.x * 256 + t;   // RTOT*8
  int row = gid >> 3, q = gid & 7;
  int len = rowlen[row];
  const float4* ev = (const float4*)(ellv + (size_t)row * CAP);
  const uint2*  ec = (const uint2*) (ellc + (size_t)row * CAP);
  const float4* HW4 = (const float4*)Hw + (size_t)(row >> 11) * (NN*8);
  const float4* HB4 = (const float4*)Hb + (size_t)(row >> 11) * (NN*8);
  float4 aw = {0,0,0,0}, ab = {0,0,0,0};
  int nit = len >> 2;
  for (int i = 0; i < nit; ++i) {
    float4 v = ev[i];
    uint2 cc = ec[i];
    int c0 = cc.x & 0xffff, c1 = cc.x >> 16, c2 = cc.y & 0xffff, c3 = cc.y >> 16;
    float4 h0 = HW4[c0*8+q], h1 = HW4[c1*8+q], h2 = HW4[c2*8+q], h3 = HW4[c3*8+q];
    FMA4(aw, v.x, h0); FMA4(aw, v.y, h1); FMA4(aw, v.z, h2); FMA4(aw, v.w, h3);
    if (PAIR) {
      float4 g0 = HB4[c0*8+q], g1 = HB4[c1*8+q], g2 = HB4[c2*8+q], g3 = HB4[c3*8+q];
      float b0 = v.x>0.f?1.f:0.f, b1 = v.y>0.f?1.f:0.f, b2 = v.z>0.f?1.f:0.f, b3 = v.w>0.f?1.f:0.f;
      FMA4(ab, b0, g0); FMA4(ab, b1, g1); FMA4(ab, b2, g2); FMA4(ab, b3, g3);
    }
  }
  int rl = (row & (NN-1));
  float4 hs = HW4[rl*8+q];
  aw.x += hs.x; aw.y += hs.y; aw.z += hs.z; aw.w += hs.w;
  float dw = dinvw[row];
  float4 ow = {dw*aw.x, dw*aw.y, dw*aw.z, dw*aw.w};
  ((float4*)Zw)[(size_t)row*8+q] = ow;
  float4 ob;
  if (PAIR) {
    float4 gs = HB4[rl*8+q];
    ab.x += gs.x; ab.y += gs.y; ab.z += gs.z; ab.w += gs.w;
    float db = dinvb[row];
    ob.x = db*ab.x; ob.y = db*ab.y; ob.z = db*ab.z; ob.w = db*ab.w;
    ((float4*)Zb)[(size_t)row*8+q] = ob;
  }
  if (STATS) {
    ((float4*)zs)[t] = ow;   // zs laid out [32 rows][32 ch]
    __syncthreads();
    if (t < 30) {
      float s1 = 0.f, s2 = 0.f;
      for (int r = 0; r < 32; ++r) { float v = zs[r*32 + t]; s1 += v; s2 += v*v; }
      bktW[((size_t)blockIdx.x*30 + t)*2]   = s1;
      bktW[((size_t)blockIdx.x*30 + t)*2+1] = s2;
    }
    if (PAIR) {
      __syncthreads();
      ((float4*)zs)[t] = ob;
      __syncthreads();
      if (t < 30) {
        float s1 = 0.f, s2 = 0.f;
        for (int r = 0; r < 32; ++r) { float v = zs[r*32 + t]; s1 += v; s2 += v*v; }
        bktB[((size_t)blockIdx.x*30 + t)*2]   = s1;
        bktB[((size_t)blockIdx.x*30 + t)*2+1] = s2;
      }
    }
  }
}

// ELL SpMM, C=100 (25 float4/row) with optional LDS-reduced per-block BN buckets.
template<bool WEIGHTED, bool SELFLOOP, bool SCALED, bool STATS>
__global__ __launch_bounds__(256) void k_spmm100(
    const float* __restrict__ H, const float* __restrict__ ellv,
    const unsigned short* __restrict__ ellc, const int* __restrict__ rowlen,
    const float* __restrict__ scale, float* __restrict__ Z, float* __restrict__ bkt)
{
  __shared__ float st[200];
  int t = threadIdx.x;
  if (STATS) { for (int i = t; i < 200; i += 256) st[i] = 0.f; __syncthreads(); }
  int gid = blockIdx.x * 256 + t;   // RTOT*25
  int row = gid / 25, q = gid - row*25;
  int len = rowlen[row];
  const float4* ev = (const float4*)(ellv + (size_t)row * CAP);
  const uint2*  ec = (const uint2*) (ellc + (size_t)row * CAP);
  const float4* H4 = (const float4*)H + (size_t)(row >> 11) * (NN*25);
  float4 acc = {0,0,0,0};
  int nit = len >> 2;
  for (int i = 0; i < nit; ++i) {
    float4 v = ev[i];
    uint2 cc = ec[i];
    int c0 = cc.x & 0xffff, c1 = cc.x >> 16, c2 = cc.y & 0xffff, c3 = cc.y >> 16;
    float4 h0 = H4[c0*25+q], h1 = H4[c1*25+q], h2 = H4[c2*25+q], h3 = H4[c3*25+q];
    float w0 = WEIGHTED ? v.x : (v.x>0.f?1.f:0.f);
    float w1 = WEIGHTED ? v.y : (v.y>0.f?1.f:0.f);
    float w2 = WEIGHTED ? v.z : (v.z>0.f?1.f:0.f);
    float w3 = WEIGHTED ? v.w : (v.w>0.f?1.f:0.f);
    FMA4(acc, w0, h0); FMA4(acc, w1, h1); FMA4(acc, w2, h2); FMA4(acc, w3, h3);
  }
  if (SELFLOOP) {
    float4 hs = H4[(row & (NN-1))*25+q];
    acc.x += hs.x; acc.y += hs.y; acc.z += hs.z; acc.w += hs.w;
  }
  float s = SCALED ? scale[row] : 1.f;
  float4 o = {s*acc.x, s*acc.y, s*acc.z, s*acc.w};
  ((float4*)Z)[(size_t)row*25+q] = o;
  if (STATS) {
    int c0 = q*4;
    atomicAdd(&st[(c0+0)*2], o.x); atomicAdd(&st[(c0+0)*2+1], o.x*o.x);
    atomicAdd(&st[(c0+1)*2], o.y); atomicAdd(&st[(c0+1)*2+1], o.y*o.y);
    atomicAdd(&st[(c0+2)*2], o.z); atomicAdd(&st[(c0+2)*2+1], o.z*o.z);
    atomicAdd(&st[(c0+3)*2], o.w); atomicAdd(&st[(c0+3)*2+1], o.w*o.w);
    __syncthreads();
    for (int i = t; i < 200; i += 256) bkt[(size_t)blockIdx.x*200 + i] = st[i];
  }
}

// PARALLEL bucket finalize: one block per channel (cA+cB blocks x 256 threads).
// Thread t covers buckets t, t+256, ... (independent float2 loads, latency hidden
// by TLP across 4 waves x many CUs); LDS tree-reduce; thread 0 writes scale/shift.
__global__ __launch_bounds__(256) void k_finalize_par(
    const float* __restrict__ bA, int nA, int cA, const float* __restrict__ gA,
    const float* __restrict__ beA, float* __restrict__ outA,
    const float* __restrict__ bB, int nB, int cB, const float* __restrict__ gB,
    const float* __restrict__ beB, float* __restrict__ outB, float count)
{
  __shared__ float r1[256], r2[256];
  int c = blockIdx.x, t = threadIdx.x;
  const float* src; int n, C, cc;
  float* dst; const float* g; const float* be; int cap;
  if (c < cA) { src = bA; n = nA; C = cA; cc = c; dst = outA; g = gA; be = beA; cap = cA; }
  else { src = bB; n = nB; C = cB; cc = c - cA; dst = outB; g = gB; be = beB; cap = cB; }
  float s1 = 0.f, s2 = 0.f;
  for (int b = t; b < n; b += 256) {
    float2 v = *(const float2*)(src + ((size_t)b*C + cc)*2);
    s1 += v.x; s2 += v.y;
  }
  r1[t] = s1; r2[t] = s2;
  __syncthreads();
  for (int o = 128; o > 0; o >>= 1) {
    if (t < o) { r1[t] += r1[t+o]; r2[t] += r2[t+o]; }
    __syncthreads();
  }
  if (t == 0) {
    float mean = r1[0]/count, var = r2[0]/count - mean*mean, inv = rsqrtf(var + 1e-5f);
    float aa = g[cc]*inv; dst[cc] = aa; dst[cap + cc] = be[cc] - mean*aa;
  }
}

// apply BN -> store x/s (stride 32) -> next-layer weight GEMM pre-scaled by dinv.
template<int NGB, int OSTRIDEB>
__global__ __launch_bounds__(256) void k_apply_gemm(
    const float* __restrict__ Zw, const float* __restrict__ acW,
    float* __restrict__ xst, const float* __restrict__ Ww,
    float* __restrict__ Hwo, const float* __restrict__ dinvw,
    const float* __restrict__ Zb, const float* __restrict__ acB,
    float* __restrict__ sst, const float* __restrict__ Wb,
    float* __restrict__ Hbo, const float* __restrict__ dinvb)
{
  constexpr int NG = 8 + NGB;
  __shared__ float WwL[30*32];
  __shared__ float WbL[30*OSTRIDEB];
  __shared__ float awL[60], abL[60];
  int t = threadIdx.x;
  for (int idx = t; idx < 30*32; idx += 256) {
    int k = idx >> 5, c = idx & 31;
    WwL[idx] = (c < 30) ? Ww[k*30 + c] : 0.f;
  }
  if (OSTRIDEB == 32) {
    for (int idx = t; idx < 30*32; idx += 256) {
      int k = idx >> 5, c = idx & 31;
      WbL[idx] = (c < 30) ? Wb[k*30 + c] : 0.f;
    }
  } else {
    for (int idx = t; idx < 30*OSTRIDEB; idx += 256) WbL[idx] = Wb[idx];
  }
  if (t < 60) { awL[t] = acW[t]; abL[t] = acB[t]; }
  __syncthreads();
  int gid = blockIdx.x * 256 + t;
  int row = gid / NG, g = gid % NG;
  if (g < 8) {
    const float4* Z4 = (const float4*)Zw + (size_t)row*8;
    float4 z4[8];
#pragma unroll
    for (int u = 0; u < 8; ++u) z4[u] = Z4[u];
    const float* z = (const float*)z4;
    float4 xv;
    int ch = 4*g;
    xv.x = (ch+0 < 30) ? awL[ch+0]*z[ch+0] + awL[30+ch+0] : 0.f;
    xv.y = (ch+1 < 30) ? awL[ch+1]*z[ch+1] + awL[30+ch+1] : 0.f;
    xv.z = (ch+2 < 30) ? awL[ch+2]*z[ch+2] + awL[30+ch+2] : 0.f;
    xv.w = (ch+3 < 30) ? awL[ch+3]*z[ch+3] + awL[30+ch+3] : 0.f;
    ((float4*)xst)[(size_t)row*8+g] = xv;
    float4 o = {0,0,0,0};
#pragma unroll
    for (int k = 0; k < 30; ++k) {
      float xk = awL[k]*z[k] + awL[30+k];
      float4 w = *(const float4*)(WwL + k*32 + 4*g);
      FMA4(o, xk, w);
    }
    float d = dinvw[row];
    float4 ov = {d*o.x, d*o.y, d*o.z, d*o.w};
    ((float4*)Hwo)[(size_t)row*8+g] = ov;
  } else {
    int gb = g - 8;
    const float4* Z4 = (const float4*)Zb + (size_t)row*8;
    float4 z4[8];
#pragma unroll
    for (int u = 0; u < 8; ++u) z4[u] = Z4[u];
    const float* z = (const float*)z4;
    if (gb < 8) {
      int ch = 4*gb;
      float4 sv;
      sv.x = (ch+0 < 30) ? abL[ch+0]*z[ch+0] + abL[30+ch+0] : 0.f;
      sv.y = (ch+1 < 30) ? abL[ch+1]*z[ch+1] + abL[30+ch+1] : 0.f;
      sv.z = (ch+2 < 30) ? abL[ch+2]*z[ch+2] + abL[30+ch+2] : 0.f;
      sv.w = (ch+3 < 30) ? abL[ch+3]*z[ch+3] + abL[30+ch+3] : 0.f;
      ((float4*)sst)[(size_t)row*8+gb] = sv;
    }
    float4 o = {0,0,0,0};
#pragma unroll
    for (int k = 0; k < 30; ++k) {
      float sk = abL[k]*z[k] + abL[30+k];
      float4 w = *(const float4*)(WbL + k*OSTRIDEB + 4*gb);
      FMA4(o, sk, w);
    }
    float d = dinvb[row];
    float4 ov = {d*o.x, d*o.y, d*o.z, d*o.w};
    ((float4*)Hbo)[(size_t)row*(OSTRIDEB/4) + gb] = ov;
  }
}

// BN(Z3w)->x13 (stride 32); s13=BN(Z3b); s1 = [s11|s12|s13]@Wfc + bfc; FUSED softmax -> S
__global__ __launch_bounds__(256) void k_fcpool(
    const float* __restrict__ Zw3, const float* __restrict__ acW3,
    const float* __restrict__ Zb3, const float* __restrict__ acB3,
    const float* __restrict__ s11, const float* __restrict__ s12,
    const float* __restrict__ Wfc, const float* __restrict__ bfc,
    float* __restrict__ x13, float* __restrict__ S)
{
  __shared__ float shm[14240];   // feat 64x160 = 10240 | Wl 40x100 = 4000
  float* feat = shm;
  float* Wl = shm + 10240;
  int t = threadIdx.x;
  int g0 = blockIdx.x * 64;
  for (int idx = t; idx < 64*160; idx += 256) {
    int l = idx / 160, c = idx % 160;
    int g = g0 + l;
    float v;
    if (c < 30) v = s11[(size_t)g*32 + c];
    else if (c < 60) v = s12[(size_t)g*32 + (c-30)];
    else { int k = c - 60; v = acB3[k]*Zb3[(size_t)g*100 + k] + acB3[100 + k]; }
    feat[l*160 + c] = v;
  }
  for (int idx = t; idx < 64*32; idx += 256) {
    int l = idx >> 5, c = idx & 31;
    int g = g0 + l;
    x13[(size_t)g*32+c] = (c < 30) ? acW3[c]*Zw3[(size_t)g*32+c] + acW3[30+c] : 0.f;
  }
  int np = t >> 3, kg = t & 7;
  int n0 = np*2, n1 = np*2 + 1;
  int kbase = kg*12 + (kg < 4 ? kg : 4);
  int klen  = kg < 4 ? 13 : 12;
  float a0[13], a1[13];
#pragma unroll
  for (int j = 0; j < 13; ++j) { a0[j] = 0.f; a1[j] = 0.f; }
  for (int ch = 0; ch < 4; ++ch) {
    __syncthreads();
    for (int idx = t; idx < 4000; idx += 256) {
      int r = idx/100, j = idx%100;
      Wl[r*100 + j] = Wfc[(ch*40 + r)*100 + j];
    }
    __syncthreads();
    for (int kk = 0; kk < 40; ++kk) {
      float f0 = feat[n0*160 + ch*40+kk];
      float f1 = feat[n1*160 + ch*40+kk];
#pragma unroll
      for (int j = 0; j < 13; ++j) {
        if (j < klen) {
          float w = Wl[kk*100 + kbase + j];
          a0[j] += f0*w; a1[j] += f1*w;
        }
      }
    }
  }
  __syncthreads();
  // reuse shm[0..6399] as sRow[64][100]
  float* sRow = shm;
  for (int j = 0; j < klen; ++j) {
    int k = kbase + j;
    sRow[n0*100 + k] = a0[j] + bfc[k];
    sRow[n1*100 + k] = a1[j] + bfc[k];
  }
  __syncthreads();
  // softmax: 4 threads per node (25 entries each)
  int n = t >> 2, part = t & 3;
  int i0 = part*25;
  float m = -3.4e38f;
  for (int i = 0; i < 25; ++i) m = fmaxf(m, sRow[n*100 + i0 + i]);
  m = fmaxf(m, __shfl_xor(m, 1));
  m = fmaxf(m, __shfl_xor(m, 2));
  float ev[25]; float s = 0.f;
  for (int i = 0; i < 25; ++i) { float e = __expf(sRow[n*100 + i0 + i] - m); ev[i] = e; s += e; }
  s += __shfl_xor(s, 1);
  s += __shfl_xor(s, 2);
  float rinv = 1.f / s;
  for (int i = 0; i < 25; ++i) S[(size_t)(g0+n)*100 + i0 + i] = ev[i] * rinv;
}

// pooled partials: pp[blk][k][d] over this block's 256 nodes; NO atomics
__global__ __launch_bounds__(256) void k_pool_part(
    const float* __restrict__ S, const float* __restrict__ x13,
    const float* __restrict__ As, float* __restrict__ pp)
{
  __shared__ float sL[64][100];
  __shared__ float xL[64][132];
  int t = threadIdx.x;
  int b = blockIdx.x >> 3, chunk = blockIdx.x & 7;
  int g00 = b * 2048 + chunk * 256;
  int kt = t/10, dt = t%10;
  int k0 = kt*4, d0 = dt*13;
  float acc[4][13];
#pragma unroll
  for (int a = 0; a < 4; ++a)
#pragma unroll
    for (int j = 0; j < 13; ++j) acc[a][j] = 0.f;
  for (int tile = 0; tile < 4; ++tile) {
    int g0 = g00 + tile*64;
    __syncthreads();
    for (int idx = t; idx < 64*100; idx += 256) {
      int l = idx/100, k = idx%100;
      sL[l][k] = S[(size_t)(g0+l)*100 + k];
    }
    for (int idx = t; idx < 64*130; idx += 256) {
      int l = idx/130, d = idx%130;
      xL[l][d] = d < 30 ? x13[(size_t)(g0+l)*32 + d] : As[(size_t)(g0+l)*100 + (d-30)];
    }
    __syncthreads();
    if (t < 250) {
      for (int kk = 0; kk < 64; ++kk) {
        float sv[4];
#pragma unroll
        for (int a = 0; a < 4; ++a) sv[a] = sL[kk][k0+a];
#pragma unroll
        for (int j = 0; j < 13; ++j) {
          float xv = xL[kk][d0+j];
#pragma unroll
          for (int a = 0; a < 4; ++a) acc[a][j] += sv[a]*xv;
        }
      }
    }
  }
  if (t < 250) {
    float* dst = pp + (size_t)blockIdx.x * 13000;
    for (int a = 0; a < 4; ++a)
      for (int j = 0; j < 13; ++j)
        dst[(k0+a)*130 + (d0+j)] = acc[a][j];
  }
}

// stage-2 layer 1 FUSED with pool-reduce + A2 normalize. One block per batch.
__global__ __launch_bounds__(256) void k_s2pool(
    const float* __restrict__ pp, const float* __restrict__ Wm,
    float* __restrict__ A2, float* __restrict__ Zout, float* __restrict__ bkt)
{
  __shared__ float Ah[10000];
  __shared__ float Xl[3000];
  __shared__ float Tl[3000];
  __shared__ float dl[100];
  __shared__ float st1[30], st2[30];
  int b = blockIdx.x, t = threadIdx.x;
  if (t < 30) { st1[t] = 0.f; st2[t] = 0.f; }
  for (int idx = t; idx < 13000; idx += 256) {
    float s = 0.f;
    for (int ch = 0; ch < 8; ++ch) s += pp[(size_t)(b*8 + ch)*13000 + idx];
    int k = idx/130, d = idx%130;
    if (d < 30) Xl[k*30 + d] = s; else Ah[k*100 + (d-30)] = s;
  }
  __syncthreads();
  if (t < 100 && Ah[t*101] == 0.f) Ah[t*101] = 1.f;
  __syncthreads();
  if (t < 100) {
    float s = 0.f;
    for (int j = 0; j < 100; ++j) s += Ah[t*100 + j];
    dl[t] = s > 0.f ? rsqrtf(s) : 0.f;
  }
  __syncthreads();
  for (int idx = t; idx < 10000; idx += 256) {
    int i = idx/100, j = idx%100;
    float v = dl[i]*dl[j]*Ah[idx];
    Ah[idx] = v;
    A2[(size_t)b*10000 + idx] = v;
  }
  __syncthreads();
  for (int idx = t; idx < 3000; idx += 256) {
    int i = idx/30, c = idx%30;
    float acc = 0.f;
    for (int k = 0; k < 30; ++k) acc += Xl[i*30+k]*Wm[k*30+c];
    Tl[idx] = acc;
  }
  __syncthreads();
  for (int idx = t; idx < 3000; idx += 256) {
    int i = idx/30, c = idx%30;
    float acc = 0.f;
    for (int j = 0; j < 100; ++j) acc += Ah[i*100+j]*Tl[j*30+c];
    Zout[(size_t)b*3000 + idx] = acc;
    atomicAdd(&st1[c], acc);
    atomicAdd(&st2[c], acc*acc);
  }
  __syncthreads();
  if (t < 30) {
    bkt[((size_t)b*30 + t)*2]   = st1[t];
    bkt[((size_t)b*30 + t)*2+1] = st2[t];
  }
}

// stage-2 layers 2,3: inline BN-finalize of prev bucket, then layer + stats
__global__ __launch_bounds__(256) void k_s2layer(
    const float* __restrict__ Zprev, const float* __restrict__ prevBkt,
    const float* __restrict__ gamma, const float* __restrict__ beta,
    float* __restrict__ xst, const float* __restrict__ Wm,
    const float* __restrict__ A2, float* __restrict__ Zout, float* __restrict__ bkt)
{
  __shared__ float Xl[3000];
  __shared__ float Tl[3000];
  __shared__ float Al[10000];
  __shared__ float acL[60];
  __shared__ float st1[30], st2[30];
  int b = blockIdx.x, t = threadIdx.x;
  if (t < 30) {
    float s1 = 0.f, s2 = 0.f;
    for (int q = 0; q < 8; ++q) {
      s1 += prevBkt[((size_t)q*30 + t)*2];
      s2 += prevBkt[((size_t)q*30 + t)*2+1];
    }
    float mean = s1/800.f, var = s2/800.f - mean*mean, inv = rsqrtf(var + 1e-5f);
    float aa = gamma[t]*inv; acL[t] = aa; acL[30+t] = beta[t] - mean*aa;
    st1[t] = 0.f; st2[t] = 0.f;
  }
  __syncthreads();
  for (int idx = t; idx < 3000; idx += 256) {
    int c = idx % 30;
    float v = acL[c]*Zprev[(size_t)b*3000 + idx] + acL[30+c];
    xst[(size_t)b*3000 + idx] = v;
    Xl[idx] = v;
  }
  for (int idx = t; idx < 10000; idx += 256) Al[idx] = A2[(size_t)b*10000 + idx];
  __syncthreads();
  for (int idx = t; idx < 3000; idx += 256) {
    int i = idx/30, c = idx%30;
    float acc = 0.f;
    for (int k = 0; k < 30; ++k) acc += Xl[i*30+k]*Wm[k*30+c];
    Tl[idx] = acc;
  }
  __syncthreads();
  for (int idx = t; idx < 3000; idx += 256) {
    int i = idx/30, c = idx%30;
    float acc = 0.f;
    for (int j = 0; j < 100; ++j) acc += Al[i*100+j]*Tl[j*30+c];
    Zout[(size_t)b*3000 + idx] = acc;
    atomicAdd(&st1[c], acc);
    atomicAdd(&st2[c], acc*acc);
  }
  __syncthreads();
  if (t < 30) {
    bkt[((size_t)b*30 + t)*2]   = st1[t];
    bkt[((size_t)b*30 + t)*2+1] = st2[t];
  }
}

// stage-1 per-segment column max of [x11|x12|x13] (stride 32, coalesced)
__global__ __launch_bounds__(256) void k_max1(
    const float* __restrict__ x11, const float* __restrict__ x12,
    const float* __restrict__ x13, float* __restrict__ pm)
{
  __shared__ float red[256];
  int t = threadIdx.x, c = t & 31, rg = t >> 5;
  int b = blockIdx.x >> 3, seg = blockIdx.x & 7;
  int r0 = b*2048 + seg*256;
  const float* srcs[3] = {x11, x12, x13};
  for (int a = 0; a < 3; ++a) {
    const float* p = srcs[a] + (size_t)(r0+rg)*32 + c;
    float m = -3.4e38f;
    for (int it = 0; it < 32; ++it) m = fmaxf(m, p[it*256]);
    red[t] = m;
    __syncthreads();
    if (t < 30) {
      float mm = red[t];
      for (int g = 1; g < 8; ++g) mm = fmaxf(mm, red[g*32+t]);
      pm[(size_t)(b*8+seg)*90 + a*30 + t] = mm;
    }
    __syncthreads();
  }
}

// FUSED: finalize bktS2c -> x1out/x2out maxes -> MLP -> out. One block per batch.
__global__ __launch_bounds__(128) void k_maxmlp(
    const float* __restrict__ pm, const float* __restrict__ x21,
    const float* __restrict__ x22, const float* __restrict__ Z23,
    const float* __restrict__ bktS2c, const float* __restrict__ gamma,
    const float* __restrict__ beta,
    const float* __restrict__ W1, const float* __restrict__ b1,
    const float* __restrict__ W2, const float* __restrict__ b2,
    float* __restrict__ out)
{
  __shared__ float ac[60], x1L[90], x2L[90], hh[50];
  int b = blockIdx.x, t = threadIdx.x;
  if (t < 30) {
    float s1 = 0.f, s2 = 0.f;
    for (int q = 0; q < 8; ++q) {
      s1 += bktS2c[((size_t)q*30 + t)*2];
      s2 += bktS2c[((size_t)q*30 + t)*2+1];
    }
    float mean = s1/800.f, var = s2/800.f - mean*mean, inv = rsqrtf(var + 1e-5f);
    float aa = gamma[t]*inv; ac[t] = aa; ac[30+t] = beta[t] - mean*aa;
  }
  __syncthreads();
  if (t < 90) {
    float m = -3.4e38f;
    for (int s = 0; s < 8; ++s) m = fmaxf(m, pm[(size_t)(b*8+s)*90 + t]);
    x1L[t] = m;
    float m2 = -3.4e38f;
    int cc = t % 30;
    for (int i = 0; i < 100; ++i) {
      float v;
      if (t < 30) v = x21[(size_t)b*3000 + i*30 + cc];
      else if (t < 60) v = x22[(size_t)b*3000 + i*30 + cc];
      else v = ac[cc]*Z23[(size_t)b*3000 + i*30 + cc] + ac[30+cc];
      m2 = fmaxf(m2, v);
    }
    x2L[t] = m2;
  }
  __syncthreads();
  if (t < 50) {
    float acc = b1[t];
    for (int k = 0; k < 90; ++k) acc += x1L[k]*W1[k*50+t];
    for (int k = 0; k < 90; ++k) acc += x2L[k]*W1[(90+k)*50+t];
    hh[t] = fmaxf(acc, 0.f);
  }
  __syncthreads();
  if (t < 6) {
    float acc = b2[t];
    for (int j = 0; j < 50; ++j) acc += hh[j]*W2[j*6+t];
    out[b*6+t] = acc;
  }
}

// ---------------- launcher ----------------
extern "C" void kernel_launch(void* const* d_in, const int* in_sizes, int n_in,
                              void* d_out, int out_size, void* d_ws, size_t ws_size,
                              hipStream_t stream)
{
  const float* x    = (const float*)d_in[0];
  const float* adj  = (const float*)d_in[1];
  const float* Win  = (const float*)d_in[2];
  const float* W3030= (const float*)d_in[3];
  const float* Wp13 = (const float*)d_in[4];
  // d_in[5]=b30, d_in[6]=b100: cancel through training-mode BN -> unused
  const float* Wfc  = (const float*)d_in[7];
  const float* bfc  = (const float*)d_in[8];
  const float* W1   = (const float*)d_in[9];
  const float* b1   = (const float*)d_in[10];
  const float* W2   = (const float*)d_in[11];
  const float* b2   = (const float*)d_in[12];
  const float* g30  = (const float*)d_in[13];
  const float* be30 = (const float*)d_in[14];
  const float* g100 = (const float*)d_in[15];
  const float* be100= (const float*)d_in[16];
  float* out = (float*)d_out;

  float* wsf = (float*)d_ws;
  float* bL1W = wsf + OF_L1W;  float* bL1B = wsf + OF_L1B;
  float* bL2W = wsf + OF_L2W;  float* bL2B = wsf + OF_L2B;
  float* bL3W = wsf + OF_L3W;  float* bL3B = wsf + OF_L3B;
  float* bktS2a = wsf + OF_S2A;
  float* bktS2b = wsf + OF_S2B;
  float* bktS2c = wsf + OF_S2C;
  float* ellv  = wsf + OF_ELLV;
  unsigned short* ellc = (unsigned short*)(wsf + OF_ELLC);
  int*   rowlen = (int*)(wsf + OF_ROWLEN);
  float* dinvw = wsf + OF_DINVW;
  float* dinvb = wsf + OF_DINVB;
  float* Hw = wsf + OF_HW;
  float* Hb = wsf + OF_HB;      // later: softmax S
  float* Zw = wsf + OF_ZW;
  float* Zb = wsf + OF_ZB;      // later: As = adj@s
  float* x11 = wsf + OF_X11;
  float* x12 = wsf + OF_X12;
  float* x13 = wsf + OF_X13;
  float* s11 = wsf + OF_S11;
  float* s12 = wsf + OF_S12;
  float* pp  = wsf + OF_S11;    // pool partials reuse s11+s12 (dead after fcpool)
  float* acw1 = wsf + OF_AC + 0;
  float* acb1 = wsf + OF_AC + 256;
  float* acw2 = wsf + OF_AC + 512;
  float* acb2 = wsf + OF_AC + 768;
  float* acw3 = wsf + OF_AC + 1024;
  float* acb3 = wsf + OF_AC + 1280;
  float* A2  = wsf + OF_A2;
  float* Z21 = wsf + OF_Z21;
  float* Z22 = wsf + OF_Z22;
  float* Z23 = wsf + OF_Z23;
  float* x21 = wsf + OF_X21;
  float* x22 = wsf + OF_X22;
  float* partmax = wsf + OF_PARTMAX;

  k_build_ell<<<RTOT, 256, 0, stream>>>(adj, x, Win, ellv, ellc, rowlen, dinvw, dinvb, Hw, Hb);

  // level 1
  k_spmm32<true,true><<<512, 256, 0, stream>>>(Hw, Hb, ellv, ellc, rowlen, dinvw, dinvb, Zw, Zb, bL1W, bL1B);
  k_finalize_par<<<60, 256, 0, stream>>>(bL1W, 512, 30, g30+0,  be30+0,  acw1, bL1B, 512, 30, g30+90,  be30+90,  acb1, 16384.f);
  k_apply_gemm<8,32><<<1024, 256, 0, stream>>>(Zw, acw1, x11, W3030+0, Hw, dinvw, Zb, acb1, s11, W3030+2*900, Hb, dinvb);

  // level 2
  k_spmm32<true,true><<<512, 256, 0, stream>>>(Hw, Hb, ellv, ellc, rowlen, dinvw, dinvb, Zw, Zb, bL2W, bL2B);
  k_finalize_par<<<60, 256, 0, stream>>>(bL2W, 512, 30, g30+30, be30+30, acw2, bL2B, 512, 30, g30+120, be30+120, acb2, 16384.f);
  k_apply_gemm<25,100><<<2112, 256, 0, stream>>>(Zw, acw2, x12, W3030+900, Hw, dinvw, Zb, acb2, s12, Wp13, Hb, dinvb);

  // level 3
  k_spmm32<false,true><<<512, 256, 0, stream>>>(Hw, nullptr, ellv, ellc, rowlen, dinvw, nullptr, Zw, nullptr, bL3W, nullptr);
  k_spmm100<false,true,true,true><<<1600, 256, 0, stream>>>(Hb, ellv, ellc, rowlen, dinvb, Zb, bL3B);
  k_finalize_par<<<130, 256, 0, stream>>>(bL3W, 512, 30, g30+60, be30+60, acw3, bL3B, 1600, 100, g100, be100, acb3, 16384.f);

  // pooling assignment (fcpool fuses softmax; writes S into Hb region)
  k_fcpool<<<256, 256, 0, stream>>>(Zw, acw3, Zb, acb3, s11, s12, Wfc, bfc, x13, Hb /* S */);
  k_spmm100<true,false,false,false><<<1600, 256, 0, stream>>>(Hb, ellv, ellc, rowlen, nullptr, Zb /* As */, nullptr);
  k_pool_part<<<64, 256, 0, stream>>>(Hb, x13, Zb, pp);

  // stage 2 (s2pool fuses pool-reduce + A2 normalize + layer1)
  k_s2pool<<<BATCH, 256, 0, stream>>>(pp, W3030+3*900, A2, Z21, bktS2a);
  k_s2layer<<<BATCH, 256, 0, stream>>>(Z21, bktS2a, g30+150, be30+150, x21, W3030+4*900, A2, Z22, bktS2b);
  k_s2layer<<<BATCH, 256, 0, stream>>>(Z22, bktS2b, g30+180, be30+180, x22, W3030+5*900, A2, Z23, bktS2c);

  // readout (maxmlp fuses bktS2c finalize + max2 + MLP)
  k_max1<<<64, 256, 0, stream>>>(x11, x12, x13, partmax);
  k_maxmlp<<<BATCH, 128, 0, stream>>>(partmax, x21, x22, Z23, bktS2c, g30+210, be30+210, W1, b1, W2, b2, out);
}

// Round 8
// 750.860 us; speedup vs baseline: 2.3305x; 1.0194x over previous
//
#include <hip/hip_runtime.h>
#include <hip/hip_fp16.h>
#include <cstdint>
#include <cstddef>

#define BATCH 8
#define NN 2048
#define RTOT 16384   // BATCH*NN
#define KCL 100
#define CAP 176      // ELL row capacity (mean nnz/row ~102, sigma ~10; 7.5 sigma headroom)

// ---------------- workspace layout (offsets in floats) ----------------
// NOTE (R8 fix): u16 arrays sized as count/2 floats. R6/R7 undersized OF_HWB and
// OF_HW3 by 2x, causing apply_gemm<2>'s Hw3/Hb100 writes to alias (race) -> the
// deterministic absmax 0.297 in both bf16 and fp16 rounds.
static constexpr size_t OF_L1W   = 0;                         // 512*30*2
static constexpr size_t OF_L1B   = 30720;
static constexpr size_t OF_L2W   = 61440;
static constexpr size_t OF_L2B   = 92160;
static constexpr size_t OF_L3W   = 122880;                    // 256*30*2 = 15360
static constexpr size_t OF_L3B   = 138240;                    // 832*200 = 166400
static constexpr size_t OF_S2A   = 304640;
static constexpr size_t OF_S2B   = 305120;
static constexpr size_t OF_S2C   = 305600;
static constexpr size_t OF_AC    = 306080;                    // slots
static constexpr size_t OF_ELLV  = 308384;                    // fp32 16384*176 = 2883584
static constexpr size_t OF_ELLC  = OF_ELLV + 2883584;         // u16 16384*176 = 1441792 floats
static constexpr size_t OF_ROWLEN= OF_ELLC + 1441792;
static constexpr size_t OF_DINVW = OF_ROWLEN + 16384;
static constexpr size_t OF_DINVB = OF_DINVW + 16384;
static constexpr size_t OF_HWB   = OF_DINVB + 16384;          // fp16 [RTOT][64]  = 1048576 u16 = 524288 floats
static constexpr size_t OF_HW3   = OF_HWB + 524288;           // fp16 [RTOT][32]  =  524288 u16 = 262144 floats
static constexpr size_t OF_HB100 = OF_HW3 + 262144;           // fp16 [RTOT][104] = 1703936 u16 = 851968 floats (reused as S)
static constexpr size_t OF_ZW    = OF_HB100 + 851968;         // fp32 stride 32
static constexpr size_t OF_ZB    = OF_ZW + 524288;            // fp32 stride 104 = 1703936 (reused as As)
static constexpr size_t OF_X11   = OF_ZB + 1703936;           // fp32 stride 32
static constexpr size_t OF_X12   = OF_X11 + 524288;
static constexpr size_t OF_X13   = OF_X12 + 524288;
static constexpr size_t OF_S11   = OF_X13 + 524288;           // fp32 stride 32; s11+s12 reused as pool partials
static constexpr size_t OF_S12   = OF_S11 + 524288;
static constexpr size_t OF_A2    = OF_S12 + 524288;           // 8*100*100
static constexpr size_t OF_Z21   = OF_A2 + 80000;             // stage-2 stride 30
static constexpr size_t OF_Z22   = OF_Z21 + 24000;
static constexpr size_t OF_Z23   = OF_Z22 + 24000;
static constexpr size_t OF_X21   = OF_Z23 + 24000;
static constexpr size_t OF_X22   = OF_X21 + 24000;
static constexpr size_t OF_PARTMAX = OF_X22 + 24000;          // 8*8*90

#define FMA4(acc, s, h) { acc.x += (s)*(h).x; acc.y += (s)*(h).y; acc.z += (s)*(h).z; acc.w += (s)*(h).w; }

// fp16 conversions (11-bit mantissa: rel eps ~4.9e-4)
__device__ __forceinline__ unsigned short f2h(float f) {
  _Float16 h = (_Float16)f;
  return *(unsigned short*)&h;
}
__device__ __forceinline__ float h2f(unsigned short s) {
  _Float16 h = *(_Float16*)&s;
  return (float)h;
}
__device__ __forceinline__ float2 h2f2(unsigned int u) {
  __half2 h = *(__half2*)&u;
  return __half22float2(h);
}

struct __align__(8) us4 { unsigned short x, y, z, w; };

// accumulate 8 fp16 channels (one uint4 = 8 fp16) into acc[8] with weight wt
#define ACC8(g, wt) { \
  float2 f0=h2f2((g).x), f1=h2f2((g).y), f2=h2f2((g).z), f3=h2f2((g).w); \
  acc[0] += (wt)*f0.x; acc[1] += (wt)*f0.y; acc[2] += (wt)*f1.x; acc[3] += (wt)*f1.y; \
  acc[4] += (wt)*f2.x; acc[5] += (wt)*f2.y; acc[6] += (wt)*f3.x; acc[7] += (wt)*f3.y; }

// ---------------- kernels ----------------

// One pass over adj: build ELL (scan-based compaction), degrees, FUSED H1 (fp16 interleaved).
__global__ __launch_bounds__(256) void k_build_ell(
    const float* __restrict__ adj, const float* __restrict__ x,
    const float* __restrict__ Win, float* __restrict__ ellv,
    unsigned short* __restrict__ ellc, int* __restrict__ rowlen,
    float* __restrict__ dinvw, float* __restrict__ dinvb,
    unsigned short* __restrict__ Hwb)
{
  int r = blockIdx.x;
  const float* row = adj + (size_t)r * NN;
  int t = threadIdx.x, lane = t & 63, wv = t >> 6;
  __shared__ int wcnt[4];
  __shared__ float wsumA[4];
  __shared__ float dsh[2];
  float4 a = ((const float4*)row)[t];
  float4 b = ((const float4*)row)[256 + t];
  float vals[8] = {a.x, a.y, a.z, a.w, b.x, b.y, b.z, b.w};
  int cbase0 = t*4, cbase1 = 1024 + t*4;
  int cnt = 0; float sum = 0.f;
#pragma unroll
  for (int k = 0; k < 8; ++k) { sum += vals[k]; cnt += (vals[k] != 0.f) ? 1 : 0; }
  int pre = cnt;
#pragma unroll
  for (int o = 1; o < 64; o <<= 1) { int n = __shfl_up(pre, o); if (lane >= o) pre += n; }
  int excl = pre - cnt;
  int wtot = __shfl(pre, 63);
#pragma unroll
  for (int o = 32; o; o >>= 1) sum += __shfl_down(sum, o);
  if (lane == 0) { wcnt[wv] = wtot; wsumA[wv] = sum; }
  __syncthreads();
  int base = 0;
  for (int w = 0; w < wv; ++w) base += wcnt[w];
  int p = base + excl;
  size_t rb = (size_t)r * CAP;
#pragma unroll
  for (int k = 0; k < 8; ++k) {
    float v = vals[k];
    if (v != 0.f && p < CAP) {
      ellv[rb + p] = v;
      ellc[rb + p] = (unsigned short)((k < 4) ? (cbase0 + k) : (cbase1 + (k - 4)));
      ++p;
    }
  }
  if (t == 0) {
    int tot = wcnt[0] + wcnt[1] + wcnt[2] + wcnt[3];
    float ws = wsumA[0] + wsumA[1] + wsumA[2] + wsumA[3];
    int nnz = tot < CAP ? tot : CAP;
    int n = nnz;
    while ((n & 3) && n < CAP) { ellv[rb + n] = 0.f; ellc[rb + n] = 0; ++n; }
    rowlen[r] = n;
    float dw = rsqrtf(ws + 1.f), db = rsqrtf((float)nnz + 1.f);
    dinvw[r] = dw; dinvb[r] = db;
    dsh[0] = dw; dsh[1] = db;
  }
  __syncthreads();
  if (t < 64) {  // fused H1: interleaved [row][64] fp16 (ch 0..31 = w, 32..63 = b)
    int c = t & 31, side = t >> 5;
    float v = 0.f;
    if (c < 30) {
      float x0 = x[r*3], x1 = x[r*3+1], x2 = x[r*3+2];
      const float* W = Win + side*90;
      v = (x0*W[c] + x1*W[30+c] + x2*W[60+c]) * dsh[side];
    }
    Hwb[(size_t)r*64 + t] = f2h(v);
  }
}

// Fused SpMM pair, fp16 interleaved source: 8 lanes/row, each lane = 8 channels of one side.
// q<4 -> weighted side (Zw), q>=4 -> binary side (Zb). Per-block BN stat buckets (no atomics).
__global__ __launch_bounds__(256) void k_spmm_pair(
    const unsigned short* __restrict__ Hwb, const float* __restrict__ ellv,
    const unsigned short* __restrict__ ellc, const int* __restrict__ rowlen,
    const float* __restrict__ dinvw, const float* __restrict__ dinvb,
    float* __restrict__ Zw, float* __restrict__ Zb,
    float* __restrict__ bktW, float* __restrict__ bktB)
{
  __shared__ float zsW[32][32];
  __shared__ float zsB[32][32];
  int t = threadIdx.x;
  int gid = blockIdx.x * 256 + t;   // RTOT*8
  int row = gid >> 3, q = gid & 7;
  int side = q >> 2, sub = q & 3;
  int len = rowlen[row];
  const float4* ev = (const float4*)(ellv + (size_t)row * CAP);
  const uint2*  ec = (const uint2*) (ellc + (size_t)row * CAP);
  const uint4* HP = (const uint4*)(Hwb + (size_t)(row >> 11) * (NN*64));
  float acc[8] = {0,0,0,0,0,0,0,0};
  int nit = len >> 2;
  for (int i = 0; i < nit; ++i) {
    float4 v = ev[i];
    uint2 cc = ec[i];
    int c0 = cc.x & 0xffff, c1 = cc.x >> 16, c2 = cc.y & 0xffff, c3 = cc.y >> 16;
    uint4 g0 = HP[c0*8+q], g1 = HP[c1*8+q], g2 = HP[c2*8+q], g3 = HP[c3*8+q];
    float w0 = side ? (v.x>0.f?1.f:0.f) : v.x;
    float w1 = side ? (v.y>0.f?1.f:0.f) : v.y;
    float w2 = side ? (v.z>0.f?1.f:0.f) : v.z;
    float w3 = side ? (v.w>0.f?1.f:0.f) : v.w;
    ACC8(g0, w0); ACC8(g1, w1); ACC8(g2, w2); ACC8(g3, w3);
  }
  uint4 hs = HP[(row & (NN-1))*8 + q];
  ACC8(hs, 1.f);
  float d = side ? dinvb[row] : dinvw[row];
#pragma unroll
  for (int k = 0; k < 8; ++k) acc[k] *= d;
  float* Zp = (side ? Zb : Zw) + (size_t)row*32 + sub*8;
  float4 o0 = {acc[0],acc[1],acc[2],acc[3]}, o1 = {acc[4],acc[5],acc[6],acc[7]};
  ((float4*)Zp)[0] = o0; ((float4*)Zp)[1] = o1;
  int rowloc = t >> 3;
  float (*zs)[32] = side ? zsB : zsW;
#pragma unroll
  for (int k = 0; k < 8; ++k) zs[rowloc][sub*8+k] = acc[k];
  __syncthreads();
  if (t < 30) {
    float s1 = 0.f, s2 = 0.f;
    for (int r = 0; r < 32; ++r) { float v = zsW[r][t]; s1 += v; s2 += v*v; }
    bktW[((size_t)blockIdx.x*30 + t)*2]   = s1;
    bktW[((size_t)blockIdx.x*30 + t)*2+1] = s2;
  } else if (t >= 64 && t < 94) {
    int c = t - 64;
    float s1 = 0.f, s2 = 0.f;
    for (int r = 0; r < 32; ++r) { float v = zsB[r][c]; s1 += v; s2 += v*v; }
    bktB[((size_t)blockIdx.x*30 + c)*2]   = s1;
    bktB[((size_t)blockIdx.x*30 + c)*2+1] = s2;
  }
}

// L3 weighted-side SpMM: fp16 [row][32], 4 lanes/row, stats per block (64 rows).
__global__ __launch_bounds__(256) void k_spmm_w3(
    const unsigned short* __restrict__ H, const float* __restrict__ ellv,
    const unsigned short* __restrict__ ellc, const int* __restrict__ rowlen,
    const float* __restrict__ dinvw, float* __restrict__ Zw, float* __restrict__ bkt)
{
  __shared__ float zs[64][32];
  int t = threadIdx.x;
  int gid = blockIdx.x * 256 + t;   // RTOT*4
  int row = gid >> 2, q = gid & 3;
  int len = rowlen[row];
  const float4* ev = (const float4*)(ellv + (size_t)row * CAP);
  const uint2*  ec = (const uint2*) (ellc + (size_t)row * CAP);
  const uint4* HP = (const uint4*)(H + (size_t)(row >> 11) * (NN*32));
  float acc[8] = {0,0,0,0,0,0,0,0};
  int nit = len >> 2;
  for (int i = 0; i < nit; ++i) {
    float4 v = ev[i];
    uint2 cc = ec[i];
    int c0 = cc.x & 0xffff, c1 = cc.x >> 16, c2 = cc.y & 0xffff, c3 = cc.y >> 16;
    uint4 g0 = HP[c0*4+q], g1 = HP[c1*4+q], g2 = HP[c2*4+q], g3 = HP[c3*4+q];
    ACC8(g0, v.x); ACC8(g1, v.y); ACC8(g2, v.z); ACC8(g3, v.w);
  }
  uint4 hs = HP[(row & (NN-1))*4 + q];
  ACC8(hs, 1.f);
  float d = dinvw[row];
#pragma unroll
  for (int k = 0; k < 8; ++k) acc[k] *= d;
  float* Zp = Zw + (size_t)row*32 + q*8;
  float4 o0 = {acc[0],acc[1],acc[2],acc[3]}, o1 = {acc[4],acc[5],acc[6],acc[7]};
  ((float4*)Zp)[0] = o0; ((float4*)Zp)[1] = o1;
  int rowloc = t >> 2;
#pragma unroll
  for (int k = 0; k < 8; ++k) zs[rowloc][q*8+k] = acc[k];
  __syncthreads();
  if (t < 30) {
    float s1 = 0.f, s2 = 0.f;
    for (int r = 0; r < 64; ++r) { float v = zs[r][t]; s1 += v; s2 += v*v; }
    bkt[((size_t)blockIdx.x*30 + t)*2]   = s1;
    bkt[((size_t)blockIdx.x*30 + t)*2+1] = s2;
  }
}

// C=100 SpMM from fp16 [row][104]: 13 lanes/row. Optional self+scale (L3-b) and stats.
template<bool WEIGHTED, bool SELFSCALE, bool STATS>
__global__ __launch_bounds__(256) void k_spmm100b(
    const unsigned short* __restrict__ H, const float* __restrict__ ellv,
    const unsigned short* __restrict__ ellc, const int* __restrict__ rowlen,
    const float* __restrict__ scale, float* __restrict__ Z, float* __restrict__ bkt)
{
  __shared__ float st[200];
  int t = threadIdx.x;
  if (STATS) { for (int i = t; i < 200; i += 256) st[i] = 0.f; __syncthreads(); }
  int gid = blockIdx.x * 256 + t;   // RTOT*13 exactly
  int row = gid / 13, q = gid - row*13;
  int len = rowlen[row];
  const float4* ev = (const float4*)(ellv + (size_t)row * CAP);
  const uint2*  ec = (const uint2*) (ellc + (size_t)row * CAP);
  const uint4* HP = (const uint4*)(H + (size_t)(row >> 11) * ((size_t)NN*104));
  float acc[8] = {0,0,0,0,0,0,0,0};
  int nit = len >> 2;
  for (int i = 0; i < nit; ++i) {
    float4 v = ev[i];
    uint2 cc = ec[i];
    int c0 = cc.x & 0xffff, c1 = cc.x >> 16, c2 = cc.y & 0xffff, c3 = cc.y >> 16;
    uint4 g0 = HP[c0*13+q], g1 = HP[c1*13+q], g2 = HP[c2*13+q], g3 = HP[c3*13+q];
    float w0 = WEIGHTED ? v.x : (v.x>0.f?1.f:0.f);
    float w1 = WEIGHTED ? v.y : (v.y>0.f?1.f:0.f);
    float w2 = WEIGHTED ? v.z : (v.z>0.f?1.f:0.f);
    float w3 = WEIGHTED ? v.w : (v.w>0.f?1.f:0.f);
    ACC8(g0, w0); ACC8(g1, w1); ACC8(g2, w2); ACC8(g3, w3);
  }
  if (SELFSCALE) {
    uint4 hs = HP[(row & (NN-1))*13 + q];
    ACC8(hs, 1.f);
    float d = scale[row];
#pragma unroll
    for (int k = 0; k < 8; ++k) acc[k] *= d;
  }
  float* Zp = Z + (size_t)row*104 + q*8;
  float4 o0 = {acc[0],acc[1],acc[2],acc[3]}, o1 = {acc[4],acc[5],acc[6],acc[7]};
  ((float4*)Zp)[0] = o0; ((float4*)Zp)[1] = o1;
  if (STATS) {
    int c0 = q*8;
#pragma unroll
    for (int k = 0; k < 8; ++k) {
      int ch = c0 + k;
      if (ch < 100) { atomicAdd(&st[ch*2], acc[k]); atomicAdd(&st[ch*2+1], acc[k]*acc[k]); }
    }
    __syncthreads();
    for (int i = t; i < 200; i += 256) bkt[(size_t)blockIdx.x*200 + i] = st[i];
  }
}

// PARALLEL bucket finalize: one block per channel.
__global__ __launch_bounds__(256) void k_finalize_par(
    const float* __restrict__ bA, int nA, int cA, const float* __restrict__ gA,
    const float* __restrict__ beA, float* __restrict__ outA,
    const float* __restrict__ bB, int nB, int cB, const float* __restrict__ gB,
    const float* __restrict__ beB, float* __restrict__ outB, float count)
{
  __shared__ float r1[256], r2[256];
  int c = blockIdx.x, t = threadIdx.x;
  const float* src; int n, C, cc;
  float* dst; const float* g; const float* be; int cap;
  if (c < cA) { src = bA; n = nA; C = cA; cc = c; dst = outA; g = gA; be = beA; cap = cA; }
  else { src = bB; n = nB; C = cB; cc = c - cA; dst = outB; g = gB; be = beB; cap = cB; }
  float s1 = 0.f, s2 = 0.f;
  for (int b = t; b < n; b += 256) {
    float2 v = *(const float2*)(src + ((size_t)b*C + cc)*2);
    s1 += v.x; s2 += v.y;
  }
  r1[t] = s1; r2[t] = s2;
  __syncthreads();
  for (int o = 128; o > 0; o >>= 1) {
    if (t < o) { r1[t] += r1[t+o]; r2[t] += r2[t+o]; }
    __syncthreads();
  }
  if (t == 0) {
    float mean = r1[0]/count, var = r2[0]/count - mean*mean, inv = rsqrtf(var + 1e-5f);
    float aa = g[cc]*inv; dst[cc] = aa; dst[cap + cc] = be[cc] - mean*aa;
  }
}

// apply BN -> store x/s (fp32 stride 32) -> next-layer weight GEMM * dinv -> fp16 outputs.
// LEVEL 1: out interleaved Hwb [row][64]. LEVEL 2: w -> [row][32], b -> [row][104].
template<int LEVEL>
__global__ __launch_bounds__(256) void k_apply_gemm(
    const float* __restrict__ Zw, const float* __restrict__ acW,
    float* __restrict__ xst, const float* __restrict__ Ww,
    const float* __restrict__ dinvw,
    const float* __restrict__ Zb, const float* __restrict__ acB,
    float* __restrict__ sst, const float* __restrict__ Wb,
    const float* __restrict__ dinvb,
    unsigned short* __restrict__ HwOut, unsigned short* __restrict__ HbOut)
{
  constexpr int NGB = (LEVEL == 1) ? 8 : 26;
  constexpr int OSTRIDEB = (LEVEL == 1) ? 32 : 104;
  constexpr int NG = 8 + NGB;
  __shared__ float WwL[30*32];
  __shared__ float WbL[30*OSTRIDEB];
  __shared__ float awL[60], abL[60];
  int t = threadIdx.x;
  for (int idx = t; idx < 30*32; idx += 256) {
    int k = idx >> 5, c = idx & 31;
    WwL[idx] = (c < 30) ? Ww[k*30 + c] : 0.f;
  }
  if (LEVEL == 1) {
    for (int idx = t; idx < 30*32; idx += 256) {
      int k = idx >> 5, c = idx & 31;
      WbL[idx] = (c < 30) ? Wb[k*30 + c] : 0.f;
    }
  } else {
    for (int idx = t; idx < 30*OSTRIDEB; idx += 256) {
      int k = idx / OSTRIDEB, j = idx % OSTRIDEB;
      WbL[idx] = (j < 100) ? Wb[k*100 + j] : 0.f;
    }
  }
  if (t < 60) { awL[t] = acW[t]; abL[t] = acB[t]; }
  __syncthreads();
  int gid = blockIdx.x * 256 + t;
  int row = gid / NG, g = gid % NG;
  if (g < 8) {
    const float4* Z4 = (const float4*)Zw + (size_t)row*8;
    float4 z4[8];
#pragma unroll
    for (int u = 0; u < 8; ++u) z4[u] = Z4[u];
    const float* z = (const float*)z4;
    float4 xv;
    int ch = 4*g;
    xv.x = (ch+0 < 30) ? awL[ch+0]*z[ch+0] + awL[30+ch+0] : 0.f;
    xv.y = (ch+1 < 30) ? awL[ch+1]*z[ch+1] + awL[30+ch+1] : 0.f;
    xv.z = (ch+2 < 30) ? awL[ch+2]*z[ch+2] + awL[30+ch+2] : 0.f;
    xv.w = (ch+3 < 30) ? awL[ch+3]*z[ch+3] + awL[30+ch+3] : 0.f;
    ((float4*)xst)[(size_t)row*8+g] = xv;
    float4 o = {0,0,0,0};
#pragma unroll
    for (int k = 0; k < 30; ++k) {
      float xk = awL[k]*z[k] + awL[30+k];
      float4 w = *(const float4*)(WwL + k*32 + 4*g);
      FMA4(o, xk, w);
    }
    float d = dinvw[row];
    us4 pv = { f2h(d*o.x), f2h(d*o.y), f2h(d*o.z), f2h(d*o.w) };
    unsigned short* dst = (LEVEL == 1) ? (HwOut + (size_t)row*64 + 4*g)
                                       : (HwOut + (size_t)row*32 + 4*g);
    *(us4*)dst = pv;
  } else {
    int gb = g - 8;
    const float4* Z4 = (const float4*)Zb + (size_t)row*8;
    float4 z4[8];
#pragma unroll
    for (int u = 0; u < 8; ++u) z4[u] = Z4[u];
    const float* z = (const float*)z4;
    if (gb < 8) {
      int ch = 4*gb;
      float4 sv;
      sv.x = (ch+0 < 30) ? abL[ch+0]*z[ch+0] + abL[30+ch+0] : 0.f;
      sv.y = (ch+1 < 30) ? abL[ch+1]*z[ch+1] + abL[30+ch+1] : 0.f;
      sv.z = (ch+2 < 30) ? abL[ch+2]*z[ch+2] + abL[30+ch+2] : 0.f;
      sv.w = (ch+3 < 30) ? abL[ch+3]*z[ch+3] + abL[30+ch+3] : 0.f;
      ((float4*)sst)[(size_t)row*8+gb] = sv;
    }
    float4 o = {0,0,0,0};
#pragma unroll
    for (int k = 0; k < 30; ++k) {
      float sk = abL[k]*z[k] + abL[30+k];
      float4 w = *(const float4*)(WbL + k*OSTRIDEB + 4*gb);
      FMA4(o, sk, w);
    }
    float d = dinvb[row];
    us4 pv = { f2h(d*o.x), f2h(d*o.y), f2h(d*o.z), f2h(d*o.w) };
    unsigned short* dst = (LEVEL == 1) ? (HbOut + (size_t)row*64 + 32 + 4*gb)
                                       : (HbOut + (size_t)row*104 + 4*gb);
    *(us4*)dst = pv;
  }
}

// BN(Z3w)->x13 (fp32 stride 32); s13=BN(Z3b, stride 104); s1 = [s11|s12|s13]@Wfc + bfc;
// FUSED softmax -> S (fp16 [row][104], ch 100..103 zero)
__global__ __launch_bounds__(256) void k_fcpool(
    const float* __restrict__ Zw3, const float* __restrict__ acW3,
    const float* __restrict__ Zb3, const float* __restrict__ acB3,
    const float* __restrict__ s11, const float* __restrict__ s12,
    const float* __restrict__ Wfc, const float* __restrict__ bfc,
    float* __restrict__ x13, unsigned short* __restrict__ S)
{
  __shared__ float shm[14240];   // feat 64x160 = 10240 | Wl 40x100 = 4000
  float* feat = shm;
  float* Wl = shm + 10240;
  int t = threadIdx.x;
  int g0 = blockIdx.x * 64;
  for (int idx = t; idx < 64*160; idx += 256) {
    int l = idx / 160, c = idx % 160;
    int g = g0 + l;
    float v;
    if (c < 30) v = s11[(size_t)g*32 + c];
    else if (c < 60) v = s12[(size_t)g*32 + (c-30)];
    else { int k = c - 60; v = acB3[k]*Zb3[(size_t)g*104 + k] + acB3[100 + k]; }
    feat[l*160 + c] = v;
  }
  for (int idx = t; idx < 64*32; idx += 256) {
    int l = idx >> 5, c = idx & 31;
    int g = g0 + l;
    x13[(size_t)g*32+c] = (c < 30) ? acW3[c]*Zw3[(size_t)g*32+c] + acW3[30+c] : 0.f;
  }
  int np = t >> 3, kg = t & 7;
  int n0 = np*2, n1 = np*2 + 1;
  int kbase = kg*12 + (kg < 4 ? kg : 4);
  int klen  = kg < 4 ? 13 : 12;
  float a0[13], a1[13];
#pragma unroll
  for (int j = 0; j < 13; ++j) { a0[j] = 0.f; a1[j] = 0.f; }
  for (int ch = 0; ch < 4; ++ch) {
    __syncthreads();
    for (int idx = t; idx < 4000; idx += 256) {
      int r = idx/100, j = idx%100;
      Wl[r*100 + j] = Wfc[(ch*40 + r)*100 + j];
    }
    __syncthreads();
    for (int kk = 0; kk < 40; ++kk) {
      float f0 = feat[n0*160 + ch*40+kk];
      float f1 = feat[n1*160 + ch*40+kk];
#pragma unroll
      for (int j = 0; j < 13; ++j) {
        if (j < klen) {
          float w = Wl[kk*100 + kbase + j];
          a0[j] += f0*w; a1[j] += f1*w;
        }
      }
    }
  }
  __syncthreads();
  float* sRow = shm;  // reuse as [64][100]
  for (int j = 0; j < klen; ++j) {
    int k = kbase + j;
    sRow[n0*100 + k] = a0[j] + bfc[k];
    sRow[n1*100 + k] = a1[j] + bfc[k];
  }
  __syncthreads();
  int n = t >> 2, part = t & 3;
  int i0 = part*25;
  float m = -3.4e38f;
  for (int i = 0; i < 25; ++i) m = fmaxf(m, sRow[n*100 + i0 + i]);
  m = fmaxf(m, __shfl_xor(m, 1));
  m = fmaxf(m, __shfl_xor(m, 2));
  float ev[25]; float s = 0.f;
  for (int i = 0; i < 25; ++i) { float e = __expf(sRow[n*100 + i0 + i] - m); ev[i] = e; s += e; }
  s += __shfl_xor(s, 1);
  s += __shfl_xor(s, 2);
  float rinv = 1.f / s;
  for (int i = 0; i < 25; ++i) S[(size_t)(g0+n)*104 + i0 + i] = f2h(ev[i] * rinv);
  if (part == 3) {
    S[(size_t)(g0+n)*104 + 100] = 0; S[(size_t)(g0+n)*104 + 101] = 0;
    S[(size_t)(g0+n)*104 + 102] = 0; S[(size_t)(g0+n)*104 + 103] = 0;
  }
}

// pooled partials: pp[blk][k][d] over this block's 256 nodes; NO atomics
__global__ __launch_bounds__(256) void k_pool_part(
    const unsigned short* __restrict__ S, const float* __restrict__ x13,
    const float* __restrict__ As, float* __restrict__ pp)
{
  __shared__ float sL[64][100];
  __shared__ float xL[64][132];
  int t = threadIdx.x;
  int b = blockIdx.x >> 3, chunk = blockIdx.x & 7;
  int g00 = b * 2048 + chunk * 256;
  int kt = t/10, dt = t%10;
  int k0 = kt*4, d0 = dt*13;
  float acc[4][13];
#pragma unroll
  for (int a = 0; a < 4; ++a)
#pragma unroll
    for (int j = 0; j < 13; ++j) acc[a][j] = 0.f;
  for (int tile = 0; tile < 4; ++tile) {
    int g0 = g00 + tile*64;
    __syncthreads();
    for (int idx = t; idx < 64*100; idx += 256) {
      int l = idx/100, k = idx%100;
      sL[l][k] = h2f(S[(size_t)(g0+l)*104 + k]);
    }
    for (int idx = t; idx < 64*130; idx += 256) {
      int l = idx/130, d = idx%130;
      xL[l][d] = d < 30 ? x13[(size_t)(g0+l)*32 + d] : As[(size_t)(g0+l)*104 + (d-30)];
    }
    __syncthreads();
    if (t < 250) {
      for (int kk = 0; kk < 64; ++kk) {
        float sv[4];
#pragma unroll
        for (int a = 0; a < 4; ++a) sv[a] = sL[kk][k0+a];
#pragma unroll
        for (int j = 0; j < 13; ++j) {
          float xv = xL[kk][d0+j];
#pragma unroll
          for (int a = 0; a < 4; ++a) acc[a][j] += sv[a]*xv;
        }
      }
    }
  }
  if (t < 250) {
    float* dst = pp + (size_t)blockIdx.x * 13000;
    for (int a = 0; a < 4; ++a)
      for (int j = 0; j < 13; ++j)
        dst[(k0+a)*130 + (d0+j)] = acc[a][j];
  }
}

// stage-2 layer 1 FUSED with pool-reduce + A2 normalize. One block per batch.
__global__ __launch_bounds__(256) void k_s2pool(
    const float* __restrict__ pp, const float* __restrict__ Wm,
    float* __restrict__ A2, float* __restrict__ Zout, float* __restrict__ bkt)
{
  __shared__ float Ah[10000];
  __shared__ float Xl[3000];
  __shared__ float Tl[3000];
  __shared__ float dl[100];
  __shared__ float st1[30], st2[30];
  int b = blockIdx.x, t = threadIdx.x;
  if (t < 30) { st1[t] = 0.f; st2[t] = 0.f; }
  for (int idx = t; idx < 13000; idx += 256) {
    float s = 0.f;
    for (int ch = 0; ch < 8; ++ch) s += pp[(size_t)(b*8 + ch)*13000 + idx];
    int k = idx/130, d = idx%130;
    if (d < 30) Xl[k*30 + d] = s; else Ah[k*100 + (d-30)] = s;
  }
  __syncthreads();
  if (t < 100 && Ah[t*101] == 0.f) Ah[t*101] = 1.f;
  __syncthreads();
  if (t < 100) {
    float s = 0.f;
    for (int j = 0; j < 100; ++j) s += Ah[t*100 + j];
    dl[t] = s > 0.f ? rsqrtf(s) : 0.f;
  }
  __syncthreads();
  for (int idx = t; idx < 10000; idx += 256) {
    int i = idx/100, j = idx%100;
    float v = dl[i]*dl[j]*Ah[idx];
    Ah[idx] = v;
    A2[(size_t)b*10000 + idx] = v;
  }
  __syncthreads();
  for (int idx = t; idx < 3000; idx += 256) {
    int i = idx/30, c = idx%30;
    float acc = 0.f;
    for (int k = 0; k < 30; ++k) acc += Xl[i*30+k]*Wm[k*30+c];
    Tl[idx] = acc;
  }
  __syncthreads();
  for (int idx = t; idx < 3000; idx += 256) {
    int i = idx/30, c = idx%30;
    float acc = 0.f;
    for (int j = 0; j < 100; ++j) acc += Ah[i*100+j]*Tl[j*30+c];
    Zout[(size_t)b*3000 + idx] = acc;
    atomicAdd(&st1[c], acc);
    atomicAdd(&st2[c], acc*acc);
  }
  __syncthreads();
  if (t < 30) {
    bkt[((size_t)b*30 + t)*2]   = st1[t];
    bkt[((size_t)b*30 + t)*2+1] = st2[t];
  }
}

// stage-2 layers 2,3: inline BN-finalize of prev bucket, then layer + stats
__global__ __launch_bounds__(256) void k_s2layer(
    const float* __restrict__ Zprev, const float* __restrict__ prevBkt,
    const float* __restrict__ gamma, const float* __restrict__ beta,
    float* __restrict__ xst, const float* __restrict__ Wm,
    const float* __restrict__ A2, float* __restrict__ Zout, float* __restrict__ bkt)
{
  __shared__ float Xl[3000];
  __shared__ float Tl[3000];
  __shared__ float Al[10000];
  __shared__ float acL[60];
  __shared__ float st1[30], st2[30];
  int b = blockIdx.x, t = threadIdx.x;
  if (t < 30) {
    float s1 = 0.f, s2 = 0.f;
    for (int q = 0; q < 8; ++q) {
      s1 += prevBkt[((size_t)q*30 + t)*2];
      s2 += prevBkt[((size_t)q*30 + t)*2+1];
    }
    float mean = s1/800.f, var = s2/800.f - mean*mean, inv = rsqrtf(var + 1e-5f);
    float aa = gamma[t]*inv; acL[t] = aa; acL[30+t] = beta[t] - mean*aa;
    st1[t] = 0.f; st2[t] = 0.f;
  }
  __syncthreads();
  for (int idx = t; idx < 3000; idx += 256) {
    int c = idx % 30;
    float v = acL[c]*Zprev[(size_t)b*3000 + idx] + acL[30+c];
    xst[(size_t)b*3000 + idx] = v;
    Xl[idx] = v;
  }
  for (int idx = t; idx < 10000; idx += 256) Al[idx] = A2[(size_t)b*10000 + idx];
  __syncthreads();
  for (int idx = t; idx < 3000; idx += 256) {
    int i = idx/30, c = idx%30;
    float acc = 0.f;
    for (int k = 0; k < 30; ++k) acc += Xl[i*30+k]*Wm[k*30+c];
    Tl[idx] = acc;
  }
  __syncthreads();
  for (int idx = t; idx < 3000; idx += 256) {
    int i = idx/30, c = idx%30;
    float acc = 0.f;
    for (int j = 0; j < 100; ++j) acc += Al[i*100+j]*Tl[j*30+c];
    Zout[(size_t)b*3000 + idx] = acc;
    atomicAdd(&st1[c], acc);
    atomicAdd(&st2[c], acc*acc);
  }
  __syncthreads();
  if (t < 30) {
    bkt[((size_t)b*30 + t)*2]   = st1[t];
    bkt[((size_t)b*30 + t)*2+1] = st2[t];
  }
}

// stage-1 per-segment column max of [x11|x12|x13] (fp32 stride 32, coalesced)
__global__ __launch_bounds__(256) void k_max1(
    const float* __restrict__ x11, const float* __restrict__ x12,
    const float* __restrict__ x13, float* __restrict__ pm)
{
  __shared__ float red[256];
  int t = threadIdx.x, c = t & 31, rg = t >> 5;
  int b = blockIdx.x >> 3, seg = blockIdx.x & 7;
  int r0 = b*2048 + seg*256;
  const float* srcs[3] = {x11, x12, x13};
  for (int a = 0; a < 3; ++a) {
    const float* p = srcs[a] + (size_t)(r0+rg)*32 + c;
    float m = -3.4e38f;
    for (int it = 0; it < 32; ++it) m = fmaxf(m, p[it*256]);
    red[t] = m;
    __syncthreads();
    if (t < 30) {
      float mm = red[t];
      for (int g = 1; g < 8; ++g) mm = fmaxf(mm, red[g*32+t]);
      pm[(size_t)(b*8+seg)*90 + a*30 + t] = mm;
    }
    __syncthreads();
  }
}

// FUSED: finalize bktS2c -> x1out/x2out maxes -> MLP -> out. One block per batch.
__global__ __launch_bounds__(128) void k_maxmlp(
    const float* __restrict__ pm, const float* __restrict__ x21,
    const float* __restrict__ x22, const float* __restrict__ Z23,
    const float* __restrict__ bktS2c, const float* __restrict__ gamma,
    const float* __restrict__ beta,
    const float* __restrict__ W1, const float* __restrict__ b1,
    const float* __restrict__ W2, const float* __restrict__ b2,
    float* __restrict__ out)
{
  __shared__ float ac[60], x1L[90], x2L[90], hh[50];
  int b = blockIdx.x, t = threadIdx.x;
  if (t < 30) {
    float s1 = 0.f, s2 = 0.f;
    for (int q = 0; q < 8; ++q) {
      s1 += bktS2c[((size_t)q*30 + t)*2];
      s2 += bktS2c[((size_t)q*30 + t)*2+1];
    }
    float mean = s1/800.f, var = s2/800.f - mean*mean, inv = rsqrtf(var + 1e-5f);
    float aa = gamma[t]*inv; ac[t] = aa; ac[30+t] = beta[t] - mean*aa;
  }
  __syncthreads();
  if (t < 90) {
    float m = -3.4e38f;
    for (int s = 0; s < 8; ++s) m = fmaxf(m, pm[(size_t)(b*8+s)*90 + t]);
    x1L[t] = m;
    float m2 = -3.4e38f;
    int cc = t % 30;
    for (int i = 0; i < 100; ++i) {
      float v;
      if (t < 30) v = x21[(size_t)b*3000 + i*30 + cc];
      else if (t < 60) v = x22[(size_t)b*3000 + i*30 + cc];
      else v = ac[cc]*Z23[(size_t)b*3000 + i*30 + cc] + ac[30+cc];
      m2 = fmaxf(m2, v);
    }
    x2L[t] = m2;
  }
  __syncthreads();
  if (t < 50) {
    float acc = b1[t];
    for (int k = 0; k < 90; ++k) acc += x1L[k]*W1[k*50+t];
    for (int k = 0; k < 90; ++k) acc += x2L[k]*W1[(90+k)*50+t];
    hh[t] = fmaxf(acc, 0.f);
  }
  __syncthreads();
  if (t < 6) {
    float acc = b2[t];
    for (int j = 0; j < 50; ++j) acc += hh[j]*W2[j*6+t];
    out[b*6+t] = acc;
  }
}

// ---------------- launcher ----------------
extern "C" void kernel_launch(void* const* d_in, const int* in_sizes, int n_in,
                              void* d_out, int out_size, void* d_ws, size_t ws_size,
                              hipStream_t stream)
{
  const float* x    = (const float*)d_in[0];
  const float* adj  = (const float*)d_in[1];
  const float* Win  = (const float*)d_in[2];
  const float* W3030= (const float*)d_in[3];
  const float* Wp13 = (const float*)d_in[4];
  // d_in[5]=b30, d_in[6]=b100: cancel through training-mode BN -> unused
  const float* Wfc  = (const float*)d_in[7];
  const float* bfc  = (const float*)d_in[8];
  const float* W1   = (const float*)d_in[9];
  const float* b1   = (const float*)d_in[10];
  const float* W2   = (const float*)d_in[11];
  const float* b2   = (const float*)d_in[12];
  const float* g30  = (const float*)d_in[13];
  const float* be30 = (const float*)d_in[14];
  const float* g100 = (const float*)d_in[15];
  const float* be100= (const float*)d_in[16];
  float* out = (float*)d_out;

  float* wsf = (float*)d_ws;
  float* bL1W = wsf + OF_L1W;  float* bL1B = wsf + OF_L1B;
  float* bL2W = wsf + OF_L2W;  float* bL2B = wsf + OF_L2B;
  float* bL3W = wsf + OF_L3W;  float* bL3B = wsf + OF_L3B;
  float* bktS2a = wsf + OF_S2A;
  float* bktS2b = wsf + OF_S2B;
  float* bktS2c = wsf + OF_S2C;
  float* ellv  = wsf + OF_ELLV;
  unsigned short* ellc = (unsigned short*)(wsf + OF_ELLC);
  int*   rowlen = (int*)(wsf + OF_ROWLEN);
  float* dinvw = wsf + OF_DINVW;
  float* dinvb = wsf + OF_DINVB;
  unsigned short* Hwb   = (unsigned short*)(wsf + OF_HWB);
  unsigned short* Hw3   = (unsigned short*)(wsf + OF_HW3);
  unsigned short* Hb100 = (unsigned short*)(wsf + OF_HB100);
  unsigned short* S     = Hb100;   // S reuses HB100 (dead after L3-b spmm)
  float* Zw = wsf + OF_ZW;
  float* Zb = wsf + OF_ZB;         // stride 104; later reused as As
  float* x11 = wsf + OF_X11;
  float* x12 = wsf + OF_X12;
  float* x13 = wsf + OF_X13;
  float* s11 = wsf + OF_S11;
  float* s12 = wsf + OF_S12;
  float* pp  = wsf + OF_S11;       // pool partials reuse s11+s12 (dead after fcpool)
  float* acw1 = wsf + OF_AC + 0;
  float* acb1 = wsf + OF_AC + 256;
  float* acw2 = wsf + OF_AC + 512;
  float* acb2 = wsf + OF_AC + 768;
  float* acw3 = wsf + OF_AC + 1024;
  float* acb3 = wsf + OF_AC + 1280;
  float* A2  = wsf + OF_A2;
  float* Z21 = wsf + OF_Z21;
  float* Z22 = wsf + OF_Z22;
  float* Z23 = wsf + OF_Z23;
  float* x21 = wsf + OF_X21;
  float* x22 = wsf + OF_X22;
  float* partmax = wsf + OF_PARTMAX;

  k_build_ell<<<RTOT, 256, 0, stream>>>(adj, x, Win, ellv, ellc, rowlen, dinvw, dinvb, Hwb);

  // level 1
  k_spmm_pair<<<512, 256, 0, stream>>>(Hwb, ellv, ellc, rowlen, dinvw, dinvb, Zw, Zb, bL1W, bL1B);
  k_finalize_par<<<60, 256, 0, stream>>>(bL1W, 512, 30, g30+0,  be30+0,  acw1, bL1B, 512, 30, g30+90,  be30+90,  acb1, 16384.f);
  k_apply_gemm<1><<<1024, 256, 0, stream>>>(Zw, acw1, x11, W3030+0, dinvw, Zb, acb1, s11, W3030+2*900, dinvb, Hwb, Hwb);

  // level 2
  k_spmm_pair<<<512, 256, 0, stream>>>(Hwb, ellv, ellc, rowlen, dinvw, dinvb, Zw, Zb, bL2W, bL2B);
  k_finalize_par<<<60, 256, 0, stream>>>(bL2W, 512, 30, g30+30, be30+30, acw2, bL2B, 512, 30, g30+120, be30+120, acb2, 16384.f);
  k_apply_gemm<2><<<2176, 256, 0, stream>>>(Zw, acw2, x12, W3030+900, dinvw, Zb, acb2, s12, Wp13, dinvb, Hw3, Hb100);

  // level 3
  k_spmm_w3<<<256, 256, 0, stream>>>(Hw3, ellv, ellc, rowlen, dinvw, Zw, bL3W);
  k_spmm100b<false,true,true><<<832, 256, 0, stream>>>(Hb100, ellv, ellc, rowlen, dinvb, Zb, bL3B);
  k_finalize_par<<<130, 256, 0, stream>>>(bL3W, 256, 30, g30+60, be30+60, acw3, bL3B, 832, 100, g100, be100, acb3, 16384.f);

  // pooling assignment (fcpool fuses softmax; writes fp16 S into HB100 region)
  k_fcpool<<<256, 256, 0, stream>>>(Zw, acw3, Zb, acb3, s11, s12, Wfc, bfc, x13, S);
  k_spmm100b<true,false,false><<<832, 256, 0, stream>>>(S, ellv, ellc, rowlen, nullptr, Zb /* As */, nullptr);
  k_pool_part<<<64, 256, 0, stream>>>(S, x13, Zb, pp);

  // stage 2 (s2pool fuses pool-reduce + A2 normalize + layer1)
  k_s2pool<<<BATCH, 256, 0, stream>>>(pp, W3030+3*900, A2, Z21, bktS2a);
  k_s2layer<<<BATCH, 256, 0, stream>>>(Z21, bktS2a, g30+150, be30+150, x21, W3030+4*900, A2, Z22, bktS2b);
  k_s2layer<<<BATCH, 256, 0, stream>>>(Z22, bktS2b, g30+180, be30+180, x22, W3030+5*900, A2, Z23, bktS2c);

  // readout (maxmlp fuses bktS2c finalize + max2 + MLP)
  k_max1<<<64, 256, 0, stream>>>(x11, x12, x13, partmax);
  k_maxmlp<<<BATCH, 128, 0, stream>>>(partmax, x21, x22, Z23, bktS2c, g30+210, be30+210, W1, b1, W2, b2, out);
}

// Round 9
// 698.602 us; speedup vs baseline: 2.5048x; 1.0748x over previous
//
#include <hip/hip_runtime.h>
#include <hip/hip_fp16.h>
#include <cstdint>
#include <cstddef>

#define BATCH 8
#define NN 2048
#define RTOT 16384   // BATCH*NN
#define CAP 176      // ELL row capacity

// ---------------- workspace layout (offsets in floats) ----------------
// Bucket regions + barrier counter live at the front and are zeroed by k_build_ell.
static constexpr size_t OF_B1W   = 0;         // [30][64][2] = 3840
static constexpr size_t OF_B1B   = 3840;
static constexpr size_t OF_B2W   = 7680;
static constexpr size_t OF_B2B   = 11520;
static constexpr size_t OF_B3W   = 15360;     // [30][8][2] = 480
static constexpr size_t OF_B3B   = 15840;     // [100][8][2] = 1600
static constexpr size_t OF_S2    = 17440;     // [3][30][2] = 180
static constexpr size_t OF_CNT   = 17620;     // int barrier counter (+pad)
static constexpr size_t ZEND     = 17632;     // zero range [0, ZEND)
static constexpr size_t OF_ELLV  = 17664;                     // fp32 16384*176
static constexpr size_t OF_ELLC  = OF_ELLV + 2883584;         // u16 16384*176 = 1441792 floats
static constexpr size_t OF_ROWLEN= OF_ELLC + 1441792;
static constexpr size_t OF_DINVW = OF_ROWLEN + 16384;
static constexpr size_t OF_DINVB = OF_DINVW + 16384;
static constexpr size_t OF_HWB   = OF_DINVB + 16384;          // fp16 [RTOT][64]  = 524288 floats
static constexpr size_t OF_HW3   = OF_HWB + 524288;           // fp16 [RTOT][32]  = 262144 floats
static constexpr size_t OF_HB100 = OF_HW3 + 262144;           // fp16 [RTOT][104] = 851968 floats (reused as S)
static constexpr size_t OF_ZW    = OF_HB100 + 851968;         // fp32 stride 32
static constexpr size_t OF_ZB    = OF_ZW + 524288;            // fp32 stride 104 (reused as As)
static constexpr size_t OF_X11   = OF_ZB + 1703936;           // fp32 stride 32
static constexpr size_t OF_X12   = OF_X11 + 524288;
static constexpr size_t OF_X13   = OF_X12 + 524288;
static constexpr size_t OF_S11   = OF_X13 + 524288;           // s11+s12 reused as pool partials pp
static constexpr size_t OF_S12   = OF_S11 + 524288;
static constexpr size_t OF_PARTMAX = OF_S12 + 524288;         // 64*90

#define FMA4(acc, s, h) { acc.x += (s)*(h).x; acc.y += (s)*(h).y; acc.z += (s)*(h).z; acc.w += (s)*(h).w; }

__device__ __forceinline__ unsigned short f2h(float f) {
  _Float16 h = (_Float16)f;
  return *(unsigned short*)&h;
}
__device__ __forceinline__ float h2f(unsigned short s) {
  _Float16 h = *(_Float16*)&s;
  return (float)h;
}
__device__ __forceinline__ float2 h2f2(unsigned int u) {
  __half2 h = *(__half2*)&u;
  return __half22float2(h);
}

struct __align__(8) us4 { unsigned short x, y, z, w; };

// accumulate 8 fp16 channels (one uint4 = 8 fp16) into acc[8] with weight wt
#define ACC8(g, wt) { \
  float2 f0=h2f2((g).x), f1=h2f2((g).y), f2=h2f2((g).z), f3=h2f2((g).w); \
  acc[0] += (wt)*f0.x; acc[1] += (wt)*f0.y; acc[2] += (wt)*f1.x; acc[3] += (wt)*f1.y; \
  acc[4] += (wt)*f2.x; acc[5] += (wt)*f2.y; acc[6] += (wt)*f3.x; acc[7] += (wt)*f3.y; }

// ---------------- kernels ----------------

// One pass over adj: zero bucket/counter region, build ELL (scan-based compaction),
// degrees, FUSED H1 (fp16 interleaved [row][64]).
__global__ __launch_bounds__(256) void k_build_ell(
    const float* __restrict__ adj, const float* __restrict__ x,
    const float* __restrict__ Win, float* __restrict__ ellv,
    unsigned short* __restrict__ ellc, int* __restrict__ rowlen,
    float* __restrict__ dinvw, float* __restrict__ dinvb,
    unsigned short* __restrict__ Hwb, float* __restrict__ zbase)
{
  int r = blockIdx.x;
  int t = threadIdx.x, lane = t & 63, wv = t >> 6;
  if (blockIdx.x < 69) {
    int zi = blockIdx.x * 256 + t;
    if (zi < (int)ZEND) zbase[zi] = 0.f;
  }
  const float* row = adj + (size_t)r * NN;
  __shared__ int wcnt[4];
  __shared__ float wsumA[4];
  __shared__ float dsh[2];
  float4 a = ((const float4*)row)[t];
  float4 b = ((const float4*)row)[256 + t];
  float vals[8] = {a.x, a.y, a.z, a.w, b.x, b.y, b.z, b.w};
  int cbase0 = t*4, cbase1 = 1024 + t*4;
  int cnt = 0; float sum = 0.f;
#pragma unroll
  for (int k = 0; k < 8; ++k) { sum += vals[k]; cnt += (vals[k] != 0.f) ? 1 : 0; }
  int pre = cnt;
#pragma unroll
  for (int o = 1; o < 64; o <<= 1) { int n = __shfl_up(pre, o); if (lane >= o) pre += n; }
  int excl = pre - cnt;
  int wtot = __shfl(pre, 63);
#pragma unroll
  for (int o = 32; o; o >>= 1) sum += __shfl_down(sum, o);
  if (lane == 0) { wcnt[wv] = wtot; wsumA[wv] = sum; }
  __syncthreads();
  int base = 0;
  for (int w = 0; w < wv; ++w) base += wcnt[w];
  int p = base + excl;
  size_t rb = (size_t)r * CAP;
#pragma unroll
  for (int k = 0; k < 8; ++k) {
    float v = vals[k];
    if (v != 0.f && p < CAP) {
      ellv[rb + p] = v;
      ellc[rb + p] = (unsigned short)((k < 4) ? (cbase0 + k) : (cbase1 + (k - 4)));
      ++p;
    }
  }
  if (t == 0) {
    int tot = wcnt[0] + wcnt[1] + wcnt[2] + wcnt[3];
    float ws = wsumA[0] + wsumA[1] + wsumA[2] + wsumA[3];
    int nnz = tot < CAP ? tot : CAP;
    int n = nnz;
    while ((n & 3) && n < CAP) { ellv[rb + n] = 0.f; ellc[rb + n] = 0; ++n; }
    rowlen[r] = n;
    float dw = rsqrtf(ws + 1.f), db = rsqrtf((float)nnz + 1.f);
    dinvw[r] = dw; dinvb[r] = db;
    dsh[0] = dw; dsh[1] = db;
  }
  __syncthreads();
  if (t < 64) {
    int c = t & 31, side = t >> 5;
    float v = 0.f;
    if (c < 30) {
      float x0 = x[r*3], x1 = x[r*3+1], x2 = x[r*3+2];
      const float* W = Win + side*90;
      v = (x0*W[c] + x1*W[30+c] + x2*W[60+c]) * dsh[side];
    }
    Hwb[(size_t)r*64 + t] = f2h(v);
  }
}

// Fused SpMM pair (levels 1,2), fp16 interleaved source. BN stats -> atomic buckets
// laid out [ch][64 copies][2], copy = blockIdx & 63 (8-way contention per address).
__global__ __launch_bounds__(256) void k_spmm_pair(
    const unsigned short* __restrict__ Hwb, const float* __restrict__ ellv,
    const unsigned short* __restrict__ ellc, const int* __restrict__ rowlen,
    const float* __restrict__ dinvw, const float* __restrict__ dinvb,
    float* __restrict__ Zw, float* __restrict__ Zb,
    float* __restrict__ bktW, float* __restrict__ bktB)
{
  __shared__ float zsW[32][32];
  __shared__ float zsB[32][32];
  int t = threadIdx.x;
  int gid = blockIdx.x * 256 + t;   // RTOT*8
  int row = gid >> 3, q = gid & 7;
  int side = q >> 2, sub = q & 3;
  int len = rowlen[row];
  const float4* ev = (const float4*)(ellv + (size_t)row * CAP);
  const uint2*  ec = (const uint2*) (ellc + (size_t)row * CAP);
  const uint4* HP = (const uint4*)(Hwb + (size_t)(row >> 11) * (NN*64));
  float acc[8] = {0,0,0,0,0,0,0,0};
  int nit = len >> 2;
  for (int i = 0; i < nit; ++i) {
    float4 v = ev[i];
    uint2 cc = ec[i];
    int c0 = cc.x & 0xffff, c1 = cc.x >> 16, c2 = cc.y & 0xffff, c3 = cc.y >> 16;
    uint4 g0 = HP[c0*8+q], g1 = HP[c1*8+q], g2 = HP[c2*8+q], g3 = HP[c3*8+q];
    float w0 = side ? (v.x>0.f?1.f:0.f) : v.x;
    float w1 = side ? (v.y>0.f?1.f:0.f) : v.y;
    float w2 = side ? (v.z>0.f?1.f:0.f) : v.z;
    float w3 = side ? (v.w>0.f?1.f:0.f) : v.w;
    ACC8(g0, w0); ACC8(g1, w1); ACC8(g2, w2); ACC8(g3, w3);
  }
  uint4 hs = HP[(row & (NN-1))*8 + q];
  ACC8(hs, 1.f);
  float d = side ? dinvb[row] : dinvw[row];
#pragma unroll
  for (int k = 0; k < 8; ++k) acc[k] *= d;
  float* Zp = (side ? Zb : Zw) + (size_t)row*32 + sub*8;
  float4 o0 = {acc[0],acc[1],acc[2],acc[3]}, o1 = {acc[4],acc[5],acc[6],acc[7]};
  ((float4*)Zp)[0] = o0; ((float4*)Zp)[1] = o1;
  int rowloc = t >> 3;
  float (*zs)[32] = side ? zsB : zsW;
#pragma unroll
  for (int k = 0; k < 8; ++k) zs[rowloc][sub*8+k] = acc[k];
  __syncthreads();
  int copy = blockIdx.x & 63;
  if (t < 30) {
    float s1 = 0.f, s2 = 0.f;
    for (int r = 0; r < 32; ++r) { float v = zsW[r][t]; s1 += v; s2 += v*v; }
    atomicAdd(&bktW[(t*64+copy)*2],   s1);
    atomicAdd(&bktW[(t*64+copy)*2+1], s2);
  } else if (t >= 64 && t < 94) {
    int c = t - 64;
    float s1 = 0.f, s2 = 0.f;
    for (int r = 0; r < 32; ++r) { float v = zsB[r][c]; s1 += v; s2 += v*v; }
    atomicAdd(&bktB[(c*64+copy)*2],   s1);
    atomicAdd(&bktB[(c*64+copy)*2+1], s2);
  }
}

// Level-3 merged SpMM: blocks [0,256) do the w-side (fp16 [row][32], 4 lanes/row),
// blocks [256,1088) do the b-side (fp16 [row][104], 13 lanes/row, self+scale).
// Stats -> atomic buckets: W3 [30][8][2], B3 [100][8][2].
__global__ __launch_bounds__(256) void k_spmm_l3(
    const unsigned short* __restrict__ Hw3, const unsigned short* __restrict__ Hb100,
    const float* __restrict__ ellv, const unsigned short* __restrict__ ellc,
    const int* __restrict__ rowlen, const float* __restrict__ dinvw,
    const float* __restrict__ dinvb, float* __restrict__ Zw, float* __restrict__ Zb,
    float* __restrict__ bktW3, float* __restrict__ bktB3)
{
  __shared__ float zs[64][32];
  __shared__ float st[200];
  int t = threadIdx.x;
  if (blockIdx.x < 256) {
    int gid = blockIdx.x * 256 + t;   // RTOT*4
    int row = gid >> 2, q = gid & 3;
    int len = rowlen[row];
    const float4* ev = (const float4*)(ellv + (size_t)row * CAP);
    const uint2*  ec = (const uint2*) (ellc + (size_t)row * CAP);
    const uint4* HP = (const uint4*)(Hw3 + (size_t)(row >> 11) * (NN*32));
    float acc[8] = {0,0,0,0,0,0,0,0};
    int nit = len >> 2;
    for (int i = 0; i < nit; ++i) {
      float4 v = ev[i];
      uint2 cc = ec[i];
      int c0 = cc.x & 0xffff, c1 = cc.x >> 16, c2 = cc.y & 0xffff, c3 = cc.y >> 16;
      uint4 g0 = HP[c0*4+q], g1 = HP[c1*4+q], g2 = HP[c2*4+q], g3 = HP[c3*4+q];
      ACC8(g0, v.x); ACC8(g1, v.y); ACC8(g2, v.z); ACC8(g3, v.w);
    }
    uint4 hs = HP[(row & (NN-1))*4 + q];
    ACC8(hs, 1.f);
    float d = dinvw[row];
#pragma unroll
    for (int k = 0; k < 8; ++k) acc[k] *= d;
    float* Zp = Zw + (size_t)row*32 + q*8;
    float4 o0 = {acc[0],acc[1],acc[2],acc[3]}, o1 = {acc[4],acc[5],acc[6],acc[7]};
    ((float4*)Zp)[0] = o0; ((float4*)Zp)[1] = o1;
    int rowloc = t >> 2;
#pragma unroll
    for (int k = 0; k < 8; ++k) zs[rowloc][q*8+k] = acc[k];
    __syncthreads();
    if (t < 30) {
      float s1 = 0.f, s2 = 0.f;
      for (int r = 0; r < 64; ++r) { float v = zs[r][t]; s1 += v; s2 += v*v; }
      int copy = blockIdx.x & 7;
      atomicAdd(&bktW3[(t*8+copy)*2],   s1);
      atomicAdd(&bktW3[(t*8+copy)*2+1], s2);
    }
  } else {
    int bid = blockIdx.x - 256;
    for (int i = t; i < 200; i += 256) st[i] = 0.f;
    __syncthreads();
    int gid = bid * 256 + t;   // RTOT*13 exactly (832*256)
    int row = gid / 13, q = gid - row*13;
    int len = rowlen[row];
    const float4* ev = (const float4*)(ellv + (size_t)row * CAP);
    const uint2*  ec = (const uint2*) (ellc + (size_t)row * CAP);
    const uint4* HP = (const uint4*)(Hb100 + (size_t)(row >> 11) * ((size_t)NN*104));
    float acc[8] = {0,0,0,0,0,0,0,0};
    int nit = len >> 2;
    for (int i = 0; i < nit; ++i) {
      float4 v = ev[i];
      uint2 cc = ec[i];
      int c0 = cc.x & 0xffff, c1 = cc.x >> 16, c2 = cc.y & 0xffff, c3 = cc.y >> 16;
      uint4 g0 = HP[c0*13+q], g1 = HP[c1*13+q], g2 = HP[c2*13+q], g3 = HP[c3*13+q];
      float w0 = (v.x>0.f?1.f:0.f), w1 = (v.y>0.f?1.f:0.f);
      float w2 = (v.z>0.f?1.f:0.f), w3 = (v.w>0.f?1.f:0.f);
      ACC8(g0, w0); ACC8(g1, w1); ACC8(g2, w2); ACC8(g3, w3);
    }
    uint4 hs = HP[(row & (NN-1))*13 + q];
    ACC8(hs, 1.f);
    float d = dinvb[row];
#pragma unroll
    for (int k = 0; k < 8; ++k) acc[k] *= d;
    float* Zp = Zb + (size_t)row*104 + q*8;
    float4 o0 = {acc[0],acc[1],acc[2],acc[3]}, o1 = {acc[4],acc[5],acc[6],acc[7]};
    ((float4*)Zp)[0] = o0; ((float4*)Zp)[1] = o1;
    int c0 = q*8;
#pragma unroll
    for (int k = 0; k < 8; ++k) {
      int ch = c0 + k;
      if (ch < 100) { atomicAdd(&st[ch*2], acc[k]); atomicAdd(&st[ch*2+1], acc[k]*acc[k]); }
    }
    __syncthreads();
    int copy = bid & 7;
    for (int i = t; i < 200; i += 256)
      atomicAdd(&bktB3[((i>>1)*8 + copy)*2 + (i&1)], st[i]);
  }
}

// apply BN (inline bucket reduce) -> store x/s -> next-layer weight GEMM -> fp16 outputs.
template<int LEVEL>
__global__ __launch_bounds__(256) void k_apply_gemm(
    const float* __restrict__ Zw, const float* __restrict__ bktW,
    const float* __restrict__ gW, const float* __restrict__ beW,
    float* __restrict__ xst, const float* __restrict__ Ww,
    const float* __restrict__ dinvw,
    const float* __restrict__ Zb, const float* __restrict__ bktB,
    const float* __restrict__ gB, const float* __restrict__ beB,
    float* __restrict__ sst, const float* __restrict__ Wb,
    const float* __restrict__ dinvb,
    unsigned short* __restrict__ HwOut, unsigned short* __restrict__ HbOut)
{
  constexpr int NGB = (LEVEL == 1) ? 8 : 26;
  constexpr int OSTRIDEB = (LEVEL == 1) ? 32 : 104;
  constexpr int NG = 8 + NGB;
  __shared__ float WwL[30*32];
  __shared__ float WbL[30*OSTRIDEB];
  __shared__ float awL[60], abL[60];
  int t = threadIdx.x;
  // inline finalize: reduce [ch][64][2] buckets
  if (t < 60) {
    int c = t % 30;
    bool isW = t < 30;
    const float4* p = (const float4*)((isW ? bktW : bktB) + c*128);
    float s1 = 0.f, s2 = 0.f;
#pragma unroll
    for (int k = 0; k < 32; ++k) { float4 v = p[k]; s1 += v.x + v.z; s2 += v.y + v.w; }
    float mean = s1/16384.f, var = s2/16384.f - mean*mean, inv = rsqrtf(var + 1e-5f);
    float aa = (isW ? gW : gB)[c]*inv;
    float* dst = isW ? awL : abL;
    dst[c] = aa; dst[30+c] = (isW ? beW : beB)[c] - mean*aa;
  }
  for (int idx = t; idx < 30*32; idx += 256) {
    int k = idx >> 5, c = idx & 31;
    WwL[idx] = (c < 30) ? Ww[k*30 + c] : 0.f;
  }
  if (LEVEL == 1) {
    for (int idx = t; idx < 30*32; idx += 256) {
      int k = idx >> 5, c = idx & 31;
      WbL[idx] = (c < 30) ? Wb[k*30 + c] : 0.f;
    }
  } else {
    for (int idx = t; idx < 30*OSTRIDEB; idx += 256) {
      int k = idx / OSTRIDEB, j = idx % OSTRIDEB;
      WbL[idx] = (j < 100) ? Wb[k*100 + j] : 0.f;
    }
  }
  __syncthreads();
  int gid = blockIdx.x * 256 + t;
  int row = gid / NG, g = gid % NG;
  if (g < 8) {
    const float4* Z4 = (const float4*)Zw + (size_t)row*8;
    float4 z4[8];
#pragma unroll
    for (int u = 0; u < 8; ++u) z4[u] = Z4[u];
    const float* z = (const float*)z4;
    float4 xv;
    int ch = 4*g;
    xv.x = (ch+0 < 30) ? awL[ch+0]*z[ch+0] + awL[30+ch+0] : 0.f;
    xv.y = (ch+1 < 30) ? awL[ch+1]*z[ch+1] + awL[30+ch+1] : 0.f;
    xv.z = (ch+2 < 30) ? awL[ch+2]*z[ch+2] + awL[30+ch+2] : 0.f;
    xv.w = (ch+3 < 30) ? awL[ch+3]*z[ch+3] + awL[30+ch+3] : 0.f;
    ((float4*)xst)[(size_t)row*8+g] = xv;
    float4 o = {0,0,0,0};
#pragma unroll
    for (int k = 0; k < 30; ++k) {
      float xk = awL[k]*z[k] + awL[30+k];
      float4 w = *(const float4*)(WwL + k*32 + 4*g);
      FMA4(o, xk, w);
    }
    float d = dinvw[row];
    us4 pv = { f2h(d*o.x), f2h(d*o.y), f2h(d*o.z), f2h(d*o.w) };
    unsigned short* dst = (LEVEL == 1) ? (HwOut + (size_t)row*64 + 4*g)
                                       : (HwOut + (size_t)row*32 + 4*g);
    *(us4*)dst = pv;
  } else {
    int gb = g - 8;
    const float4* Z4 = (const float4*)Zb + (size_t)row*8;
    float4 z4[8];
#pragma unroll
    for (int u = 0; u < 8; ++u) z4[u] = Z4[u];
    const float* z = (const float*)z4;
    if (gb < 8) {
      int ch = 4*gb;
      float4 sv;
      sv.x = (ch+0 < 30) ? abL[ch+0]*z[ch+0] + abL[30+ch+0] : 0.f;
      sv.y = (ch+1 < 30) ? abL[ch+1]*z[ch+1] + abL[30+ch+1] : 0.f;
      sv.z = (ch+2 < 30) ? abL[ch+2]*z[ch+2] + abL[30+ch+2] : 0.f;
      sv.w = (ch+3 < 30) ? abL[ch+3]*z[ch+3] + abL[30+ch+3] : 0.f;
      ((float4*)sst)[(size_t)row*8+gb] = sv;
    }
    float4 o = {0,0,0,0};
#pragma unroll
    for (int k = 0; k < 30; ++k) {
      float sk = abL[k]*z[k] + abL[30+k];
      float4 w = *(const float4*)(WbL + k*OSTRIDEB + 4*gb);
      FMA4(o, sk, w);
    }
    float d = dinvb[row];
    us4 pv = { f2h(d*o.x), f2h(d*o.y), f2h(d*o.z), f2h(d*o.w) };
    unsigned short* dst = (LEVEL == 1) ? (HbOut + (size_t)row*64 + 32 + 4*gb)
                                       : (HbOut + (size_t)row*104 + 4*gb);
    *(us4*)dst = pv;
  }
}

// fcpool with inline L3 finalize: BN(Z3w)->x13; s13=BN(Z3b); s1=[s11|s12|s13]@Wfc+bfc;
// fused softmax -> fp16 S [row][104]
__global__ __launch_bounds__(256) void k_fcpool(
    const float* __restrict__ Zw3, const float* __restrict__ bktW3,
    const float* __restrict__ gW3, const float* __restrict__ beW3,
    const float* __restrict__ Zb3, const float* __restrict__ bktB3,
    const float* __restrict__ g100, const float* __restrict__ be100,
    const float* __restrict__ s11, const float* __restrict__ s12,
    const float* __restrict__ Wfc, const float* __restrict__ bfc,
    float* __restrict__ x13, unsigned short* __restrict__ S)
{
  __shared__ float shm[14240];   // feat 64x160 = 10240 | Wl 40x100 = 4000
  __shared__ float aw3[60], ab3[200];
  float* feat = shm;
  float* Wl = shm + 10240;
  int t = threadIdx.x;
  int g0 = blockIdx.x * 64;
  if (t < 30) {
    const float4* p = (const float4*)(bktW3 + t*16);
    float s1 = 0.f, s2 = 0.f;
#pragma unroll
    for (int k = 0; k < 4; ++k) { float4 v = p[k]; s1 += v.x + v.z; s2 += v.y + v.w; }
    float mean = s1/16384.f, var = s2/16384.f - mean*mean, inv = rsqrtf(var + 1e-5f);
    float aa = gW3[t]*inv; aw3[t] = aa; aw3[30+t] = beW3[t] - mean*aa;
  } else if (t >= 64 && t < 164) {
    int c = t - 64;
    const float4* p = (const float4*)(bktB3 + c*16);
    float s1 = 0.f, s2 = 0.f;
#pragma unroll
    for (int k = 0; k < 4; ++k) { float4 v = p[k]; s1 += v.x + v.z; s2 += v.y + v.w; }
    float mean = s1/16384.f, var = s2/16384.f - mean*mean, inv = rsqrtf(var + 1e-5f);
    float aa = g100[c]*inv; ab3[c] = aa; ab3[100+c] = be100[c] - mean*aa;
  }
  __syncthreads();
  for (int idx = t; idx < 64*160; idx += 256) {
    int l = idx / 160, c = idx % 160;
    int g = g0 + l;
    float v;
    if (c < 30) v = s11[(size_t)g*32 + c];
    else if (c < 60) v = s12[(size_t)g*32 + (c-30)];
    else { int k = c - 60; v = ab3[k]*Zb3[(size_t)g*104 + k] + ab3[100 + k]; }
    feat[l*160 + c] = v;
  }
  for (int idx = t; idx < 64*32; idx += 256) {
    int l = idx >> 5, c = idx & 31;
    int g = g0 + l;
    x13[(size_t)g*32+c] = (c < 30) ? aw3[c]*Zw3[(size_t)g*32+c] + aw3[30+c] : 0.f;
  }
  int np = t >> 3, kg = t & 7;
  int n0 = np*2, n1 = np*2 + 1;
  int kbase = kg*12 + (kg < 4 ? kg : 4);
  int klen  = kg < 4 ? 13 : 12;
  float a0[13], a1[13];
#pragma unroll
  for (int j = 0; j < 13; ++j) { a0[j] = 0.f; a1[j] = 0.f; }
  for (int ch = 0; ch < 4; ++ch) {
    __syncthreads();
    for (int idx = t; idx < 4000; idx += 256) {
      int r = idx/100, j = idx%100;
      Wl[r*100 + j] = Wfc[(ch*40 + r)*100 + j];
    }
    __syncthreads();
    for (int kk = 0; kk < 40; ++kk) {
      float f0 = feat[n0*160 + ch*40+kk];
      float f1 = feat[n1*160 + ch*40+kk];
#pragma unroll
      for (int j = 0; j < 13; ++j) {
        if (j < klen) {
          float w = Wl[kk*100 + kbase + j];
          a0[j] += f0*w; a1[j] += f1*w;
        }
      }
    }
  }
  __syncthreads();
  float* sRow = shm;  // reuse as [64][100]
  for (int j = 0; j < klen; ++j) {
    int k = kbase + j;
    sRow[n0*100 + k] = a0[j] + bfc[k];
    sRow[n1*100 + k] = a1[j] + bfc[k];
  }
  __syncthreads();
  int n = t >> 2, part = t & 3;
  int i0 = part*25;
  float m = -3.4e38f;
  for (int i = 0; i < 25; ++i) m = fmaxf(m, sRow[n*100 + i0 + i]);
  m = fmaxf(m, __shfl_xor(m, 1));
  m = fmaxf(m, __shfl_xor(m, 2));
  float ev[25]; float s = 0.f;
  for (int i = 0; i < 25; ++i) { float e = __expf(sRow[n*100 + i0 + i] - m); ev[i] = e; s += e; }
  s += __shfl_xor(s, 1);
  s += __shfl_xor(s, 2);
  float rinv = 1.f / s;
  for (int i = 0; i < 25; ++i) S[(size_t)(g0+n)*104 + i0 + i] = f2h(ev[i] * rinv);
  if (part == 3) {
    S[(size_t)(g0+n)*104 + 100] = 0; S[(size_t)(g0+n)*104 + 101] = 0;
    S[(size_t)(g0+n)*104 + 102] = 0; S[(size_t)(g0+n)*104 + 103] = 0;
  }
}

// As = adj @ S (weighted, no self, no scale): fp16 S [row][104], 13 lanes/row.
__global__ __launch_bounds__(256) void k_spmm_as(
    const unsigned short* __restrict__ S, const float* __restrict__ ellv,
    const unsigned short* __restrict__ ellc, const int* __restrict__ rowlen,
    float* __restrict__ Z)
{
  int t = threadIdx.x;
  int gid = blockIdx.x * 256 + t;
  int row = gid / 13, q = gid - row*13;
  int len = rowlen[row];
  const float4* ev = (const float4*)(ellv + (size_t)row * CAP);
  const uint2*  ec = (const uint2*) (ellc + (size_t)row * CAP);
  const uint4* HP = (const uint4*)(S + (size_t)(row >> 11) * ((size_t)NN*104));
  float acc[8] = {0,0,0,0,0,0,0,0};
  int nit = len >> 2;
  for (int i = 0; i < nit; ++i) {
    float4 v = ev[i];
    uint2 cc = ec[i];
    int c0 = cc.x & 0xffff, c1 = cc.x >> 16, c2 = cc.y & 0xffff, c3 = cc.y >> 16;
    uint4 g0 = HP[c0*13+q], g1 = HP[c1*13+q], g2 = HP[c2*13+q], g3 = HP[c3*13+q];
    ACC8(g0, v.x); ACC8(g1, v.y); ACC8(g2, v.z); ACC8(g3, v.w);
  }
  float* Zp = Z + (size_t)row*104 + q*8;
  float4 o0 = {acc[0],acc[1],acc[2],acc[3]}, o1 = {acc[4],acc[5],acc[6],acc[7]};
  ((float4*)Zp)[0] = o0; ((float4*)Zp)[1] = o1;
}

// pooled partials + FUSED stage-1 column max (same 256-row partition as old max1).
__global__ __launch_bounds__(256) void k_pool_part(
    const unsigned short* __restrict__ S, const float* __restrict__ x13,
    const float* __restrict__ As, const float* __restrict__ x11,
    const float* __restrict__ x12, float* __restrict__ pp, float* __restrict__ pm)
{
  __shared__ float sL[64][100];
  __shared__ float xL[64][132];
  __shared__ float red[256];
  int t = threadIdx.x;
  int b = blockIdx.x >> 3, chunk = blockIdx.x & 7;
  int g00 = b * 2048 + chunk * 256;
  int kt = t/10, dt = t%10;
  int k0 = kt*4, d0 = dt*13;
  float acc[4][13];
#pragma unroll
  for (int a = 0; a < 4; ++a)
#pragma unroll
    for (int j = 0; j < 13; ++j) acc[a][j] = 0.f;
  for (int tile = 0; tile < 4; ++tile) {
    int g0 = g00 + tile*64;
    __syncthreads();
    for (int idx = t; idx < 64*100; idx += 256) {
      int l = idx/100, k = idx%100;
      sL[l][k] = h2f(S[(size_t)(g0+l)*104 + k]);
    }
    for (int idx = t; idx < 64*130; idx += 256) {
      int l = idx/130, d = idx%130;
      xL[l][d] = d < 30 ? x13[(size_t)(g0+l)*32 + d] : As[(size_t)(g0+l)*104 + (d-30)];
    }
    __syncthreads();
    if (t < 250) {
      for (int kk = 0; kk < 64; ++kk) {
        float sv[4];
#pragma unroll
        for (int a = 0; a < 4; ++a) sv[a] = sL[kk][k0+a];
#pragma unroll
        for (int j = 0; j < 13; ++j) {
          float xv = xL[kk][d0+j];
#pragma unroll
          for (int a = 0; a < 4; ++a) acc[a][j] += sv[a]*xv;
        }
      }
    }
  }
  if (t < 250) {
    float* dst = pp + (size_t)blockIdx.x * 13000;
    for (int a = 0; a < 4; ++a)
      for (int j = 0; j < 13; ++j)
        dst[(k0+a)*130 + (d0+j)] = acc[a][j];
  }
  // fused stage-1 col-max over this block's 256 rows
  __syncthreads();
  {
    int c = t & 31, rg = t >> 5;
    const float* srcs[3] = {x11, x12, x13};
    for (int a = 0; a < 3; ++a) {
      const float* p = srcs[a] + (size_t)(g00+rg)*32 + c;
      float m = -3.4e38f;
      for (int it = 0; it < 32; ++it) m = fmaxf(m, p[it*256]);
      red[t] = m;
      __syncthreads();
      if (t < 30) {
        float mm = red[t];
        for (int g = 1; g < 8; ++g) mm = fmaxf(mm, red[g*32+t]);
        pm[(size_t)blockIdx.x*90 + a*30 + t] = mm;
      }
      __syncthreads();
    }
  }
}

// Fully fused stage 2: pool-reduce + A2 normalize + 3 GCN+BN layers + readout MLP.
// 8 blocks (always co-resident), device-atomic grid barrier for the 3 BN syncs.
// A2 kept as fp16 in LDS; per-batch state never leaves LDS.
__global__ __launch_bounds__(256) void k_s2fused(
    const float* __restrict__ pp, const float* __restrict__ partmax,
    const float* __restrict__ Wm,    // W3030 + 3*900 (3 consecutive 30x30)
    const float* __restrict__ g30,   // g30 + 150
    const float* __restrict__ be30,  // be30 + 150
    float* __restrict__ bktS2,       // [3][30][2] (zeroed)
    int* __restrict__ cnt,           // zeroed barrier counter
    const float* __restrict__ W1, const float* __restrict__ b1,
    const float* __restrict__ W2, const float* __restrict__ b2,
    float* __restrict__ out)
{
  __shared__ unsigned short A2h[10000];
  __shared__ float buf1[3000];
  __shared__ float buf2[3000];
  __shared__ float dl[100];
  __shared__ float st1[30], st2[30];
  __shared__ float coef[60];
  __shared__ float x1L[90], x2L[90], hh[50];
  int b = blockIdx.x, t = threadIdx.x;
  // pool-reduce: Xpool -> buf1, raw pooled adj -> A2h (fp16)
  for (int idx = t; idx < 13000; idx += 256) {
    float s = 0.f;
    for (int ch = 0; ch < 8; ++ch) s += pp[(size_t)(b*8 + ch)*13000 + idx];
    int k = idx/130, d = idx%130;
    if (d < 30) buf1[k*30 + d] = s;
    else A2h[k*100 + (d-30)] = f2h(s);
  }
  __syncthreads();
  if (t < 100 && h2f(A2h[t*101]) == 0.f) A2h[t*101] = f2h(1.f);
  __syncthreads();
  if (t < 100) {
    float s = 0.f;
    for (int j = 0; j < 100; ++j) s += h2f(A2h[t*100 + j]);
    dl[t] = s > 0.f ? rsqrtf(s) : 0.f;
  }
  __syncthreads();
  for (int idx = t; idx < 10000; idx += 256) {
    int i = idx/100, j = idx%100;
    A2h[idx] = f2h(dl[i]*dl[j]*h2f(A2h[idx]));
  }
  for (int L = 0; L < 3; ++L) {
    if (t < 30) { st1[t] = 0.f; st2[t] = 0.f; }
    __syncthreads();
    // T = X @ W  (buf1 -> buf2)
    const float* W = Wm + L*900;
    for (int idx = t; idx < 3000; idx += 256) {
      int i = idx/30, c = idx%30;
      float a = 0.f;
      for (int k = 0; k < 30; ++k) a += buf1[i*30+k]*W[k*30+c];
      buf2[idx] = a;
    }
    __syncthreads();
    // Z = A2 @ T  (-> buf1) + LDS stats
    for (int idx = t; idx < 3000; idx += 256) {
      int i = idx/30, c = idx%30;
      float a = 0.f;
      for (int j = 0; j < 100; ++j) a += h2f(A2h[i*100+j]) * buf2[j*30+c];
      buf1[idx] = a;
      atomicAdd(&st1[c], a);
      atomicAdd(&st2[c], a*a);
    }
    __syncthreads();
    if (t < 30) {
      atomicAdd(&bktS2[(L*30+t)*2],   st1[t]);
      atomicAdd(&bktS2[(L*30+t)*2+1], st2[t]);
    }
    // grid barrier (8 blocks co-resident; atomics are device-coherent)
    __syncthreads();
    if (t == 0) {
      __threadfence();
      atomicAdd(cnt, 1);
      while (atomicAdd(cnt, 0) < (L+1)*8) {}
      __threadfence();
    }
    __syncthreads();
    if (t < 30) {
      float s1 = atomicAdd(&bktS2[(L*30+t)*2],   0.f);
      float s2 = atomicAdd(&bktS2[(L*30+t)*2+1], 0.f);
      float mean = s1/800.f, var = s2/800.f - mean*mean, inv = rsqrtf(var + 1e-5f);
      float aa = g30[L*30+t]*inv;
      coef[t] = aa; coef[30+t] = be30[L*30+t] - mean*aa;
    }
    __syncthreads();
    if (L < 2) {
      for (int idx = t; idx < 3000; idx += 256) {
        int c = idx % 30;
        buf1[idx] = coef[c]*buf1[idx] + coef[30+c];
      }
      __syncthreads();
      if (t < 30) {
        float m = -3.4e38f;
        for (int i = 0; i < 100; ++i) m = fmaxf(m, buf1[i*30+t]);
        x2L[L*30+t] = m;
      }
    } else {
      if (t < 30) {
        float m = -3.4e38f;
        for (int i = 0; i < 100; ++i) m = fmaxf(m, coef[t]*buf1[i*30+t] + coef[30+t]);
        x2L[60+t] = m;
      }
    }
  }
  if (t < 90) {
    float m = -3.4e38f;
    for (int s = 0; s < 8; ++s) m = fmaxf(m, partmax[(size_t)(b*8+s)*90 + t]);
    x1L[t] = m;
  }
  __syncthreads();
  if (t < 50) {
    float a = b1[t];
    for (int k = 0; k < 90; ++k) a += x1L[k]*W1[k*50+t];
    for (int k = 0; k < 90; ++k) a += x2L[k]*W1[(90+k)*50+t];
    hh[t] = fmaxf(a, 0.f);
  }
  __syncthreads();
  if (t < 6) {
    float a = b2[t];
    for (int j = 0; j < 50; ++j) a += hh[j]*W2[j*6+t];
    out[b*6+t] = a;
  }
}

// ---------------- launcher ----------------
extern "C" void kernel_launch(void* const* d_in, const int* in_sizes, int n_in,
                              void* d_out, int out_size, void* d_ws, size_t ws_size,
                              hipStream_t stream)
{
  const float* x    = (const float*)d_in[0];
  const float* adj  = (const float*)d_in[1];
  const float* Win  = (const float*)d_in[2];
  const float* W3030= (const float*)d_in[3];
  const float* Wp13 = (const float*)d_in[4];
  // d_in[5]=b30, d_in[6]=b100: cancel through training-mode BN -> unused
  const float* Wfc  = (const float*)d_in[7];
  const float* bfc  = (const float*)d_in[8];
  const float* W1   = (const float*)d_in[9];
  const float* b1   = (const float*)d_in[10];
  const float* W2   = (const float*)d_in[11];
  const float* b2   = (const float*)d_in[12];
  const float* g30  = (const float*)d_in[13];
  const float* be30 = (const float*)d_in[14];
  const float* g100 = (const float*)d_in[15];
  const float* be100= (const float*)d_in[16];
  float* out = (float*)d_out;

  float* wsf = (float*)d_ws;
  float* bL1W = wsf + OF_B1W;  float* bL1B = wsf + OF_B1B;
  float* bL2W = wsf + OF_B2W;  float* bL2B = wsf + OF_B2B;
  float* bL3W = wsf + OF_B3W;  float* bL3B = wsf + OF_B3B;
  float* bktS2 = wsf + OF_S2;
  int*   cnt  = (int*)(wsf + OF_CNT);
  float* ellv  = wsf + OF_ELLV;
  unsigned short* ellc = (unsigned short*)(wsf + OF_ELLC);
  int*   rowlen = (int*)(wsf + OF_ROWLEN);
  float* dinvw = wsf + OF_DINVW;
  float* dinvb = wsf + OF_DINVB;
  unsigned short* Hwb   = (unsigned short*)(wsf + OF_HWB);
  unsigned short* Hw3   = (unsigned short*)(wsf + OF_HW3);
  unsigned short* Hb100 = (unsigned short*)(wsf + OF_HB100);
  unsigned short* S     = Hb100;   // S reuses HB100 (dead after L3-b spmm)
  float* Zw = wsf + OF_ZW;
  float* Zb = wsf + OF_ZB;         // stride 104; later reused as As
  float* x11 = wsf + OF_X11;
  float* x12 = wsf + OF_X12;
  float* x13 = wsf + OF_X13;
  float* s11 = wsf + OF_S11;
  float* s12 = wsf + OF_S12;
  float* pp  = wsf + OF_S11;       // pool partials reuse s11+s12 (dead after fcpool)
  float* partmax = wsf + OF_PARTMAX;

  // 10 dispatches total (was 18) — pipeline is dispatch-overhead-bound (~25us each).
  k_build_ell<<<RTOT, 256, 0, stream>>>(adj, x, Win, ellv, ellc, rowlen, dinvw, dinvb, Hwb, wsf);

  k_spmm_pair<<<512, 256, 0, stream>>>(Hwb, ellv, ellc, rowlen, dinvw, dinvb, Zw, Zb, bL1W, bL1B);
  k_apply_gemm<1><<<1024, 256, 0, stream>>>(Zw, bL1W, g30+0, be30+0, x11, W3030+0, dinvw,
                                            Zb, bL1B, g30+90, be30+90, s11, W3030+2*900, dinvb, Hwb, Hwb);

  k_spmm_pair<<<512, 256, 0, stream>>>(Hwb, ellv, ellc, rowlen, dinvw, dinvb, Zw, Zb, bL2W, bL2B);
  k_apply_gemm<2><<<2176, 256, 0, stream>>>(Zw, bL2W, g30+30, be30+30, x12, W3030+900, dinvw,
                                            Zb, bL2B, g30+120, be30+120, s12, Wp13, dinvb, Hw3, Hb100);

  k_spmm_l3<<<1088, 256, 0, stream>>>(Hw3, Hb100, ellv, ellc, rowlen, dinvw, dinvb, Zw, Zb, bL3W, bL3B);
  k_fcpool<<<256, 256, 0, stream>>>(Zw, bL3W, g30+60, be30+60, Zb, bL3B, g100, be100,
                                    s11, s12, Wfc, bfc, x13, S);

  k_spmm_as<<<832, 256, 0, stream>>>(S, ellv, ellc, rowlen, Zb /* As */);
  k_pool_part<<<64, 256, 0, stream>>>(S, x13, Zb, x11, x12, pp, partmax);

  k_s2fused<<<BATCH, 256, 0, stream>>>(pp, partmax, W3030+3*900, g30+150, be30+150,
                                       bktS2, cnt, W1, b1, W2, b2, out);
}

// Round 10
// 655.760 us; speedup vs baseline: 2.6684x; 1.0653x over previous
//
#include <hip/hip_runtime.h>
#include <hip/hip_fp16.h>
#include <cstdint>
#include <cstddef>

#define BATCH 8
#define NN 2048
#define RTOT 16384   // BATCH*NN
#define CAP 176      // ELL row capacity

// ---------------- workspace layout (offsets in floats) ----------------
// Bucket regions + barrier counter live at the front and are zeroed by k_build_ell.
static constexpr size_t OF_B1W   = 0;         // [30][64][2] = 3840
static constexpr size_t OF_B1B   = 3840;
static constexpr size_t OF_B2W   = 7680;
static constexpr size_t OF_B2B   = 11520;
static constexpr size_t OF_B3W   = 15360;     // [30][8][2] = 480
static constexpr size_t OF_B3B   = 15840;     // [100][8][2] = 1600
static constexpr size_t OF_S2    = 17440;     // [3][30][2] = 180
static constexpr size_t OF_CNT   = 17620;     // int barrier counter (+pad)
static constexpr size_t ZEND     = 17632;     // zero range [0, ZEND)
static constexpr size_t OF_ELLV  = 17664;                     // fp32 16384*176
static constexpr size_t OF_ELLC  = OF_ELLV + 2883584;         // u16 16384*176 = 1441792 floats
static constexpr size_t OF_ROWLEN= OF_ELLC + 1441792;
static constexpr size_t OF_DINVW = OF_ROWLEN + 16384;
static constexpr size_t OF_DINVB = OF_DINVW + 16384;
static constexpr size_t OF_HWB   = OF_DINVB + 16384;          // fp16 [RTOT][64]  = 524288 floats
static constexpr size_t OF_HW3   = OF_HWB + 524288;           // fp16 [RTOT][32]  = 262144 floats
static constexpr size_t OF_HB100 = OF_HW3 + 262144;           // fp16 [RTOT][104] = 851968 floats (reused as S)
static constexpr size_t OF_ZW    = OF_HB100 + 851968;         // fp32 stride 32
static constexpr size_t OF_ZB    = OF_ZW + 524288;            // fp32 stride 104 (reused as As)
static constexpr size_t OF_X11   = OF_ZB + 1703936;           // fp32 stride 32
static constexpr size_t OF_X12   = OF_X11 + 524288;
static constexpr size_t OF_X13   = OF_X12 + 524288;
static constexpr size_t OF_S11   = OF_X13 + 524288;           // s11+s12 reused as pool partials pp
static constexpr size_t OF_S12   = OF_S11 + 524288;
static constexpr size_t OF_PARTMAX = OF_S12 + 524288;         // 64*90

#define FMA4(acc, s, h) { acc.x += (s)*(h).x; acc.y += (s)*(h).y; acc.z += (s)*(h).z; acc.w += (s)*(h).w; }

__device__ __forceinline__ unsigned short f2h(float f) {
  _Float16 h = (_Float16)f;
  return *(unsigned short*)&h;
}
__device__ __forceinline__ float h2f(unsigned short s) {
  _Float16 h = *(_Float16*)&s;
  return (float)h;
}
__device__ __forceinline__ float2 h2f2(unsigned int u) {
  __half2 h = *(__half2*)&u;
  return __half22float2(h);
}

struct __align__(8) us4 { unsigned short x, y, z, w; };

// accumulate 8 fp16 channels (one uint4 = 8 fp16) into acc[8] with weight wt
#define ACC8(g, wt) { \
  float2 f0=h2f2((g).x), f1=h2f2((g).y), f2=h2f2((g).z), f3=h2f2((g).w); \
  acc[0] += (wt)*f0.x; acc[1] += (wt)*f0.y; acc[2] += (wt)*f1.x; acc[3] += (wt)*f1.y; \
  acc[4] += (wt)*f2.x; acc[5] += (wt)*f2.y; acc[6] += (wt)*f3.x; acc[7] += (wt)*f3.y; }

// ---------------- kernels ----------------

// One pass over adj: zero bucket/counter region, build ELL (scan-based compaction),
// degrees, FUSED H1 (fp16 interleaved [row][64]).
__global__ __launch_bounds__(256) void k_build_ell(
    const float* __restrict__ adj, const float* __restrict__ x,
    const float* __restrict__ Win, float* __restrict__ ellv,
    unsigned short* __restrict__ ellc, int* __restrict__ rowlen,
    float* __restrict__ dinvw, float* __restrict__ dinvb,
    unsigned short* __restrict__ Hwb, float* __restrict__ zbase)
{
  int r = blockIdx.x;
  int t = threadIdx.x, lane = t & 63, wv = t >> 6;
  if (blockIdx.x < 69) {
    int zi = blockIdx.x * 256 + t;
    if (zi < (int)ZEND) zbase[zi] = 0.f;
  }
  const float* row = adj + (size_t)r * NN;
  __shared__ int wcnt[4];
  __shared__ float wsumA[4];
  __shared__ float dsh[2];
  float4 a = ((const float4*)row)[t];
  float4 b = ((const float4*)row)[256 + t];
  float vals[8] = {a.x, a.y, a.z, a.w, b.x, b.y, b.z, b.w};
  int cbase0 = t*4, cbase1 = 1024 + t*4;
  int cnt = 0; float sum = 0.f;
#pragma unroll
  for (int k = 0; k < 8; ++k) { sum += vals[k]; cnt += (vals[k] != 0.f) ? 1 : 0; }
  int pre = cnt;
#pragma unroll
  for (int o = 1; o < 64; o <<= 1) { int n = __shfl_up(pre, o); if (lane >= o) pre += n; }
  int excl = pre - cnt;
  int wtot = __shfl(pre, 63);
#pragma unroll
  for (int o = 32; o; o >>= 1) sum += __shfl_down(sum, o);
  if (lane == 0) { wcnt[wv] = wtot; wsumA[wv] = sum; }
  __syncthreads();
  int base = 0;
  for (int w = 0; w < wv; ++w) base += wcnt[w];
  int p = base + excl;
  size_t rb = (size_t)r * CAP;
#pragma unroll
  for (int k = 0; k < 8; ++k) {
    float v = vals[k];
    if (v != 0.f && p < CAP) {
      ellv[rb + p] = v;
      ellc[rb + p] = (unsigned short)((k < 4) ? (cbase0 + k) : (cbase1 + (k - 4)));
      ++p;
    }
  }
  if (t == 0) {
    int tot = wcnt[0] + wcnt[1] + wcnt[2] + wcnt[3];
    float ws = wsumA[0] + wsumA[1] + wsumA[2] + wsumA[3];
    int nnz = tot < CAP ? tot : CAP;
    int n = nnz;
    while ((n & 3) && n < CAP) { ellv[rb + n] = 0.f; ellc[rb + n] = 0; ++n; }
    rowlen[r] = n;
    float dw = rsqrtf(ws + 1.f), db = rsqrtf((float)nnz + 1.f);
    dinvw[r] = dw; dinvb[r] = db;
    dsh[0] = dw; dsh[1] = db;
  }
  __syncthreads();
  if (t < 64) {
    int c = t & 31, side = t >> 5;
    float v = 0.f;
    if (c < 30) {
      float x0 = x[r*3], x1 = x[r*3+1], x2 = x[r*3+2];
      const float* W = Win + side*90;
      v = (x0*W[c] + x1*W[30+c] + x2*W[60+c]) * dsh[side];
    }
    Hwb[(size_t)r*64 + t] = f2h(v);
  }
}

// Fused SpMM pair (levels 1,2), fp16 interleaved source. BN stats -> atomic buckets
// laid out [ch][64 copies][2], copy = blockIdx & 63.
__global__ __launch_bounds__(256) void k_spmm_pair(
    const unsigned short* __restrict__ Hwb, const float* __restrict__ ellv,
    const unsigned short* __restrict__ ellc, const int* __restrict__ rowlen,
    const float* __restrict__ dinvw, const float* __restrict__ dinvb,
    float* __restrict__ Zw, float* __restrict__ Zb,
    float* __restrict__ bktW, float* __restrict__ bktB)
{
  __shared__ float zsW[32][32];
  __shared__ float zsB[32][32];
  int t = threadIdx.x;
  int gid = blockIdx.x * 256 + t;   // RTOT*8
  int row = gid >> 3, q = gid & 7;
  int side = q >> 2, sub = q & 3;
  int len = rowlen[row];
  const float4* ev = (const float4*)(ellv + (size_t)row * CAP);
  const uint2*  ec = (const uint2*) (ellc + (size_t)row * CAP);
  const uint4* HP = (const uint4*)(Hwb + (size_t)(row >> 11) * (NN*64));
  float acc[8] = {0,0,0,0,0,0,0,0};
  int nit = len >> 2;
  for (int i = 0; i < nit; ++i) {
    float4 v = ev[i];
    uint2 cc = ec[i];
    int c0 = cc.x & 0xffff, c1 = cc.x >> 16, c2 = cc.y & 0xffff, c3 = cc.y >> 16;
    uint4 g0 = HP[c0*8+q], g1 = HP[c1*8+q], g2 = HP[c2*8+q], g3 = HP[c3*8+q];
    float w0 = side ? (v.x>0.f?1.f:0.f) : v.x;
    float w1 = side ? (v.y>0.f?1.f:0.f) : v.y;
    float w2 = side ? (v.z>0.f?1.f:0.f) : v.z;
    float w3 = side ? (v.w>0.f?1.f:0.f) : v.w;
    ACC8(g0, w0); ACC8(g1, w1); ACC8(g2, w2); ACC8(g3, w3);
  }
  uint4 hs = HP[(row & (NN-1))*8 + q];
  ACC8(hs, 1.f);
  float d = side ? dinvb[row] : dinvw[row];
#pragma unroll
  for (int k = 0; k < 8; ++k) acc[k] *= d;
  float* Zp = (side ? Zb : Zw) + (size_t)row*32 + sub*8;
  float4 o0 = {acc[0],acc[1],acc[2],acc[3]}, o1 = {acc[4],acc[5],acc[6],acc[7]};
  ((float4*)Zp)[0] = o0; ((float4*)Zp)[1] = o1;
  int rowloc = t >> 3;
  float (*zs)[32] = side ? zsB : zsW;
#pragma unroll
  for (int k = 0; k < 8; ++k) zs[rowloc][sub*8+k] = acc[k];
  __syncthreads();
  int copy = blockIdx.x & 63;
  if (t < 30) {
    float s1 = 0.f, s2 = 0.f;
    for (int r = 0; r < 32; ++r) { float v = zsW[r][t]; s1 += v; s2 += v*v; }
    atomicAdd(&bktW[(t*64+copy)*2],   s1);
    atomicAdd(&bktW[(t*64+copy)*2+1], s2);
  } else if (t >= 64 && t < 94) {
    int c = t - 64;
    float s1 = 0.f, s2 = 0.f;
    for (int r = 0; r < 32; ++r) { float v = zsB[r][c]; s1 += v; s2 += v*v; }
    atomicAdd(&bktB[(c*64+copy)*2],   s1);
    atomicAdd(&bktB[(c*64+copy)*2+1], s2);
  }
}

// Level-3 merged SpMM: blocks [0,256) w-side, [256,1088) b-side.
__global__ __launch_bounds__(256) void k_spmm_l3(
    const unsigned short* __restrict__ Hw3, const unsigned short* __restrict__ Hb100,
    const float* __restrict__ ellv, const unsigned short* __restrict__ ellc,
    const int* __restrict__ rowlen, const float* __restrict__ dinvw,
    const float* __restrict__ dinvb, float* __restrict__ Zw, float* __restrict__ Zb,
    float* __restrict__ bktW3, float* __restrict__ bktB3)
{
  __shared__ float zs[64][32];
  __shared__ float st[200];
  int t = threadIdx.x;
  if (blockIdx.x < 256) {
    int gid = blockIdx.x * 256 + t;   // RTOT*4
    int row = gid >> 2, q = gid & 3;
    int len = rowlen[row];
    const float4* ev = (const float4*)(ellv + (size_t)row * CAP);
    const uint2*  ec = (const uint2*) (ellc + (size_t)row * CAP);
    const uint4* HP = (const uint4*)(Hw3 + (size_t)(row >> 11) * (NN*32));
    float acc[8] = {0,0,0,0,0,0,0,0};
    int nit = len >> 2;
    for (int i = 0; i < nit; ++i) {
      float4 v = ev[i];
      uint2 cc = ec[i];
      int c0 = cc.x & 0xffff, c1 = cc.x >> 16, c2 = cc.y & 0xffff, c3 = cc.y >> 16;
      uint4 g0 = HP[c0*4+q], g1 = HP[c1*4+q], g2 = HP[c2*4+q], g3 = HP[c3*4+q];
      ACC8(g0, v.x); ACC8(g1, v.y); ACC8(g2, v.z); ACC8(g3, v.w);
    }
    uint4 hs = HP[(row & (NN-1))*4 + q];
    ACC8(hs, 1.f);
    float d = dinvw[row];
#pragma unroll
    for (int k = 0; k < 8; ++k) acc[k] *= d;
    float* Zp = Zw + (size_t)row*32 + q*8;
    float4 o0 = {acc[0],acc[1],acc[2],acc[3]}, o1 = {acc[4],acc[5],acc[6],acc[7]};
    ((float4*)Zp)[0] = o0; ((float4*)Zp)[1] = o1;
    int rowloc = t >> 2;
#pragma unroll
    for (int k = 0; k < 8; ++k) zs[rowloc][q*8+k] = acc[k];
    __syncthreads();
    if (t < 30) {
      float s1 = 0.f, s2 = 0.f;
      for (int r = 0; r < 64; ++r) { float v = zs[r][t]; s1 += v; s2 += v*v; }
      int copy = blockIdx.x & 7;
      atomicAdd(&bktW3[(t*8+copy)*2],   s1);
      atomicAdd(&bktW3[(t*8+copy)*2+1], s2);
    }
  } else {
    int bid = blockIdx.x - 256;
    for (int i = t; i < 200; i += 256) st[i] = 0.f;
    __syncthreads();
    int gid = bid * 256 + t;   // RTOT*13 exactly (832*256)
    int row = gid / 13, q = gid - row*13;
    int len = rowlen[row];
    const float4* ev = (const float4*)(ellv + (size_t)row * CAP);
    const uint2*  ec = (const uint2*) (ellc + (size_t)row * CAP);
    const uint4* HP = (const uint4*)(Hb100 + (size_t)(row >> 11) * ((size_t)NN*104));
    float acc[8] = {0,0,0,0,0,0,0,0};
    int nit = len >> 2;
    for (int i = 0; i < nit; ++i) {
      float4 v = ev[i];
      uint2 cc = ec[i];
      int c0 = cc.x & 0xffff, c1 = cc.x >> 16, c2 = cc.y & 0xffff, c3 = cc.y >> 16;
      uint4 g0 = HP[c0*13+q], g1 = HP[c1*13+q], g2 = HP[c2*13+q], g3 = HP[c3*13+q];
      float w0 = (v.x>0.f?1.f:0.f), w1 = (v.y>0.f?1.f:0.f);
      float w2 = (v.z>0.f?1.f:0.f), w3 = (v.w>0.f?1.f:0.f);
      ACC8(g0, w0); ACC8(g1, w1); ACC8(g2, w2); ACC8(g3, w3);
    }
    uint4 hs = HP[(row & (NN-1))*13 + q];
    ACC8(hs, 1.f);
    float d = dinvb[row];
#pragma unroll
    for (int k = 0; k < 8; ++k) acc[k] *= d;
    float* Zp = Zb + (size_t)row*104 + q*8;
    float4 o0 = {acc[0],acc[1],acc[2],acc[3]}, o1 = {acc[4],acc[5],acc[6],acc[7]};
    ((float4*)Zp)[0] = o0; ((float4*)Zp)[1] = o1;
    int c0 = q*8;
#pragma unroll
    for (int k = 0; k < 8; ++k) {
      int ch = c0 + k;
      if (ch < 100) { atomicAdd(&st[ch*2], acc[k]); atomicAdd(&st[ch*2+1], acc[k]*acc[k]); }
    }
    __syncthreads();
    int copy = bid & 7;
    for (int i = t; i < 200; i += 256)
      atomicAdd(&bktB3[((i>>1)*8 + copy)*2 + (i&1)], st[i]);
  }
}

// apply BN (inline bucket reduce) -> store x/s -> next-layer weight GEMM -> fp16 outputs.
template<int LEVEL>
__global__ __launch_bounds__(256) void k_apply_gemm(
    const float* __restrict__ Zw, const float* __restrict__ bktW,
    const float* __restrict__ gW, const float* __restrict__ beW,
    float* __restrict__ xst, const float* __restrict__ Ww,
    const float* __restrict__ dinvw,
    const float* __restrict__ Zb, const float* __restrict__ bktB,
    const float* __restrict__ gB, const float* __restrict__ beB,
    float* __restrict__ sst, const float* __restrict__ Wb,
    const float* __restrict__ dinvb,
    unsigned short* __restrict__ HwOut, unsigned short* __restrict__ HbOut)
{
  constexpr int NGB = (LEVEL == 1) ? 8 : 26;
  constexpr int OSTRIDEB = (LEVEL == 1) ? 32 : 104;
  constexpr int NG = 8 + NGB;
  __shared__ float WwL[30*32];
  __shared__ float WbL[30*OSTRIDEB];
  __shared__ float awL[60], abL[60];
  int t = threadIdx.x;
  if (t < 60) {
    int c = t % 30;
    bool isW = t < 30;
    const float4* p = (const float4*)((isW ? bktW : bktB) + c*128);
    float s1 = 0.f, s2 = 0.f;
#pragma unroll
    for (int k = 0; k < 32; ++k) { float4 v = p[k]; s1 += v.x + v.z; s2 += v.y + v.w; }
    float mean = s1/16384.f, var = s2/16384.f - mean*mean, inv = rsqrtf(var + 1e-5f);
    float aa = (isW ? gW : gB)[c]*inv;
    float* dst = isW ? awL : abL;
    dst[c] = aa; dst[30+c] = (isW ? beW : beB)[c] - mean*aa;
  }
  for (int idx = t; idx < 30*32; idx += 256) {
    int k = idx >> 5, c = idx & 31;
    WwL[idx] = (c < 30) ? Ww[k*30 + c] : 0.f;
  }
  if (LEVEL == 1) {
    for (int idx = t; idx < 30*32; idx += 256) {
      int k = idx >> 5, c = idx & 31;
      WbL[idx] = (c < 30) ? Wb[k*30 + c] : 0.f;
    }
  } else {
    for (int idx = t; idx < 30*OSTRIDEB; idx += 256) {
      int k = idx / OSTRIDEB, j = idx % OSTRIDEB;
      WbL[idx] = (j < 100) ? Wb[k*100 + j] : 0.f;
    }
  }
  __syncthreads();
  int gid = blockIdx.x * 256 + t;
  int row = gid / NG, g = gid % NG;
  if (g < 8) {
    const float4* Z4 = (const float4*)Zw + (size_t)row*8;
    float4 z4[8];
#pragma unroll
    for (int u = 0; u < 8; ++u) z4[u] = Z4[u];
    const float* z = (const float*)z4;
    float4 xv;
    int ch = 4*g;
    xv.x = (ch+0 < 30) ? awL[ch+0]*z[ch+0] + awL[30+ch+0] : 0.f;
    xv.y = (ch+1 < 30) ? awL[ch+1]*z[ch+1] + awL[30+ch+1] : 0.f;
    xv.z = (ch+2 < 30) ? awL[ch+2]*z[ch+2] + awL[30+ch+2] : 0.f;
    xv.w = (ch+3 < 30) ? awL[ch+3]*z[ch+3] + awL[30+ch+3] : 0.f;
    ((float4*)xst)[(size_t)row*8+g] = xv;
    float4 o = {0,0,0,0};
#pragma unroll
    for (int k = 0; k < 30; ++k) {
      float xk = awL[k]*z[k] + awL[30+k];
      float4 w = *(const float4*)(WwL + k*32 + 4*g);
      FMA4(o, xk, w);
    }
    float d = dinvw[row];
    us4 pv = { f2h(d*o.x), f2h(d*o.y), f2h(d*o.z), f2h(d*o.w) };
    unsigned short* dst = (LEVEL == 1) ? (HwOut + (size_t)row*64 + 4*g)
                                       : (HwOut + (size_t)row*32 + 4*g);
    *(us4*)dst = pv;
  } else {
    int gb = g - 8;
    const float4* Z4 = (const float4*)Zb + (size_t)row*8;
    float4 z4[8];
#pragma unroll
    for (int u = 0; u < 8; ++u) z4[u] = Z4[u];
    const float* z = (const float*)z4;
    if (gb < 8) {
      int ch = 4*gb;
      float4 sv;
      sv.x = (ch+0 < 30) ? abL[ch+0]*z[ch+0] + abL[30+ch+0] : 0.f;
      sv.y = (ch+1 < 30) ? abL[ch+1]*z[ch+1] + abL[30+ch+1] : 0.f;
      sv.z = (ch+2 < 30) ? abL[ch+2]*z[ch+2] + abL[30+ch+2] : 0.f;
      sv.w = (ch+3 < 30) ? abL[ch+3]*z[ch+3] + abL[30+ch+3] : 0.f;
      ((float4*)sst)[(size_t)row*8+gb] = sv;
    }
    float4 o = {0,0,0,0};
#pragma unroll
    for (int k = 0; k < 30; ++k) {
      float sk = abL[k]*z[k] + abL[30+k];
      float4 w = *(const float4*)(WbL + k*OSTRIDEB + 4*gb);
      FMA4(o, sk, w);
    }
    float d = dinvb[row];
    us4 pv = { f2h(d*o.x), f2h(d*o.y), f2h(d*o.z), f2h(d*o.w) };
    unsigned short* dst = (LEVEL == 1) ? (HbOut + (size_t)row*64 + 32 + 4*gb)
                                       : (HbOut + (size_t)row*104 + 4*gb);
    *(us4*)dst = pv;
  }
}

// fcpool with inline L3 finalize + fused softmax -> fp16 S [row][104]
__global__ __launch_bounds__(256) void k_fcpool(
    const float* __restrict__ Zw3, const float* __restrict__ bktW3,
    const float* __restrict__ gW3, const float* __restrict__ beW3,
    const float* __restrict__ Zb3, const float* __restrict__ bktB3,
    const float* __restrict__ g100, const float* __restrict__ be100,
    const float* __restrict__ s11, const float* __restrict__ s12,
    const float* __restrict__ Wfc, const float* __restrict__ bfc,
    float* __restrict__ x13, unsigned short* __restrict__ S)
{
  __shared__ float shm[14240];   // feat 64x160 = 10240 | Wl 40x100 = 4000
  __shared__ float aw3[60], ab3[200];
  float* feat = shm;
  float* Wl = shm + 10240;
  int t = threadIdx.x;
  int g0 = blockIdx.x * 64;
  if (t < 30) {
    const float4* p = (const float4*)(bktW3 + t*16);
    float s1 = 0.f, s2 = 0.f;
#pragma unroll
    for (int k = 0; k < 4; ++k) { float4 v = p[k]; s1 += v.x + v.z; s2 += v.y + v.w; }
    float mean = s1/16384.f, var = s2/16384.f - mean*mean, inv = rsqrtf(var + 1e-5f);
    float aa = gW3[t]*inv; aw3[t] = aa; aw3[30+t] = beW3[t] - mean*aa;
  } else if (t >= 64 && t < 164) {
    int c = t - 64;
    const float4* p = (const float4*)(bktB3 + c*16);
    float s1 = 0.f, s2 = 0.f;
#pragma unroll
    for (int k = 0; k < 4; ++k) { float4 v = p[k]; s1 += v.x + v.z; s2 += v.y + v.w; }
    float mean = s1/16384.f, var = s2/16384.f - mean*mean, inv = rsqrtf(var + 1e-5f);
    float aa = g100[c]*inv; ab3[c] = aa; ab3[100+c] = be100[c] - mean*aa;
  }
  __syncthreads();
  for (int idx = t; idx < 64*160; idx += 256) {
    int l = idx / 160, c = idx % 160;
    int g = g0 + l;
    float v;
    if (c < 30) v = s11[(size_t)g*32 + c];
    else if (c < 60) v = s12[(size_t)g*32 + (c-30)];
    else { int k = c - 60; v = ab3[k]*Zb3[(size_t)g*104 + k] + ab3[100 + k]; }
    feat[l*160 + c] = v;
  }
  for (int idx = t; idx < 64*32; idx += 256) {
    int l = idx >> 5, c = idx & 31;
    int g = g0 + l;
    x13[(size_t)g*32+c] = (c < 30) ? aw3[c]*Zw3[(size_t)g*32+c] + aw3[30+c] : 0.f;
  }
  int np = t >> 3, kg = t & 7;
  int n0 = np*2, n1 = np*2 + 1;
  int kbase = kg*12 + (kg < 4 ? kg : 4);
  int klen  = kg < 4 ? 13 : 12;
  float a0[13], a1[13];
#pragma unroll
  for (int j = 0; j < 13; ++j) { a0[j] = 0.f; a1[j] = 0.f; }
  for (int ch = 0; ch < 4; ++ch) {
    __syncthreads();
    for (int idx = t; idx < 4000; idx += 256) {
      int r = idx/100, j = idx%100;
      Wl[r*100 + j] = Wfc[(ch*40 + r)*100 + j];
    }
    __syncthreads();
    for (int kk = 0; kk < 40; ++kk) {
      float f0 = feat[n0*160 + ch*40+kk];
      float f1 = feat[n1*160 + ch*40+kk];
#pragma unroll
      for (int j = 0; j < 13; ++j) {
        if (j < klen) {
          float w = Wl[kk*100 + kbase + j];
          a0[j] += f0*w; a1[j] += f1*w;
        }
      }
    }
  }
  __syncthreads();
  float* sRow = shm;  // reuse as [64][100]
  for (int j = 0; j < klen; ++j) {
    int k = kbase + j;
    sRow[n0*100 + k] = a0[j] + bfc[k];
    sRow[n1*100 + k] = a1[j] + bfc[k];
  }
  __syncthreads();
  int n = t >> 2, part = t & 3;
  int i0 = part*25;
  float m = -3.4e38f;
  for (int i = 0; i < 25; ++i) m = fmaxf(m, sRow[n*100 + i0 + i]);
  m = fmaxf(m, __shfl_xor(m, 1));
  m = fmaxf(m, __shfl_xor(m, 2));
  float ev[25]; float s = 0.f;
  for (int i = 0; i < 25; ++i) { float e = __expf(sRow[n*100 + i0 + i] - m); ev[i] = e; s += e; }
  s += __shfl_xor(s, 1);
  s += __shfl_xor(s, 2);
  float rinv = 1.f / s;
  for (int i = 0; i < 25; ++i) S[(size_t)(g0+n)*104 + i0 + i] = f2h(ev[i] * rinv);
  if (part == 3) {
    S[(size_t)(g0+n)*104 + 100] = 0; S[(size_t)(g0+n)*104 + 101] = 0;
    S[(size_t)(g0+n)*104 + 102] = 0; S[(size_t)(g0+n)*104 + 103] = 0;
  }
}

// As = adj @ S (weighted): fp16 S [row][104], 13 lanes/row.
__global__ __launch_bounds__(256) void k_spmm_as(
    const unsigned short* __restrict__ S, const float* __restrict__ ellv,
    const unsigned short* __restrict__ ellc, const int* __restrict__ rowlen,
    float* __restrict__ Z)
{
  int t = threadIdx.x;
  int gid = blockIdx.x * 256 + t;
  int row = gid / 13, q = gid - row*13;
  int len = rowlen[row];
  const float4* ev = (const float4*)(ellv + (size_t)row * CAP);
  const uint2*  ec = (const uint2*) (ellc + (size_t)row * CAP);
  const uint4* HP = (const uint4*)(S + (size_t)(row >> 11) * ((size_t)NN*104));
  float acc[8] = {0,0,0,0,0,0,0,0};
  int nit = len >> 2;
  for (int i = 0; i < nit; ++i) {
    float4 v = ev[i];
    uint2 cc = ec[i];
    int c0 = cc.x & 0xffff, c1 = cc.x >> 16, c2 = cc.y & 0xffff, c3 = cc.y >> 16;
    uint4 g0 = HP[c0*13+q], g1 = HP[c1*13+q], g2 = HP[c2*13+q], g3 = HP[c3*13+q];
    ACC8(g0, v.x); ACC8(g1, v.y); ACC8(g2, v.z); ACC8(g3, v.w);
  }
  float* Zp = Z + (size_t)row*104 + q*8;
  float4 o0 = {acc[0],acc[1],acc[2],acc[3]}, o1 = {acc[4],acc[5],acc[6],acc[7]};
  ((float4*)Zp)[0] = o0; ((float4*)Zp)[1] = o1;
}

// pooled partials + FUSED stage-1 column max.
__global__ __launch_bounds__(256) void k_pool_part(
    const unsigned short* __restrict__ S, const float* __restrict__ x13,
    const float* __restrict__ As, const float* __restrict__ x11,
    const float* __restrict__ x12, float* __restrict__ pp, float* __restrict__ pm)
{
  __shared__ float sL[64][100];
  __shared__ float xL[64][132];
  __shared__ float red[256];
  int t = threadIdx.x;
  int b = blockIdx.x >> 3, chunk = blockIdx.x & 7;
  int g00 = b * 2048 + chunk * 256;
  int kt = t/10, dt = t%10;
  int k0 = kt*4, d0 = dt*13;
  float acc[4][13];
#pragma unroll
  for (int a = 0; a < 4; ++a)
#pragma unroll
    for (int j = 0; j < 13; ++j) acc[a][j] = 0.f;
  for (int tile = 0; tile < 4; ++tile) {
    int g0 = g00 + tile*64;
    __syncthreads();
    for (int idx = t; idx < 64*100; idx += 256) {
      int l = idx/100, k = idx%100;
      sL[l][k] = h2f(S[(size_t)(g0+l)*104 + k]);
    }
    for (int idx = t; idx < 64*130; idx += 256) {
      int l = idx/130, d = idx%130;
      xL[l][d] = d < 30 ? x13[(size_t)(g0+l)*32 + d] : As[(size_t)(g0+l)*104 + (d-30)];
    }
    __syncthreads();
    if (t < 250) {
      for (int kk = 0; kk < 64; ++kk) {
        float sv[4];
#pragma unroll
        for (int a = 0; a < 4; ++a) sv[a] = sL[kk][k0+a];
#pragma unroll
        for (int j = 0; j < 13; ++j) {
          float xv = xL[kk][d0+j];
#pragma unroll
          for (int a = 0; a < 4; ++a) acc[a][j] += sv[a]*xv;
        }
      }
    }
  }
  if (t < 250) {
    float* dst = pp + (size_t)blockIdx.x * 13000;
    for (int a = 0; a < 4; ++a)
      for (int j = 0; j < 13; ++j)
        dst[(k0+a)*130 + (d0+j)] = acc[a][j];
  }
  __syncthreads();
  {
    int c = t & 31, rg = t >> 5;
    const float* srcs[3] = {x11, x12, x13};
    for (int a = 0; a < 3; ++a) {
      const float* p = srcs[a] + (size_t)(g00+rg)*32 + c;
      float m = -3.4e38f;
      for (int it = 0; it < 32; ++it) m = fmaxf(m, p[it*256]);
      red[t] = m;
      __syncthreads();
      if (t < 30) {
        float mm = red[t];
        for (int g = 1; g < 8; ++g) mm = fmaxf(mm, red[g*32+t]);
        pm[(size_t)blockIdx.x*90 + a*30 + t] = mm;
      }
      __syncthreads();
    }
  }
}

// Fully fused stage 2 (R10: register-tiled, fp32 A2 in LDS — was LDS-read-throughput
// bound at 109us: 2 ds_reads per FMA; now 4 reads per 16 FMAs via 2x8 tiles).
__global__ __launch_bounds__(256) void k_s2fused(
    const float* __restrict__ pp, const float* __restrict__ partmax,
    const float* __restrict__ Wm,    // 3 consecutive 30x30
    const float* __restrict__ g30,   // +150
    const float* __restrict__ be30,  // +150
    float* __restrict__ bktS2,       // [3][30][2] (zeroed)
    int* __restrict__ cnt,           // zeroed barrier counter
    const float* __restrict__ W1, const float* __restrict__ b1,
    const float* __restrict__ W2, const float* __restrict__ b2,
    float* __restrict__ out)
{
  __shared__ float A2f[10000];     // 40 KB, fp32
  __shared__ float buf1[3000];     // X (stride 30)
  __shared__ float buf2[3200];     // T padded [100][32]
  __shared__ float WL[960];        // W padded [30][32]
  __shared__ float dl[100];
  __shared__ float st1[30], st2[30];
  __shared__ float coef[60];
  __shared__ float x1L[90], x2L[90], hh[50];
  int b = blockIdx.x, t = threadIdx.x;
  // pool-reduce: Xpool -> buf1, raw pooled adj -> A2f
  for (int idx = t; idx < 13000; idx += 256) {
    float s = 0.f;
    for (int ch = 0; ch < 8; ++ch) s += pp[(size_t)(b*8 + ch)*13000 + idx];
    int k = idx/130, d = idx%130;
    if (d < 30) buf1[k*30 + d] = s;
    else A2f[k*100 + (d-30)] = s;
  }
  __syncthreads();
  if (t < 100 && A2f[t*101] == 0.f) A2f[t*101] = 1.f;
  __syncthreads();
  if (t < 100) {
    float s = 0.f;
    for (int j = 0; j < 100; ++j) s += A2f[t*100 + j];
    dl[t] = s > 0.f ? rsqrtf(s) : 0.f;
  }
  __syncthreads();
  for (int idx = t; idx < 10000; idx += 256) {
    int i = idx/100, j = idx%100;
    A2f[idx] = dl[i]*dl[j]*A2f[idx];
  }
  // tile assignment: 200 active threads, 2 rows x 8 cols each
  int rp = t >> 2, cg = t & 3;        // rp 0..63(49 used), cg 0..3
  int i0 = rp*2, c0 = cg*8;
  bool act = (t < 200);
  for (int L = 0; L < 3; ++L) {
    if (t < 30) { st1[t] = 0.f; st2[t] = 0.f; }
    const float* W = Wm + L*900;
    for (int idx = t; idx < 960; idx += 256) {
      int k = idx >> 5, c = idx & 31;
      WL[idx] = (c < 30) ? W[k*30 + c] : 0.f;
    }
    __syncthreads();
    // T = X @ W  (buf1 -> buf2 padded), 2x8 tiles
    if (act) {
      float a0[8] = {0,0,0,0,0,0,0,0}, a1[8] = {0,0,0,0,0,0,0,0};
      for (int k = 0; k < 30; ++k) {
        float xx0 = buf1[i0*30 + k], xx1 = buf1[(i0+1)*30 + k];
        float4 w0 = *(const float4*)&WL[k*32 + c0];
        float4 w1 = *(const float4*)&WL[k*32 + c0 + 4];
        a0[0] += xx0*w0.x; a0[1] += xx0*w0.y; a0[2] += xx0*w0.z; a0[3] += xx0*w0.w;
        a0[4] += xx0*w1.x; a0[5] += xx0*w1.y; a0[6] += xx0*w1.z; a0[7] += xx0*w1.w;
        a1[0] += xx1*w0.x; a1[1] += xx1*w0.y; a1[2] += xx1*w0.z; a1[3] += xx1*w0.w;
        a1[4] += xx1*w1.x; a1[5] += xx1*w1.y; a1[6] += xx1*w1.z; a1[7] += xx1*w1.w;
      }
      float4 s00 = {a0[0],a0[1],a0[2],a0[3]}, s01 = {a0[4],a0[5],a0[6],a0[7]};
      float4 s10 = {a1[0],a1[1],a1[2],a1[3]}, s11v = {a1[4],a1[5],a1[6],a1[7]};
      *(float4*)&buf2[i0*32 + c0]       = s00;
      *(float4*)&buf2[i0*32 + c0 + 4]   = s01;
      *(float4*)&buf2[(i0+1)*32 + c0]   = s10;
      *(float4*)&buf2[(i0+1)*32 + c0+4] = s11v;
    }
    __syncthreads();
    // Z = A2 @ T  (-> buf1) + per-thread stats from registers
    if (act) {
      float z0[8] = {0,0,0,0,0,0,0,0}, z1[8] = {0,0,0,0,0,0,0,0};
      for (int j = 0; j < 100; ++j) {
        float av0 = A2f[i0*100 + j], av1 = A2f[(i0+1)*100 + j];
        float4 t0 = *(const float4*)&buf2[j*32 + c0];
        float4 t1 = *(const float4*)&buf2[j*32 + c0 + 4];
        z0[0] += av0*t0.x; z0[1] += av0*t0.y; z0[2] += av0*t0.z; z0[3] += av0*t0.w;
        z0[4] += av0*t1.x; z0[5] += av0*t1.y; z0[6] += av0*t1.z; z0[7] += av0*t1.w;
        z1[0] += av1*t0.x; z1[1] += av1*t0.y; z1[2] += av1*t0.z; z1[3] += av1*t0.w;
        z1[4] += av1*t1.x; z1[5] += av1*t1.y; z1[6] += av1*t1.z; z1[7] += av1*t1.w;
      }
#pragma unroll
      for (int k = 0; k < 8; ++k) {
        int c = c0 + k;
        if (c < 30) {
          buf1[i0*30 + c]     = z0[k];
          buf1[(i0+1)*30 + c] = z1[k];
          atomicAdd(&st1[c], z0[k] + z1[k]);
          atomicAdd(&st2[c], z0[k]*z0[k] + z1[k]*z1[k]);
        }
      }
    }
    __syncthreads();
    if (t < 30) {
      atomicAdd(&bktS2[(L*30+t)*2],   st1[t]);
      atomicAdd(&bktS2[(L*30+t)*2+1], st2[t]);
    }
    __syncthreads();
    if (t == 0) {
      __threadfence();
      atomicAdd(cnt, 1);
      while (atomicAdd(cnt, 0) < (L+1)*8) {}
      __threadfence();
    }
    __syncthreads();
    if (t < 30) {
      float s1 = atomicAdd(&bktS2[(L*30+t)*2],   0.f);
      float s2 = atomicAdd(&bktS2[(L*30+t)*2+1], 0.f);
      float mean = s1/800.f, var = s2/800.f - mean*mean, inv = rsqrtf(var + 1e-5f);
      float aa = g30[L*30+t]*inv;
      coef[t] = aa; coef[30+t] = be30[L*30+t] - mean*aa;
    }
    __syncthreads();
    if (L < 2) {
      for (int idx = t; idx < 3000; idx += 256) {
        int c = idx % 30;
        buf1[idx] = coef[c]*buf1[idx] + coef[30+c];
      }
      __syncthreads();
      if (t < 30) {
        float m = -3.4e38f;
        for (int i = 0; i < 100; ++i) m = fmaxf(m, buf1[i*30+t]);
        x2L[L*30+t] = m;
      }
      __syncthreads();
    } else {
      if (t < 30) {
        float m = -3.4e38f;
        for (int i = 0; i < 100; ++i) m = fmaxf(m, coef[t]*buf1[i*30+t] + coef[30+t]);
        x2L[60+t] = m;
      }
    }
  }
  if (t < 90) {
    float m = -3.4e38f;
    for (int s = 0; s < 8; ++s) m = fmaxf(m, partmax[(size_t)(b*8+s)*90 + t]);
    x1L[t] = m;
  }
  __syncthreads();
  if (t < 50) {
    float a = b1[t];
    for (int k = 0; k < 90; ++k) a += x1L[k]*W1[k*50+t];
    for (int k = 0; k < 90; ++k) a += x2L[k]*W1[(90+k)*50+t];
    hh[t] = fmaxf(a, 0.f);
  }
  __syncthreads();
  if (t < 6) {
    float a = b2[t];
    for (int j = 0; j < 50; ++j) a += hh[j]*W2[j*6+t];
    out[b*6+t] = a;
  }
}

// ---------------- launcher ----------------
extern "C" void kernel_launch(void* const* d_in, const int* in_sizes, int n_in,
                              void* d_out, int out_size, void* d_ws, size_t ws_size,
                              hipStream_t stream)
{
  const float* x    = (const float*)d_in[0];
  const float* adj  = (const float*)d_in[1];
  const float* Win  = (const float*)d_in[2];
  const float* W3030= (const float*)d_in[3];
  const float* Wp13 = (const float*)d_in[4];
  // d_in[5]=b30, d_in[6]=b100: cancel through training-mode BN -> unused
  const float* Wfc  = (const float*)d_in[7];
  const float* bfc  = (const float*)d_in[8];
  const float* W1   = (const float*)d_in[9];
  const float* b1   = (const float*)d_in[10];
  const float* W2   = (const float*)d_in[11];
  const float* b2   = (const float*)d_in[12];
  const float* g30  = (const float*)d_in[13];
  const float* be30 = (const float*)d_in[14];
  const float* g100 = (const float*)d_in[15];
  const float* be100= (const float*)d_in[16];
  float* out = (float*)d_out;

  float* wsf = (float*)d_ws;
  float* bL1W = wsf + OF_B1W;  float* bL1B = wsf + OF_B1B;
  float* bL2W = wsf + OF_B2W;  float* bL2B = wsf + OF_B2B;
  float* bL3W = wsf + OF_B3W;  float* bL3B = wsf + OF_B3B;
  float* bktS2 = wsf + OF_S2;
  int*   cnt  = (int*)(wsf + OF_CNT);
  float* ellv  = wsf + OF_ELLV;
  unsigned short* ellc = (unsigned short*)(wsf + OF_ELLC);
  int*   rowlen = (int*)(wsf + OF_ROWLEN);
  float* dinvw = wsf + OF_DINVW;
  float* dinvb = wsf + OF_DINVB;
  unsigned short* Hwb   = (unsigned short*)(wsf + OF_HWB);
  unsigned short* Hw3   = (unsigned short*)(wsf + OF_HW3);
  unsigned short* Hb100 = (unsigned short*)(wsf + OF_HB100);
  unsigned short* S     = Hb100;   // S reuses HB100 (dead after L3-b spmm)
  float* Zw = wsf + OF_ZW;
  float* Zb = wsf + OF_ZB;         // stride 104; later reused as As
  float* x11 = wsf + OF_X11;
  float* x12 = wsf + OF_X12;
  float* x13 = wsf + OF_X13;
  float* s11 = wsf + OF_S11;
  float* s12 = wsf + OF_S12;
  float* pp  = wsf + OF_S11;       // pool partials reuse s11+s12 (dead after fcpool)
  float* partmax = wsf + OF_PARTMAX;

  // 10 dispatches
  k_build_ell<<<RTOT, 256, 0, stream>>>(adj, x, Win, ellv, ellc, rowlen, dinvw, dinvb, Hwb, wsf);

  k_spmm_pair<<<512, 256, 0, stream>>>(Hwb, ellv, ellc, rowlen, dinvw, dinvb, Zw, Zb, bL1W, bL1B);
  k_apply_gemm<1><<<1024, 256, 0, stream>>>(Zw, bL1W, g30+0, be30+0, x11, W3030+0, dinvw,
                                            Zb, bL1B, g30+90, be30+90, s11, W3030+2*900, dinvb, Hwb, Hwb);

  k_spmm_pair<<<512, 256, 0, stream>>>(Hwb, ellv, ellc, rowlen, dinvw, dinvb, Zw, Zb, bL2W, bL2B);
  k_apply_gemm<2><<<2176, 256, 0, stream>>>(Zw, bL2W, g30+30, be30+30, x12, W3030+900, dinvw,
                                            Zb, bL2B, g30+120, be30+120, s12, Wp13, dinvb, Hw3, Hb100);

  k_spmm_l3<<<1088, 256, 0, stream>>>(Hw3, Hb100, ellv, ellc, rowlen, dinvw, dinvb, Zw, Zb, bL3W, bL3B);
  k_fcpool<<<256, 256, 0, stream>>>(Zw, bL3W, g30+60, be30+60, Zb, bL3B, g100, be100,
                                    s11, s12, Wfc, bfc, x13, S);

  k_spmm_as<<<832, 256, 0, stream>>>(S, ellv, ellc, rowlen, Zb /* As */);
  k_pool_part<<<64, 256, 0, stream>>>(S, x13, Zb, x11, x12, pp, partmax);

  k_s2fused<<<BATCH, 256, 0, stream>>>(pp, partmax, W3030+3*900, g30+150, be30+150,
                                       bktS2, cnt, W1, b1, W2, b2, out);
}